// Round 14
// baseline (363.706 us; speedup 1.0000x reference)
//
#include <hip/hip_runtime.h>

// CapsTimeModel forward, round 14: conv2 -> global_load_lds double-buffer
// (m97 structure, 1 barrier/K-step); fc1+fc2 merged into k_fc.
// capsfused / nv1 / conv1 / repacks identical to R13 (passing, 320us).

#define EPSLN 1e-5f

typedef short  short8 __attribute__((ext_vector_type(8)));
typedef __bf16 bf16x8 __attribute__((ext_vector_type(8)));
typedef float  f32x4  __attribute__((ext_vector_type(4)));

union Frag { short8 s; bf16x8 b; };

__device__ __forceinline__ uint4 pack_bf16_8(float4 a, float4 b) {
    union { __bf16 h[8]; uint4 u; } r;
    r.h[0] = (__bf16)a.x; r.h[1] = (__bf16)a.y;
    r.h[2] = (__bf16)a.z; r.h[3] = (__bf16)a.w;
    r.h[4] = (__bf16)b.x; r.h[5] = (__bf16)b.y;
    r.h[6] = (__bf16)b.z; r.h[7] = (__bf16)b.w;
    return r.u;
}

// async 16B global -> LDS (direct, no VGPR round-trip)
__device__ __forceinline__ void gld16(const void* g, void* l) {
    __builtin_amdgcn_global_load_lds(
        (const __attribute__((address_space(1))) void*)g,
        (__attribute__((address_space(3))) void*)l, 16, 0, 0);
}

// ==================== fused repacks (blockIdx-range dispatch) ====================
__global__ __launch_bounds__(256) void k_repack_all(
        const float* __restrict__ bw,  float* __restrict__ bwT,
        const float* __restrict__ pw,  __bf16* __restrict__ wbT,
        const float* __restrict__ fw,  float* __restrict__ fwp,
        const float* __restrict__ cw,  __bf16* __restrict__ cw2,
        __bf16* __restrict__ cwB) {
    int blk = blockIdx.x;
    if (blk < 2304) {                         // pcw -> wbT : 589824 exact
        int i = blk * 256 + threadIdx.x;
        int oc = i / 1152, r = i % 1152;
        int ic = r / 9, tap = r % 9;
        wbT[oc * 1152 + tap * 128 + ic] = (__bf16)pw[i];
    } else if (blk < 3284) {                  // fw -> fwp : 250880 exact (unused; kept)
        int i = (blk - 2304) * 256 + threadIdx.x;
        int m = i % 10;
        int d = (i / 10) & 3;
        int x = (i / 40) & 3;
        int n = i / 160;
        fwp[(m * 1568 + n) * 16 + x * 4 + d] = fw[i];
    } else if (blk < 3860) {                  // cw -> cw2 : 147456 exact
        int i = (blk - 3284) * 256 + threadIdx.x;
        int m  = i & 31;
        int d  = (i >> 5) & 3;
        int x  = (i >> 7) & 3;
        int n  = (i >> 9) & 31;
        int kl = i >> 14;
        cw2[(((kl * 32 + n) * 32) + m) * 16 + x * 4 + d] = (__bf16)cw[i];
    } else if (blk < 4436) {                  // cw -> cwB : 147456 exact
        int i = (blk - 3860) * 256 + threadIdx.x;
        int m  = i & 31;
        int d  = (i >> 5) & 3;
        int x  = (i >> 7) & 3;
        int n  = (i >> 9) & 31;
        int kl = i >> 14;
        cwB[(m * 4 + d) * 1152 + (n * 9 + kl) * 4 + x] = (__bf16)cw[i];
    } else {                                  // bw -> bwT : 3456
        int i = (blk - 4436) * 256 + threadIdx.x;
        if (i < 3456) {
            int oc = i / 27, r = i % 27;
            bwT[r * 128 + oc] = bw[i];
        }
    }
}

// ==================== conv1: x -> c2p (NHWC bf16, padded), 4 oc/thread ====================
__global__ __launch_bounds__(256) void k_conv1(const float* __restrict__ x,
                                               const float* __restrict__ bwT,
                                               const float* __restrict__ bb,
                                               __bf16* __restrict__ c2p) {
    int gid = blockIdx.x * 256 + threadIdx.x;     // 2,097,152
    int oc4 = gid & 31;
    int p   = gid >> 5;
    int w = p & 31, h = (p >> 5) & 31, b = p >> 10;
    const float* xb = x + b * 12288;
    float4 acc = *(const float4*)(bb + oc4 * 4);
    #pragma unroll
    for (int ky = 0; ky < 3; ++ky) {
        int ih = 2 * h + ky - 1;
        if ((unsigned)ih >= 64u) continue;
        #pragma unroll
        for (int kx = 0; kx < 3; ++kx) {
            int iw = 2 * w + kx - 1;
            if ((unsigned)iw >= 64u) continue;
            #pragma unroll
            for (int ic = 0; ic < 3; ++ic) {
                float in = xb[(ic * 64 + ih) * 64 + iw];
                float4 wv = *(const float4*)(bwT + (ic * 9 + ky * 3 + kx) * 128 + oc4 * 4);
                acc.x = fmaf(in, wv.x, acc.x);
                acc.y = fmaf(in, wv.y, acc.y);
                acc.z = fmaf(in, wv.z, acc.z);
                acc.w = fmaf(in, wv.w, acc.w);
            }
        }
    }
    union { __bf16 h4[4]; unsigned long long ull; } r;
    r.h4[0] = (__bf16)fmaxf(acc.x, 0.f);
    r.h4[1] = (__bf16)fmaxf(acc.y, 0.f);
    r.h4[2] = (__bf16)fmaxf(acc.z, 0.f);
    r.h4[3] = (__bf16)fmaxf(acc.w, 0.f);
    *(unsigned long long*)(c2p + ((b * 34 + h + 1) * 34 + (w + 1)) * 128 + oc4 * 4) = r.ull;
}

// ==================== conv2: global_load_lds dbuf MFMA GEMM + fused LN0 ====================
__global__ __launch_bounds__(256) void k_conv2_mfma(const __bf16* __restrict__ c2p,
                                                    const __bf16* __restrict__ wbT,
                                                    const float* __restrict__ g,
                                                    const float* __restrict__ bt,
                                                    float* __restrict__ val) {
    __shared__ unsigned short sA[2][128 * 32];   // 16 KB
    __shared__ unsigned short sB[2][64 * 32];    //  8 KB

    const int t = threadIdx.x;
    const int mblk = blockIdx.x >> 3, nblk = blockIdx.x & 7;
    const int pbase = mblk * 128, ocbase = nblk * 64;
    const int b = pbase >> 8;

    const int kc8 = (t & 3) * 8;
    const int r0 = t >> 2;
    const int oh0 = ((pbase + r0) >> 4) & 15, ow0 = (pbase + r0) & 15;
    const int oh1 = ((pbase + r0 + 64) >> 4) & 15, ow1 = (pbase + r0 + 64) & 15;

    const unsigned short* cb = (const unsigned short*)c2p + (size_t)b * 147968;
    const unsigned short* ws = (const unsigned short*)wbT
                               + (ocbase + (t >> 2)) * 1152 + kc8;

    const int lane = t & 63, wid = t >> 6;
    const int lo = lane & 15, hi = lane >> 4;

    f32x4 acc[2][4];
    #pragma unroll
    for (int fr = 0; fr < 2; ++fr)
        #pragma unroll
        for (int fc = 0; fc < 4; ++fc)
            acc[fr][fc] = (f32x4){0.f, 0.f, 0.f, 0.f};

    auto stage = [&](int buf, int ks) {
        int tap = ks / 4, ic0 = (ks % 4) * 32;
        int ty = tap / 3, tx = tap % 3;
        gld16(cb + ((2 * oh0 + ty) * 34 + (2 * ow0 + tx)) * 128 + ic0 + kc8,
              &sA[buf][(unsigned)t * 8]);
        gld16(cb + ((2 * oh1 + ty) * 34 + (2 * ow1 + tx)) * 128 + ic0 + kc8,
              &sA[buf][((unsigned)t + 256) * 8]);
        gld16(ws + ks * 32, &sB[buf][(unsigned)t * 8]);
    };

    stage(0, 0);
    __syncthreads();                      // drains vmcnt -> buf0 ready

    for (int ks = 0; ks < 36; ++ks) {
        const int cur = ks & 1;
        if (ks + 1 < 36) stage(cur ^ 1, ks + 1);   // async into other buffer
        Frag af0, af1, bf[4];
        af0.s = *(const short8*)&sA[cur][(wid * 32 + lo) * 32 + hi * 8];
        af1.s = *(const short8*)&sA[cur][(wid * 32 + 16 + lo) * 32 + hi * 8];
        #pragma unroll
        for (int fc = 0; fc < 4; ++fc)
            bf[fc].s = *(const short8*)&sB[cur][(fc * 16 + lo) * 32 + hi * 8];
        #pragma unroll
        for (int fc = 0; fc < 4; ++fc) {
            acc[0][fc] = __builtin_amdgcn_mfma_f32_16x16x32_bf16(
                af0.b, bf[fc].b, acc[0][fc], 0, 0, 0);
            acc[1][fc] = __builtin_amdgcn_mfma_f32_16x16x32_bf16(
                af1.b, bf[fc].b, acc[1][fc], 0, 0, 0);
        }
        __syncthreads();                  // drains vmcnt -> next buf ready
    }

    const float gv = g[lo], bv = bt[lo];
    #pragma unroll
    for (int fr = 0; fr < 2; ++fr) {
        #pragma unroll
        for (int fc = 0; fc < 4; ++fc) {
            const int n = (ocbase >> 4) + fc;
            #pragma unroll
            for (int j = 0; j < 4; ++j) {
                float v = acc[fr][fc][j];
                float s1 = v, s2 = v * v;
                #pragma unroll
                for (int off = 1; off < 16; off <<= 1) {
                    s1 += __shfl_xor(s1, off);
                    s2 += __shfl_xor(s2, off);
                }
                float mu  = s1 * (1.f / 16.f);
                float var = s2 * (1.f / 16.f) - mu * mu;
                float rs  = rsqrtf(var + EPSLN);
                float o   = (v - mu) * rs * gv + bv;
                int p  = pbase + wid * 32 + fr * 16 + hi * 4 + j;
                int oh = (p >> 4) & 15, ow = p & 15;
                val[(((b * 32 + n) * 16 + oh) * 16 + ow) * 16 + lo] = o;
            }
        }
    }
}

// ==================== nv1 GEMM (pipelined, reg-staged): val x cwB -> nv1g ====================
__global__ __launch_bounds__(256) void k_nv1_mfma(const float* __restrict__ val,
                                                  const __bf16* __restrict__ cwB,
                                                  float* __restrict__ nv1g) {
    __shared__ unsigned short sA[128 * 32];
    __shared__ unsigned short sB[64 * 32];

    const int t = threadIdx.x;
    const int mblk = blockIdx.x >> 1, nblk = blockIdx.x & 1;
    const int pbase = mblk * 128, ocbase = nblk * 64;

    const float* vbase[2];
    #pragma unroll
    for (int u = 0; u < 2; ++u) {
        int r = pbase + (t >> 2) + u * 64;
        int site = r >> 2, a = r & 3;
        int b = site / 49, hw = site % 49;
        int h = hw / 7, w = hw % 7;
        vbase[u] = val + (size_t)b * 131072 + (2 * h) * 256 + (2 * w) * 16 + a * 4;
    }
    const unsigned short* wsrc = (const unsigned short*)cwB
                                 + (ocbase + (t >> 2)) * 1152 + (t & 3) * 8;

    const int lane = t & 63, wid = t >> 6;
    const int lo = lane & 15, hi = lane >> 4;

    f32x4 acc[2][4];
    #pragma unroll
    for (int fr = 0; fr < 2; ++fr)
        #pragma unroll
        for (int fc = 0; fc < 4; ++fc)
            acc[fr][fc] = (f32x4){0.f, 0.f, 0.f, 0.f};

    auto itemoff = [](int i) {
        int n = i / 9, kl = i % 9;
        return n * 4096 + (kl / 3) * 256 + (kl % 3) * 16;
    };

    {
        int i0 = (t & 3) * 2;
        int o0 = itemoff(i0), o1 = itemoff(i0 + 1);
        uint4 a0 = pack_bf16_8(*(const float4*)(vbase[0] + o0),
                               *(const float4*)(vbase[0] + o1));
        uint4 a1 = pack_bf16_8(*(const float4*)(vbase[1] + o0),
                               *(const float4*)(vbase[1] + o1));
        uint4 b0 = *(const uint4*)(wsrc);
        *(uint4*)&sA[(unsigned)t * 8]         = a0;
        *(uint4*)&sA[((unsigned)t + 256) * 8] = a1;
        *(uint4*)&sB[(unsigned)t * 8]         = b0;
        __syncthreads();
    }

    for (int ks = 0; ks < 36; ++ks) {
        uint4 a0, a1, b0;
        const bool pre = (ks + 1) < 36;
        if (pre) {
            int i0 = (ks + 1) * 8 + (t & 3) * 2;
            int o0 = itemoff(i0), o1 = itemoff(i0 + 1);
            a0 = pack_bf16_8(*(const float4*)(vbase[0] + o0),
                             *(const float4*)(vbase[0] + o1));
            a1 = pack_bf16_8(*(const float4*)(vbase[1] + o0),
                             *(const float4*)(vbase[1] + o1));
            b0 = *(const uint4*)(wsrc + (ks + 1) * 32);
        }
        Frag af0, af1, bf[4];
        af0.s = *(const short8*)&sA[(wid * 32 + lo) * 32 + hi * 8];
        af1.s = *(const short8*)&sA[(wid * 32 + 16 + lo) * 32 + hi * 8];
        #pragma unroll
        for (int fc = 0; fc < 4; ++fc)
            bf[fc].s = *(const short8*)&sB[(fc * 16 + lo) * 32 + hi * 8];
        #pragma unroll
        for (int fc = 0; fc < 4; ++fc) {
            acc[0][fc] = __builtin_amdgcn_mfma_f32_16x16x32_bf16(
                af0.b, bf[fc].b, acc[0][fc], 0, 0, 0);
            acc[1][fc] = __builtin_amdgcn_mfma_f32_16x16x32_bf16(
                af1.b, bf[fc].b, acc[1][fc], 0, 0, 0);
        }
        __syncthreads();
        if (pre) {
            *(uint4*)&sA[(unsigned)t * 8]         = a0;
            *(uint4*)&sA[((unsigned)t + 256) * 8] = a1;
            *(uint4*)&sB[(unsigned)t * 8]         = b0;
        }
        __syncthreads();
    }

    #pragma unroll
    for (int fr = 0; fr < 2; ++fr)
        #pragma unroll
        for (int fc = 0; fc < 4; ++fc)
            #pragma unroll
            for (int j = 0; j < 4; ++j) {
                int row = pbase + wid * 32 + fr * 16 + hi * 4 + j;
                int col = ocbase + fc * 16 + lo;
                nv1g[row * 128 + col] = acc[fr][fc][j];
            }
}

// ===================== caps routing pass 2 + LN1 (pass 1 via k_nv1_mfma) =====================
__global__ __launch_bounds__(256) void k_capsfused(const float* __restrict__ val,
                                                   const __bf16* __restrict__ cw2,
                                                   const float* __restrict__ nv1g,
                                                   const float* __restrict__ g,
                                                   const float* __restrict__ bt,
                                                   float* __restrict__ vout) {
    int bb = blockIdx.x / 49;
    int hw = blockIdx.x % 49;
    int h = hw / 7, w = hw % 7;

    __shared__ float4 uloc4[2][1152];   // 36864 B; aliased by wred after loop
    __shared__ float  v1s[2][512];      //  4096 B
    float* wred = (float*)uloc4;

    for (int t = threadIdx.x; t < 2304; t += 256) {
        int s  = t >= 1152;
        int tt = t - s * 1152;
        int f  = tt & 3;
        int kl = (tt >> 2) % 9;
        int n  = tt / 36;
        int k = kl / 3, l = kl % 3;
        int b = bb + s * 32;
        uloc4[s][tt] = *(const float4*)(val +
            (((b * 32 + n) * 16 + (2 * h + k)) * 16 + (2 * w + l)) * 16 + f * 4);
    }

    const int lane  = threadIdx.x & 31;
    const int grpid = threadIdx.x >> 5;
    const int wid   = threadIdx.x >> 6;
    const bool half0 = (threadIdx.x & 32) == 0;

    float nvp[2][16];
    #pragma unroll
    for (int s = 0; s < 2; ++s) {
        int site = (bb + s * 32) * 49 + hw;
        #pragma unroll
        for (int a = 0; a < 4; ++a) {
            float4 q = *(const float4*)(nv1g + (site * 4 + a) * 128 + lane * 4);
            nvp[s][a * 4 + 0] = q.x * (1.f / 32.f);
            nvp[s][a * 4 + 1] = q.y * (1.f / 32.f);
            nvp[s][a * 4 + 2] = q.z * (1.f / 32.f);
            nvp[s][a * 4 + 3] = q.w * (1.f / 32.f);
        }
        float mu = 0.f;
        #pragma unroll
        for (int j = 0; j < 16; ++j) mu += nvp[s][j];
        mu *= (1.f / 16.f);
        float var = 0.f;
        #pragma unroll
        for (int j = 0; j < 16; ++j) { float d = nvp[s][j] - mu; var += d * d; }
        var *= (1.f / 16.f);
        float rs = rsqrtf(var + EPSLN);
        #pragma unroll
        for (int j = 0; j < 16; ++j)
            nvp[s][j] = (nvp[s][j] - mu) * rs * g[j] + bt[j];
    }

    float nvacc[2][16];
    #pragma unroll
    for (int s = 0; s < 2; ++s)
        #pragma unroll
        for (int j = 0; j < 16; ++j) nvacc[s][j] = 0.f;

    __syncthreads();

    {
        uint4 wq0, wq1;
        {
            int n = grpid / 9, kl = grpid % 9;
            const uint4* wb = (const uint4*)(cw2 + (((kl * 32 + n) * 32) + lane) * 16);
            wq0 = wb[0]; wq1 = wb[1];
        }
        for (int it = grpid; it < 288; it += 8) {
            int nit = it + 8;
            uint4 nq0 = wq0, nq1 = wq1;
            if (nit < 288) {
                int n = nit / 9, kl = nit % 9;
                const uint4* wb = (const uint4*)(cw2 + (((kl * 32 + n) * 32) + lane) * 16);
                nq0 = wb[0]; nq1 = wb[1];
            }
            float cwv[16];
            {
                union { uint4 u; __bf16 hh[8]; } qa, qb;
                qa.u = wq0; qb.u = wq1;
                #pragma unroll
                for (int j = 0; j < 8; ++j) {
                    cwv[j] = (float)qa.hh[j]; cwv[8 + j] = (float)qb.hh[j];
                }
            }
            #pragma unroll
            for (int s = 0; s < 2; ++s) {
                float u16[16];
                #pragma unroll
                for (int f = 0; f < 4; ++f) {
                    float4 t4 = uloc4[s][it * 4 + f];
                    u16[f * 4 + 0] = t4.x; u16[f * 4 + 1] = t4.y;
                    u16[f * 4 + 2] = t4.z; u16[f * 4 + 3] = t4.w;
                }
                float votes[16];
                #pragma unroll
                for (int a = 0; a < 4; ++a)
                    #pragma unroll
                    for (int d = 0; d < 4; ++d) {
                        float v = 0.f;
                        #pragma unroll
                        for (int x = 0; x < 4; ++x)
                            v = fmaf(u16[a * 4 + x], cwv[x * 4 + d], v);
                        votes[a * 4 + d] = v;
                    }
                float qk = 0.f;
                #pragma unroll
                for (int j = 0; j < 16; ++j) qk = fmaf(votes[j], nvp[s][j], qk);
                qk *= 0.25f;
                float e = __expf(fminf(qk, 60.f));
                float sm = e;
                #pragma unroll
                for (int off = 1; off < 32; off <<= 1) sm += __shfl_xor(sm, off);
                float qv = e * __builtin_amdgcn_rcpf(sm);
                #pragma unroll
                for (int j = 0; j < 16; ++j) nvacc[s][j] = fmaf(qv, votes[j], nvacc[s][j]);
            }
            wq0 = nq0; wq1 = nq1;
        }
    }

    #pragma unroll
    for (int s = 0; s < 2; ++s)
        #pragma unroll
        for (int j = 0; j < 16; ++j)
            nvacc[s][j] += __shfl_xor(nvacc[s][j], 32);
    #pragma unroll
    for (int s = 0; s < 2; ++s) {
        __syncthreads();
        if (half0) {
            #pragma unroll
            for (int j = 0; j < 16; ++j) wred[wid * 544 + lane * 17 + j] = nvacc[s][j];
        }
        __syncthreads();
        for (int o = threadIdx.x; o < 512; o += 256) {
            int mm = o >> 4, j = o & 15;
            float sum = wred[0 * 544 + mm * 17 + j] + wred[1 * 544 + mm * 17 + j]
                      + wred[2 * 544 + mm * 17 + j] + wred[3 * 544 + mm * 17 + j];
            v1s[s][o] = sum;
        }
    }
    __syncthreads();
    if (threadIdx.x < 64) {
        int s = threadIdx.x >> 5, m = threadIdx.x & 31;
        int b = bb + s * 32;
        float v16[16], mu = 0.f;
        #pragma unroll
        for (int j = 0; j < 16; ++j) { v16[j] = v1s[s][m * 16 + j]; mu += v16[j]; }
        mu *= (1.f / 16.f);
        float var = 0.f;
        #pragma unroll
        for (int j = 0; j < 16; ++j) { float t = v16[j] - mu; var += t * t; }
        var *= (1.f / 16.f);
        float rs = rsqrtf(var + EPSLN);
        float o16[16];
        #pragma unroll
        for (int j = 0; j < 16; ++j) o16[j] = (v16[j] - mu) * rs * g[j] + bt[j];
        float4* dst = (float4*)(vout + (((b * 32 + m) * 7 + h) * 7 + w) * 16);
        dst[0] = make_float4(o16[0],  o16[1],  o16[2],  o16[3]);
        dst[1] = make_float4(o16[4],  o16[5],  o16[6],  o16[7]);
        dst[2] = make_float4(o16[8],  o16[9],  o16[10], o16[11]);
        dst[3] = make_float4(o16[12], o16[13], o16[14], o16[15]);
    }
}

// ===================== merged fc (phase1 = uniform p + LN2, phase2 = routed + LN2) =====================
__global__ __launch_bounds__(1024) void k_fc(const float* __restrict__ fin,
                                             const float* __restrict__ fw,
                                             const float* __restrict__ g,
                                             const float* __restrict__ bt,
                                             float* __restrict__ out) {
    int b = blockIdx.x;
    int ad    = threadIdx.x & 15;
    int grpid = threadIdx.x >> 4;   // 0..63
    int a = ad >> 2, d = ad & 3;

    __shared__ float red[64][16][10];   // 40 KB (reused across phases)
    __shared__ float pLN[10][16];

    const float* fb = fin + b * 1568 * 16;

    // ---- phase 1: p = LN(sum votes / 10) ----
    float acc[10];
    #pragma unroll
    for (int m = 0; m < 10; ++m) acc[m] = 0.f;
    for (int n = grpid; n < 1568; n += 64) {
        float4 u4 = *(const float4*)(fb + n * 16 + a * 4);
        const float* wb = fw + n * 160 + d * 10;
        #pragma unroll
        for (int m = 0; m < 10; ++m)
            acc[m] += u4.x * wb[m] + u4.y * wb[40 + m] +
                      u4.z * wb[80 + m] + u4.w * wb[120 + m];
    }
    #pragma unroll
    for (int m = 0; m < 10; ++m) red[grpid][ad][m] = acc[m];
    __syncthreads();
    if (threadIdx.x < 160) {
        int m = threadIdx.x / 16, j = threadIdx.x % 16;
        float s = 0.f;
        for (int gg = 0; gg < 64; ++gg) s += red[gg][j][m];
        s *= 0.1f;                           // /M
        float mu = s;
        #pragma unroll
        for (int off = 1; off < 16; off <<= 1) mu += __shfl_xor(mu, off);
        mu *= (1.f / 16.f);
        float t = s - mu;
        float var = t * t;
        #pragma unroll
        for (int off = 1; off < 16; off <<= 1) var += __shfl_xor(var, off);
        var *= (1.f / 16.f);
        float rs = rsqrtf(var + EPSLN);
        pLN[m][j] = t * rs * g[j] + bt[j];
    }
    __syncthreads();

    // ---- phase 2: routed ----
    float pv[10];
    #pragma unroll
    for (int m = 0; m < 10; ++m) pv[m] = pLN[m][ad];
    #pragma unroll
    for (int m = 0; m < 10; ++m) acc[m] = 0.f;

    for (int n = grpid; n < 1568; n += 64) {
        float4 u4 = *(const float4*)(fb + n * 16 + a * 4);
        const float* wb = fw + n * 160 + d * 10;
        float votes[10];
        #pragma unroll
        for (int m = 0; m < 10; ++m)
            votes[m] = u4.x * wb[m] + u4.y * wb[40 + m] +
                       u4.z * wb[80 + m] + u4.w * wb[120 + m];
        float qk[10];
        #pragma unroll
        for (int m = 0; m < 10; ++m) {
            float t = votes[m] * pv[m];
            #pragma unroll
            for (int off = 1; off < 16; off <<= 1) t += __shfl_xor(t, off);
            qk[m] = t * 0.25f;
        }
        float mx = qk[0];
        #pragma unroll
        for (int m = 1; m < 10; ++m) mx = fmaxf(mx, qk[m]);
        float e[10], s = 0.f;
        #pragma unroll
        for (int m = 0; m < 10; ++m) { e[m] = __expf(qk[m] - mx); s += e[m]; }
        float inv = 1.f / s;
        #pragma unroll
        for (int m = 0; m < 10; ++m) acc[m] = fmaf(e[m] * inv, votes[m], acc[m]);
    }

    __syncthreads();   // all pLN reads done before red reuse
    #pragma unroll
    for (int m = 0; m < 10; ++m) red[grpid][ad][m] = acc[m];
    __syncthreads();

    if (threadIdx.x < 160) {
        int m = threadIdx.x / 16, j = threadIdx.x % 16;
        float s = 0.f;
        for (int gg = 0; gg < 64; ++gg) s += red[gg][j][m];
        float mu = s;
        #pragma unroll
        for (int off = 1; off < 16; off <<= 1) mu += __shfl_xor(mu, off);
        mu *= (1.f / 16.f);
        float t = s - mu;
        float var = t * t;
        #pragma unroll
        for (int off = 1; off < 16; off <<= 1) var += __shfl_xor(var, off);
        var *= (1.f / 16.f);
        float rs = rsqrtf(var + EPSLN);
        out[(b * 10 + m) * 16 + j] = t * rs * g[j] + bt[j];
    }
}

// ============================ launch ============================
extern "C" void kernel_launch(void* const* d_in, const int* in_sizes, int n_in,
                              void* d_out, int out_size, void* d_ws, size_t ws_size,
                              hipStream_t stream) {
    const float* x    = (const float*)d_in[0];
    const float* bbw  = (const float*)d_in[1];
    const float* bbb  = (const float*)d_in[2];
    const float* pcw  = (const float*)d_in[3];
    const float* ln0g = (const float*)d_in[4];
    const float* ln0b = (const float*)d_in[5];
    const float* cwt  = (const float*)d_in[6];
    const float* ln1g = (const float*)d_in[7];
    const float* ln1b = (const float*)d_in[8];
    const float* fw   = (const float*)d_in[9];
    const float* ln2g = (const float*)d_in[10];
    const float* ln2b = (const float*)d_in[11];
    float* outp = (float*)d_out;

    // Workspace layout (f32 units) -- verified R11
    float* ws = (float*)d_ws;
    __bf16* c2p  = (__bf16*)ws;                 // [0,          4,734,976)
    __bf16* wbT  = (__bf16*)(ws + 4734976);     // [4,734,976,  5,029,888)
    float*  bwT  = ws + 5029888;                // [5,029,888,  5,033,344)
    float*  val  = ws + 5033344;                // [5,033,344, 13,421,952)
    float*  v2   = ws + 13421952;               // [13,421,952, 15,027,584)
    float*  fwp  = ws + 15027584;               // [15,027,584, 15,278,464)
    __bf16* cw2  = (__bf16*)(ws + 15288704);    // [15,288,704, 15,362,432)
    __bf16* cwB  = (__bf16*)(ws + 15362432);    // [15,362,432, 15,436,160)
    float*  nv1g = ws + 15436160;               // [15,436,160, 17,041,792)

    hipMemsetAsync(c2p, 0, (size_t)9469952 * 2, stream);
    k_repack_all <<<4450, 256, 0, stream>>>(bbw, bwT, pcw, wbT, fw, fwp, cwt, cw2, cwB);
    k_conv1      <<<8192, 256, 0, stream>>>(x, bwT, bbb, c2p);
    k_conv2_mfma <<<1024, 256, 0, stream>>>(c2p, wbT, ln0g, ln0b, val);
    k_nv1_mfma   <<<196,  256, 0, stream>>>(val, cwB, nv1g);
    k_capsfused  <<<1568, 256, 0, stream>>>(val, cw2, nv1g, ln1g, ln1b, v2);
    k_fc         <<<64, 1024, 0, stream>>>(v2, fw, ln2g, ln2b, outp);
}

// Round 15
// 276.688 us; speedup vs baseline: 1.3145x; 1.3145x over previous
//
#include <hip/hip_runtime.h>

// CapsTimeModel forward, round 15: fc un-merged + n-split.
// R14 post-mortem: k_fc (merged) = 126us @ VALUBusy 6%, Occ 11% -- 64 blocks
// used 1/4 of CUs with 40-shuffle latency chains; old fc2 was ALREADY ~75us
// hidden below the top-5 cutoff. Fix: fc1 (R13, 640 blk) + fc2 split over
// 16 n-slices (1024 blk) -> partials -> tiny final reduce.
// conv2 keeps R14 global_load_lds (absmax-clean; will show in top-5 if bad).

#define EPSLN 1e-5f

typedef short  short8 __attribute__((ext_vector_type(8)));
typedef __bf16 bf16x8 __attribute__((ext_vector_type(8)));
typedef float  f32x4  __attribute__((ext_vector_type(4)));

union Frag { short8 s; bf16x8 b; };

__device__ __forceinline__ uint4 pack_bf16_8(float4 a, float4 b) {
    union { __bf16 h[8]; uint4 u; } r;
    r.h[0] = (__bf16)a.x; r.h[1] = (__bf16)a.y;
    r.h[2] = (__bf16)a.z; r.h[3] = (__bf16)a.w;
    r.h[4] = (__bf16)b.x; r.h[5] = (__bf16)b.y;
    r.h[6] = (__bf16)b.z; r.h[7] = (__bf16)b.w;
    return r.u;
}

__device__ __forceinline__ void gld16(const void* g, void* l) {
    __builtin_amdgcn_global_load_lds(
        (const __attribute__((address_space(1))) void*)g,
        (__attribute__((address_space(3))) void*)l, 16, 0, 0);
}

// ==================== fused repacks (blockIdx-range dispatch) ====================
__global__ __launch_bounds__(256) void k_repack_all(
        const float* __restrict__ bw,  float* __restrict__ bwT,
        const float* __restrict__ pw,  __bf16* __restrict__ wbT,
        const float* __restrict__ fw,  float* __restrict__ fwp,
        const float* __restrict__ cw,  __bf16* __restrict__ cw2,
        __bf16* __restrict__ cwB) {
    int blk = blockIdx.x;
    if (blk < 2304) {                         // pcw -> wbT : 589824 exact
        int i = blk * 256 + threadIdx.x;
        int oc = i / 1152, r = i % 1152;
        int ic = r / 9, tap = r % 9;
        wbT[oc * 1152 + tap * 128 + ic] = (__bf16)pw[i];
    } else if (blk < 3284) {                  // fw -> fwp : 250880 exact
        int i = (blk - 2304) * 256 + threadIdx.x;
        int m = i % 10;
        int d = (i / 10) & 3;
        int x = (i / 40) & 3;
        int n = i / 160;
        fwp[(m * 1568 + n) * 16 + x * 4 + d] = fw[i];
    } else if (blk < 3860) {                  // cw -> cw2 : 147456 exact
        int i = (blk - 3284) * 256 + threadIdx.x;
        int m  = i & 31;
        int d  = (i >> 5) & 3;
        int x  = (i >> 7) & 3;
        int n  = (i >> 9) & 31;
        int kl = i >> 14;
        cw2[(((kl * 32 + n) * 32) + m) * 16 + x * 4 + d] = (__bf16)cw[i];
    } else if (blk < 4436) {                  // cw -> cwB : 147456 exact
        int i = (blk - 3860) * 256 + threadIdx.x;
        int m  = i & 31;
        int d  = (i >> 5) & 3;
        int x  = (i >> 7) & 3;
        int n  = (i >> 9) & 31;
        int kl = i >> 14;
        cwB[(m * 4 + d) * 1152 + (n * 9 + kl) * 4 + x] = (__bf16)cw[i];
    } else {                                  // bw -> bwT : 3456
        int i = (blk - 4436) * 256 + threadIdx.x;
        if (i < 3456) {
            int oc = i / 27, r = i % 27;
            bwT[r * 128 + oc] = bw[i];
        }
    }
}

// ==================== conv1: x -> c2p (NHWC bf16, padded), 4 oc/thread ====================
__global__ __launch_bounds__(256) void k_conv1(const float* __restrict__ x,
                                               const float* __restrict__ bwT,
                                               const float* __restrict__ bb,
                                               __bf16* __restrict__ c2p) {
    int gid = blockIdx.x * 256 + threadIdx.x;     // 2,097,152
    int oc4 = gid & 31;
    int p   = gid >> 5;
    int w = p & 31, h = (p >> 5) & 31, b = p >> 10;
    const float* xb = x + b * 12288;
    float4 acc = *(const float4*)(bb + oc4 * 4);
    #pragma unroll
    for (int ky = 0; ky < 3; ++ky) {
        int ih = 2 * h + ky - 1;
        if ((unsigned)ih >= 64u) continue;
        #pragma unroll
        for (int kx = 0; kx < 3; ++kx) {
            int iw = 2 * w + kx - 1;
            if ((unsigned)iw >= 64u) continue;
            #pragma unroll
            for (int ic = 0; ic < 3; ++ic) {
                float in = xb[(ic * 64 + ih) * 64 + iw];
                float4 wv = *(const float4*)(bwT + (ic * 9 + ky * 3 + kx) * 128 + oc4 * 4);
                acc.x = fmaf(in, wv.x, acc.x);
                acc.y = fmaf(in, wv.y, acc.y);
                acc.z = fmaf(in, wv.z, acc.z);
                acc.w = fmaf(in, wv.w, acc.w);
            }
        }
    }
    union { __bf16 h4[4]; unsigned long long ull; } r;
    r.h4[0] = (__bf16)fmaxf(acc.x, 0.f);
    r.h4[1] = (__bf16)fmaxf(acc.y, 0.f);
    r.h4[2] = (__bf16)fmaxf(acc.z, 0.f);
    r.h4[3] = (__bf16)fmaxf(acc.w, 0.f);
    *(unsigned long long*)(c2p + ((b * 34 + h + 1) * 34 + (w + 1)) * 128 + oc4 * 4) = r.ull;
}

// ==================== conv2: global_load_lds dbuf MFMA GEMM + fused LN0 ====================
__global__ __launch_bounds__(256) void k_conv2_mfma(const __bf16* __restrict__ c2p,
                                                    const __bf16* __restrict__ wbT,
                                                    const float* __restrict__ g,
                                                    const float* __restrict__ bt,
                                                    float* __restrict__ val) {
    __shared__ unsigned short sA[2][128 * 32];
    __shared__ unsigned short sB[2][64 * 32];

    const int t = threadIdx.x;
    const int mblk = blockIdx.x >> 3, nblk = blockIdx.x & 7;
    const int pbase = mblk * 128, ocbase = nblk * 64;
    const int b = pbase >> 8;

    const int kc8 = (t & 3) * 8;
    const int r0 = t >> 2;
    const int oh0 = ((pbase + r0) >> 4) & 15, ow0 = (pbase + r0) & 15;
    const int oh1 = ((pbase + r0 + 64) >> 4) & 15, ow1 = (pbase + r0 + 64) & 15;

    const unsigned short* cb = (const unsigned short*)c2p + (size_t)b * 147968;
    const unsigned short* ws = (const unsigned short*)wbT
                               + (ocbase + (t >> 2)) * 1152 + kc8;

    const int lane = t & 63, wid = t >> 6;
    const int lo = lane & 15, hi = lane >> 4;

    f32x4 acc[2][4];
    #pragma unroll
    for (int fr = 0; fr < 2; ++fr)
        #pragma unroll
        for (int fc = 0; fc < 4; ++fc)
            acc[fr][fc] = (f32x4){0.f, 0.f, 0.f, 0.f};

    auto stage = [&](int buf, int ks) {
        int tap = ks / 4, ic0 = (ks % 4) * 32;
        int ty = tap / 3, tx = tap % 3;
        gld16(cb + ((2 * oh0 + ty) * 34 + (2 * ow0 + tx)) * 128 + ic0 + kc8,
              &sA[buf][(unsigned)t * 8]);
        gld16(cb + ((2 * oh1 + ty) * 34 + (2 * ow1 + tx)) * 128 + ic0 + kc8,
              &sA[buf][((unsigned)t + 256) * 8]);
        gld16(ws + ks * 32, &sB[buf][(unsigned)t * 8]);
    };

    stage(0, 0);
    __syncthreads();

    for (int ks = 0; ks < 36; ++ks) {
        const int cur = ks & 1;
        if (ks + 1 < 36) stage(cur ^ 1, ks + 1);
        Frag af0, af1, bf[4];
        af0.s = *(const short8*)&sA[cur][(wid * 32 + lo) * 32 + hi * 8];
        af1.s = *(const short8*)&sA[cur][(wid * 32 + 16 + lo) * 32 + hi * 8];
        #pragma unroll
        for (int fc = 0; fc < 4; ++fc)
            bf[fc].s = *(const short8*)&sB[cur][(fc * 16 + lo) * 32 + hi * 8];
        #pragma unroll
        for (int fc = 0; fc < 4; ++fc) {
            acc[0][fc] = __builtin_amdgcn_mfma_f32_16x16x32_bf16(
                af0.b, bf[fc].b, acc[0][fc], 0, 0, 0);
            acc[1][fc] = __builtin_amdgcn_mfma_f32_16x16x32_bf16(
                af1.b, bf[fc].b, acc[1][fc], 0, 0, 0);
        }
        __syncthreads();
    }

    const float gv = g[lo], bv = bt[lo];
    #pragma unroll
    for (int fr = 0; fr < 2; ++fr) {
        #pragma unroll
        for (int fc = 0; fc < 4; ++fc) {
            const int n = (ocbase >> 4) + fc;
            #pragma unroll
            for (int j = 0; j < 4; ++j) {
                float v = acc[fr][fc][j];
                float s1 = v, s2 = v * v;
                #pragma unroll
                for (int off = 1; off < 16; off <<= 1) {
                    s1 += __shfl_xor(s1, off);
                    s2 += __shfl_xor(s2, off);
                }
                float mu  = s1 * (1.f / 16.f);
                float var = s2 * (1.f / 16.f) - mu * mu;
                float rs  = rsqrtf(var + EPSLN);
                float o   = (v - mu) * rs * gv + bv;
                int p  = pbase + wid * 32 + fr * 16 + hi * 4 + j;
                int oh = (p >> 4) & 15, ow = p & 15;
                val[(((b * 32 + n) * 16 + oh) * 16 + ow) * 16 + lo] = o;
            }
        }
    }
}

// ==================== nv1 GEMM (pipelined, reg-staged): val x cwB -> nv1g ====================
__global__ __launch_bounds__(256) void k_nv1_mfma(const float* __restrict__ val,
                                                  const __bf16* __restrict__ cwB,
                                                  float* __restrict__ nv1g) {
    __shared__ unsigned short sA[128 * 32];
    __shared__ unsigned short sB[64 * 32];

    const int t = threadIdx.x;
    const int mblk = blockIdx.x >> 1, nblk = blockIdx.x & 1;
    const int pbase = mblk * 128, ocbase = nblk * 64;

    const float* vbase[2];
    #pragma unroll
    for (int u = 0; u < 2; ++u) {
        int r = pbase + (t >> 2) + u * 64;
        int site = r >> 2, a = r & 3;
        int b = site / 49, hw = site % 49;
        int h = hw / 7, w = hw % 7;
        vbase[u] = val + (size_t)b * 131072 + (2 * h) * 256 + (2 * w) * 16 + a * 4;
    }
    const unsigned short* wsrc = (const unsigned short*)cwB
                                 + (ocbase + (t >> 2)) * 1152 + (t & 3) * 8;

    const int lane = t & 63, wid = t >> 6;
    const int lo = lane & 15, hi = lane >> 4;

    f32x4 acc[2][4];
    #pragma unroll
    for (int fr = 0; fr < 2; ++fr)
        #pragma unroll
        for (int fc = 0; fc < 4; ++fc)
            acc[fr][fc] = (f32x4){0.f, 0.f, 0.f, 0.f};

    auto itemoff = [](int i) {
        int n = i / 9, kl = i % 9;
        return n * 4096 + (kl / 3) * 256 + (kl % 3) * 16;
    };

    {
        int i0 = (t & 3) * 2;
        int o0 = itemoff(i0), o1 = itemoff(i0 + 1);
        uint4 a0 = pack_bf16_8(*(const float4*)(vbase[0] + o0),
                               *(const float4*)(vbase[0] + o1));
        uint4 a1 = pack_bf16_8(*(const float4*)(vbase[1] + o0),
                               *(const float4*)(vbase[1] + o1));
        uint4 b0 = *(const uint4*)(wsrc);
        *(uint4*)&sA[(unsigned)t * 8]         = a0;
        *(uint4*)&sA[((unsigned)t + 256) * 8] = a1;
        *(uint4*)&sB[(unsigned)t * 8]         = b0;
        __syncthreads();
    }

    for (int ks = 0; ks < 36; ++ks) {
        uint4 a0, a1, b0;
        const bool pre = (ks + 1) < 36;
        if (pre) {
            int i0 = (ks + 1) * 8 + (t & 3) * 2;
            int o0 = itemoff(i0), o1 = itemoff(i0 + 1);
            a0 = pack_bf16_8(*(const float4*)(vbase[0] + o0),
                             *(const float4*)(vbase[0] + o1));
            a1 = pack_bf16_8(*(const float4*)(vbase[1] + o0),
                             *(const float4*)(vbase[1] + o1));
            b0 = *(const uint4*)(wsrc + (ks + 1) * 32);
        }
        Frag af0, af1, bf[4];
        af0.s = *(const short8*)&sA[(wid * 32 + lo) * 32 + hi * 8];
        af1.s = *(const short8*)&sA[(wid * 32 + 16 + lo) * 32 + hi * 8];
        #pragma unroll
        for (int fc = 0; fc < 4; ++fc)
            bf[fc].s = *(const short8*)&sB[(fc * 16 + lo) * 32 + hi * 8];
        #pragma unroll
        for (int fc = 0; fc < 4; ++fc) {
            acc[0][fc] = __builtin_amdgcn_mfma_f32_16x16x32_bf16(
                af0.b, bf[fc].b, acc[0][fc], 0, 0, 0);
            acc[1][fc] = __builtin_amdgcn_mfma_f32_16x16x32_bf16(
                af1.b, bf[fc].b, acc[1][fc], 0, 0, 0);
        }
        __syncthreads();
        if (pre) {
            *(uint4*)&sA[(unsigned)t * 8]         = a0;
            *(uint4*)&sA[((unsigned)t + 256) * 8] = a1;
            *(uint4*)&sB[(unsigned)t * 8]         = b0;
        }
        __syncthreads();
    }

    #pragma unroll
    for (int fr = 0; fr < 2; ++fr)
        #pragma unroll
        for (int fc = 0; fc < 4; ++fc)
            #pragma unroll
            for (int j = 0; j < 4; ++j) {
                int row = pbase + wid * 32 + fr * 16 + hi * 4 + j;
                int col = ocbase + fc * 16 + lo;
                nv1g[row * 128 + col] = acc[fr][fc][j];
            }
}

// ===================== caps routing pass 2 + LN1 =====================
__global__ __launch_bounds__(256) void k_capsfused(const float* __restrict__ val,
                                                   const __bf16* __restrict__ cw2,
                                                   const float* __restrict__ nv1g,
                                                   const float* __restrict__ g,
                                                   const float* __restrict__ bt,
                                                   float* __restrict__ vout) {
    int bb = blockIdx.x / 49;
    int hw = blockIdx.x % 49;
    int h = hw / 7, w = hw % 7;

    __shared__ float4 uloc4[2][1152];
    __shared__ float  v1s[2][512];
    float* wred = (float*)uloc4;

    for (int t = threadIdx.x; t < 2304; t += 256) {
        int s  = t >= 1152;
        int tt = t - s * 1152;
        int f  = tt & 3;
        int kl = (tt >> 2) % 9;
        int n  = tt / 36;
        int k = kl / 3, l = kl % 3;
        int b = bb + s * 32;
        uloc4[s][tt] = *(const float4*)(val +
            (((b * 32 + n) * 16 + (2 * h + k)) * 16 + (2 * w + l)) * 16 + f * 4);
    }

    const int lane  = threadIdx.x & 31;
    const int grpid = threadIdx.x >> 5;
    const int wid   = threadIdx.x >> 6;
    const bool half0 = (threadIdx.x & 32) == 0;

    float nvp[2][16];
    #pragma unroll
    for (int s = 0; s < 2; ++s) {
        int site = (bb + s * 32) * 49 + hw;
        #pragma unroll
        for (int a = 0; a < 4; ++a) {
            float4 q = *(const float4*)(nv1g + (site * 4 + a) * 128 + lane * 4);
            nvp[s][a * 4 + 0] = q.x * (1.f / 32.f);
            nvp[s][a * 4 + 1] = q.y * (1.f / 32.f);
            nvp[s][a * 4 + 2] = q.z * (1.f / 32.f);
            nvp[s][a * 4 + 3] = q.w * (1.f / 32.f);
        }
        float mu = 0.f;
        #pragma unroll
        for (int j = 0; j < 16; ++j) mu += nvp[s][j];
        mu *= (1.f / 16.f);
        float var = 0.f;
        #pragma unroll
        for (int j = 0; j < 16; ++j) { float d = nvp[s][j] - mu; var += d * d; }
        var *= (1.f / 16.f);
        float rs = rsqrtf(var + EPSLN);
        #pragma unroll
        for (int j = 0; j < 16; ++j)
            nvp[s][j] = (nvp[s][j] - mu) * rs * g[j] + bt[j];
    }

    float nvacc[2][16];
    #pragma unroll
    for (int s = 0; s < 2; ++s)
        #pragma unroll
        for (int j = 0; j < 16; ++j) nvacc[s][j] = 0.f;

    __syncthreads();

    {
        uint4 wq0, wq1;
        {
            int n = grpid / 9, kl = grpid % 9;
            const uint4* wb = (const uint4*)(cw2 + (((kl * 32 + n) * 32) + lane) * 16);
            wq0 = wb[0]; wq1 = wb[1];
        }
        for (int it = grpid; it < 288; it += 8) {
            int nit = it + 8;
            uint4 nq0 = wq0, nq1 = wq1;
            if (nit < 288) {
                int n = nit / 9, kl = nit % 9;
                const uint4* wb = (const uint4*)(cw2 + (((kl * 32 + n) * 32) + lane) * 16);
                nq0 = wb[0]; nq1 = wb[1];
            }
            float cwv[16];
            {
                union { uint4 u; __bf16 hh[8]; } qa, qb;
                qa.u = wq0; qb.u = wq1;
                #pragma unroll
                for (int j = 0; j < 8; ++j) {
                    cwv[j] = (float)qa.hh[j]; cwv[8 + j] = (float)qb.hh[j];
                }
            }
            #pragma unroll
            for (int s = 0; s < 2; ++s) {
                float u16[16];
                #pragma unroll
                for (int f = 0; f < 4; ++f) {
                    float4 t4 = uloc4[s][it * 4 + f];
                    u16[f * 4 + 0] = t4.x; u16[f * 4 + 1] = t4.y;
                    u16[f * 4 + 2] = t4.z; u16[f * 4 + 3] = t4.w;
                }
                float votes[16];
                #pragma unroll
                for (int a = 0; a < 4; ++a)
                    #pragma unroll
                    for (int d = 0; d < 4; ++d) {
                        float v = 0.f;
                        #pragma unroll
                        for (int x = 0; x < 4; ++x)
                            v = fmaf(u16[a * 4 + x], cwv[x * 4 + d], v);
                        votes[a * 4 + d] = v;
                    }
                float qk = 0.f;
                #pragma unroll
                for (int j = 0; j < 16; ++j) qk = fmaf(votes[j], nvp[s][j], qk);
                qk *= 0.25f;
                float e = __expf(fminf(qk, 60.f));
                float sm = e;
                #pragma unroll
                for (int off = 1; off < 32; off <<= 1) sm += __shfl_xor(sm, off);
                float qv = e * __builtin_amdgcn_rcpf(sm);
                #pragma unroll
                for (int j = 0; j < 16; ++j) nvacc[s][j] = fmaf(qv, votes[j], nvacc[s][j]);
            }
            wq0 = nq0; wq1 = nq1;
        }
    }

    #pragma unroll
    for (int s = 0; s < 2; ++s)
        #pragma unroll
        for (int j = 0; j < 16; ++j)
            nvacc[s][j] += __shfl_xor(nvacc[s][j], 32);
    #pragma unroll
    for (int s = 0; s < 2; ++s) {
        __syncthreads();
        if (half0) {
            #pragma unroll
            for (int j = 0; j < 16; ++j) wred[wid * 544 + lane * 17 + j] = nvacc[s][j];
        }
        __syncthreads();
        for (int o = threadIdx.x; o < 512; o += 256) {
            int mm = o >> 4, j = o & 15;
            float sum = wred[0 * 544 + mm * 17 + j] + wred[1 * 544 + mm * 17 + j]
                      + wred[2 * 544 + mm * 17 + j] + wred[3 * 544 + mm * 17 + j];
            v1s[s][o] = sum;
        }
    }
    __syncthreads();
    if (threadIdx.x < 64) {
        int s = threadIdx.x >> 5, m = threadIdx.x & 31;
        int b = bb + s * 32;
        float v16[16], mu = 0.f;
        #pragma unroll
        for (int j = 0; j < 16; ++j) { v16[j] = v1s[s][m * 16 + j]; mu += v16[j]; }
        mu *= (1.f / 16.f);
        float var = 0.f;
        #pragma unroll
        for (int j = 0; j < 16; ++j) { float t = v16[j] - mu; var += t * t; }
        var *= (1.f / 16.f);
        float rs = rsqrtf(var + EPSLN);
        float o16[16];
        #pragma unroll
        for (int j = 0; j < 16; ++j) o16[j] = (v16[j] - mu) * rs * g[j] + bt[j];
        float4* dst = (float4*)(vout + (((b * 32 + m) * 7 + h) * 7 + w) * 16);
        dst[0] = make_float4(o16[0],  o16[1],  o16[2],  o16[3]);
        dst[1] = make_float4(o16[4],  o16[5],  o16[6],  o16[7]);
        dst[2] = make_float4(o16[8],  o16[9],  o16[10], o16[11]);
        dst[3] = make_float4(o16[12], o16[13], o16[14], o16[15]);
    }
}

// ===================== fc step1 + LN2: v2 -> p =====================
__global__ __launch_bounds__(256) void k_fc1(const float* __restrict__ fin,
                                             const float* __restrict__ fwp,
                                             const float* __restrict__ g,
                                             const float* __restrict__ bt,
                                             float* __restrict__ p) {
    int b = blockIdx.x / 10, m = blockIdx.x % 10;
    const float* fb = fin + b * 1568 * 16;
    const float* wb = fwp + m * 1568 * 16;
    float acc[16];
    #pragma unroll
    for (int j = 0; j < 16; ++j) acc[j] = 0.f;

    for (int n = threadIdx.x; n < 1568; n += 256) {
        const float4* u4 = (const float4*)(fb + n * 16);
        const float4* w4 = (const float4*)(wb + n * 16);
        float u16[16], w16[16];
        #pragma unroll
        for (int f = 0; f < 4; ++f) {
            float4 a = u4[f], bq = w4[f];
            u16[f * 4 + 0] = a.x;  u16[f * 4 + 1] = a.y;
            u16[f * 4 + 2] = a.z;  u16[f * 4 + 3] = a.w;
            w16[f * 4 + 0] = bq.x; w16[f * 4 + 1] = bq.y;
            w16[f * 4 + 2] = bq.z; w16[f * 4 + 3] = bq.w;
        }
        #pragma unroll
        for (int a = 0; a < 4; ++a)
            #pragma unroll
            for (int d = 0; d < 4; ++d) {
                float s = acc[a * 4 + d];
                #pragma unroll
                for (int x = 0; x < 4; ++x)
                    s = fmaf(u16[a * 4 + x], w16[x * 4 + d], s);
                acc[a * 4 + d] = s;
            }
    }
    #pragma unroll
    for (int j = 0; j < 16; ++j)
        #pragma unroll
        for (int off = 1; off < 64; off <<= 1)
            acc[j] += __shfl_xor(acc[j], off);

    __shared__ float red[4][16];
    int wid = threadIdx.x >> 6, ln = threadIdx.x & 63;
    if (ln == 0) {
        #pragma unroll
        for (int j = 0; j < 16; ++j) red[wid][j] = acc[j];
    }
    __syncthreads();
    if (threadIdx.x < 16) {
        int j = threadIdx.x;
        float s = (red[0][j] + red[1][j] + red[2][j] + red[3][j]) * 0.1f;
        float mu = s;
        #pragma unroll
        for (int off = 1; off < 16; off <<= 1) mu += __shfl_xor(mu, off);
        mu *= (1.f / 16.f);
        float t = s - mu;
        float var = t * t;
        #pragma unroll
        for (int off = 1; off < 16; off <<= 1) var += __shfl_xor(var, off);
        var *= (1.f / 16.f);
        float rs = rsqrtf(var + EPSLN);
        p[(b * 10 + m) * 16 + j] = t * rs * g[j] + bt[j];
    }
}

// ===================== fc routing, n-split partials: v2,p -> part =====================
// 1024 blocks = 64 b x 16 slices (98 n each); 16 groups of 16 lanes per block.
__global__ __launch_bounds__(256) void k_fc2_part(const float* __restrict__ fin,
                                                  const float* __restrict__ fw,
                                                  const float* __restrict__ p,
                                                  float* __restrict__ part) {
    int b = blockIdx.x >> 4, slice = blockIdx.x & 15;
    int ad    = threadIdx.x & 15;
    int grpid = threadIdx.x >> 4;   // 0..15
    int a = ad >> 2, d = ad & 3;

    float pv[10];
    #pragma unroll
    for (int m = 0; m < 10; ++m) pv[m] = p[(b * 10 + m) * 16 + ad];

    float acc[10];
    #pragma unroll
    for (int m = 0; m < 10; ++m) acc[m] = 0.f;

    const float* fb = fin + b * 1568 * 16;
    int nbase = slice * 98;
    for (int n = nbase + grpid; n < nbase + 98; n += 16) {
        float4 u4 = *(const float4*)(fb + n * 16 + a * 4);
        const float* wb = fw + n * 160 + d * 10;
        float votes[10];
        #pragma unroll
        for (int m = 0; m < 10; ++m)
            votes[m] = u4.x * wb[m] + u4.y * wb[40 + m] +
                       u4.z * wb[80 + m] + u4.w * wb[120 + m];
        float qk[10];
        #pragma unroll
        for (int m = 0; m < 10; ++m) {
            float t = votes[m] * pv[m];
            #pragma unroll
            for (int off = 1; off < 16; off <<= 1) t += __shfl_xor(t, off);
            qk[m] = t * 0.25f;
        }
        float mx = qk[0];
        #pragma unroll
        for (int m = 1; m < 10; ++m) mx = fmaxf(mx, qk[m]);
        float e[10], s = 0.f;
        #pragma unroll
        for (int m = 0; m < 10; ++m) { e[m] = __expf(qk[m] - mx); s += e[m]; }
        float inv = 1.f / s;
        #pragma unroll
        for (int m = 0; m < 10; ++m) acc[m] = fmaf(e[m] * inv, votes[m], acc[m]);
    }

    __shared__ float red[16][16][10];   // 10 KB
    #pragma unroll
    for (int m = 0; m < 10; ++m) red[grpid][ad][m] = acc[m];
    __syncthreads();

    if (threadIdx.x < 160) {
        int m = threadIdx.x / 16, j = threadIdx.x % 16;
        float s = 0.f;
        #pragma unroll
        for (int gg = 0; gg < 16; ++gg) s += red[gg][j][m];
        part[(b * 16 + slice) * 160 + m * 16 + j] = s;
    }
}

// ===================== fc final: reduce slices + LN2 -> out =====================
__global__ __launch_bounds__(256) void k_fc2_fin(const float* __restrict__ part,
                                                 const float* __restrict__ g,
                                                 const float* __restrict__ bt,
                                                 float* __restrict__ out) {
    int b = blockIdx.x;
    if (threadIdx.x >= 160) return;
    int m = threadIdx.x / 16, j = threadIdx.x % 16;
    float s = 0.f;
    #pragma unroll
    for (int sl = 0; sl < 16; ++sl)
        s += part[(b * 16 + sl) * 160 + m * 16 + j];
    float mu = s;
    #pragma unroll
    for (int off = 1; off < 16; off <<= 1) mu += __shfl_xor(mu, off);
    mu *= (1.f / 16.f);
    float t = s - mu;
    float var = t * t;
    #pragma unroll
    for (int off = 1; off < 16; off <<= 1) var += __shfl_xor(var, off);
    var *= (1.f / 16.f);
    float rs = rsqrtf(var + EPSLN);
    out[(b * 10 + m) * 16 + j] = t * rs * g[j] + bt[j];
}

// ============================ launch ============================
extern "C" void kernel_launch(void* const* d_in, const int* in_sizes, int n_in,
                              void* d_out, int out_size, void* d_ws, size_t ws_size,
                              hipStream_t stream) {
    const float* x    = (const float*)d_in[0];
    const float* bbw  = (const float*)d_in[1];
    const float* bbb  = (const float*)d_in[2];
    const float* pcw  = (const float*)d_in[3];
    const float* ln0g = (const float*)d_in[4];
    const float* ln0b = (const float*)d_in[5];
    const float* cwt  = (const float*)d_in[6];
    const float* ln1g = (const float*)d_in[7];
    const float* ln1b = (const float*)d_in[8];
    const float* fw   = (const float*)d_in[9];
    const float* ln2g = (const float*)d_in[10];
    const float* ln2b = (const float*)d_in[11];
    float* outp = (float*)d_out;

    // Workspace layout (f32 units) -- verified R11; part aliases val (dead by fc)
    float* ws = (float*)d_ws;
    __bf16* c2p  = (__bf16*)ws;                 // [0,          4,734,976)
    __bf16* wbT  = (__bf16*)(ws + 4734976);     // [4,734,976,  5,029,888)
    float*  bwT  = ws + 5029888;                // [5,029,888,  5,033,344)
    float*  val  = ws + 5033344;                // [5,033,344, 13,421,952)
    float*  v2   = ws + 13421952;               // [13,421,952, 15,027,584)
    float*  fwp  = ws + 15027584;               // [15,027,584, 15,278,464)
    float*  p    = ws + 15278464;               // [15,278,464, 15,288,704)
    __bf16* cw2  = (__bf16*)(ws + 15288704);    // [15,288,704, 15,362,432)
    __bf16* cwB  = (__bf16*)(ws + 15362432);    // [15,362,432, 15,436,160)
    float*  nv1g = ws + 15436160;               // [15,436,160, 17,041,792)
    float*  part = val;                         // 163,840 <= 8,388,608 (val dead)

    hipMemsetAsync(c2p, 0, (size_t)9469952 * 2, stream);
    k_repack_all <<<4450, 256, 0, stream>>>(bbw, bwT, pcw, wbT, fw, fwp, cwt, cw2, cwB);
    k_conv1      <<<8192, 256, 0, stream>>>(x, bwT, bbb, c2p);
    k_conv2_mfma <<<1024, 256, 0, stream>>>(c2p, wbT, ln0g, ln0b, val);
    k_nv1_mfma   <<<196,  256, 0, stream>>>(val, cwB, nv1g);
    k_capsfused  <<<1568, 256, 0, stream>>>(val, cw2, nv1g, ln1g, ln1b, v2);
    k_fc1        <<<640, 256, 0, stream>>>(v2, fwp, ln2g, ln2b, p);
    k_fc2_part   <<<1024, 256, 0, stream>>>(v2, fw, p, part);
    k_fc2_fin    <<<64, 256, 0, stream>>>(part, ln2g, ln2b, outp);
}

// Round 16
// 246.111 us; speedup vs baseline: 1.4778x; 1.1242x over previous
//
#include <hip/hip_runtime.h>

// CapsTimeModel forward, round 16:
//   - conv1: LDS-staged x window (block = (b,h) row; 27 scattered loads/pixel
//     -> shared 2.4KB LDS tile) + weights in registers
//   - nv1: BM=64 -> 392 blocks (was 196 on 256 CUs; machine underfilled)
//   - capsfused: XCD-aware blockIdx swizzle (1568 % 8 == 0, bijective)
// conv2 / fc path / repacks identical to R15 (passing, 277us).

#define EPSLN 1e-5f

typedef short  short8 __attribute__((ext_vector_type(8)));
typedef __bf16 bf16x8 __attribute__((ext_vector_type(8)));
typedef float  f32x4  __attribute__((ext_vector_type(4)));

union Frag { short8 s; bf16x8 b; };

__device__ __forceinline__ uint4 pack_bf16_8(float4 a, float4 b) {
    union { __bf16 h[8]; uint4 u; } r;
    r.h[0] = (__bf16)a.x; r.h[1] = (__bf16)a.y;
    r.h[2] = (__bf16)a.z; r.h[3] = (__bf16)a.w;
    r.h[4] = (__bf16)b.x; r.h[5] = (__bf16)b.y;
    r.h[6] = (__bf16)b.z; r.h[7] = (__bf16)b.w;
    return r.u;
}

__device__ __forceinline__ void gld16(const void* g, void* l) {
    __builtin_amdgcn_global_load_lds(
        (const __attribute__((address_space(1))) void*)g,
        (__attribute__((address_space(3))) void*)l, 16, 0, 0);
}

// ==================== fused repacks (blockIdx-range dispatch) ====================
__global__ __launch_bounds__(256) void k_repack_all(
        const float* __restrict__ bw,  float* __restrict__ bwT,
        const float* __restrict__ pw,  __bf16* __restrict__ wbT,
        const float* __restrict__ fw,  float* __restrict__ fwp,
        const float* __restrict__ cw,  __bf16* __restrict__ cw2,
        __bf16* __restrict__ cwB) {
    int blk = blockIdx.x;
    if (blk < 2304) {                         // pcw -> wbT : 589824 exact
        int i = blk * 256 + threadIdx.x;
        int oc = i / 1152, r = i % 1152;
        int ic = r / 9, tap = r % 9;
        wbT[oc * 1152 + tap * 128 + ic] = (__bf16)pw[i];
    } else if (blk < 3284) {                  // fw -> fwp : 250880 exact
        int i = (blk - 2304) * 256 + threadIdx.x;
        int m = i % 10;
        int d = (i / 10) & 3;
        int x = (i / 40) & 3;
        int n = i / 160;
        fwp[(m * 1568 + n) * 16 + x * 4 + d] = fw[i];
    } else if (blk < 3860) {                  // cw -> cw2 : 147456 exact
        int i = (blk - 3284) * 256 + threadIdx.x;
        int m  = i & 31;
        int d  = (i >> 5) & 3;
        int x  = (i >> 7) & 3;
        int n  = (i >> 9) & 31;
        int kl = i >> 14;
        cw2[(((kl * 32 + n) * 32) + m) * 16 + x * 4 + d] = (__bf16)cw[i];
    } else if (blk < 4436) {                  // cw -> cwB : 147456 exact
        int i = (blk - 3860) * 256 + threadIdx.x;
        int m  = i & 31;
        int d  = (i >> 5) & 3;
        int x  = (i >> 7) & 3;
        int n  = (i >> 9) & 31;
        int kl = i >> 14;
        cwB[(m * 4 + d) * 1152 + (n * 9 + kl) * 4 + x] = (__bf16)cw[i];
    } else {                                  // bw -> bwT : 3456
        int i = (blk - 4436) * 256 + threadIdx.x;
        if (i < 3456) {
            int oc = i / 27, r = i % 27;
            bwT[r * 128 + oc] = bw[i];
        }
    }
}

// ==================== conv1 (LDS-staged): x -> c2p (NHWC bf16, padded) ====================
// Block = (b, h): stage x rows 2h-1..2h+1, iw -1..64 (zero-padded) in LDS.
// Thread = (wq 0..7, oc4 0..31); each computes w = wq, wq+8, wq+16, wq+24.
__global__ __launch_bounds__(256) void k_conv1(const float* __restrict__ x,
                                               const float* __restrict__ bwT,
                                               const float* __restrict__ bb,
                                               __bf16* __restrict__ c2p) {
    __shared__ float xs[3][3][66];     // [ic][row][iw+1], 2376 B

    int b = blockIdx.x >> 5, h = blockIdx.x & 31;
    for (int i = threadIdx.x; i < 594; i += 256) {
        int iw = i % 66;
        int r  = (i / 66) % 3;
        int ic = i / 198;
        int ih  = 2 * h + r - 1;
        int riw = iw - 1;
        float v = 0.f;
        if ((unsigned)ih < 64u && (unsigned)riw < 64u)
            v = x[((b * 3 + ic) * 64 + ih) * 64 + riw];
        xs[ic][r][iw] = v;
    }
    __syncthreads();

    int oc4 = threadIdx.x & 31, wq = threadIdx.x >> 5;
    float4 wv[27];
    #pragma unroll
    for (int r = 0; r < 27; ++r)
        wv[r] = *(const float4*)(bwT + r * 128 + oc4 * 4);
    float4 bias = *(const float4*)(bb + oc4 * 4);

    #pragma unroll
    for (int q = 0; q < 4; ++q) {
        int w = wq + q * 8;
        float4 acc = bias;
        #pragma unroll
        for (int ky = 0; ky < 3; ++ky)
            #pragma unroll
            for (int kx = 0; kx < 3; ++kx)
                #pragma unroll
                for (int ic = 0; ic < 3; ++ic) {
                    float in = xs[ic][ky][2 * w + kx];   // iw = 2w+kx-1, +1 pad
                    float4 ww = wv[ic * 9 + ky * 3 + kx];
                    acc.x = fmaf(in, ww.x, acc.x);
                    acc.y = fmaf(in, ww.y, acc.y);
                    acc.z = fmaf(in, ww.z, acc.z);
                    acc.w = fmaf(in, ww.w, acc.w);
                }
        union { __bf16 h4[4]; unsigned long long ull; } r;
        r.h4[0] = (__bf16)fmaxf(acc.x, 0.f);
        r.h4[1] = (__bf16)fmaxf(acc.y, 0.f);
        r.h4[2] = (__bf16)fmaxf(acc.z, 0.f);
        r.h4[3] = (__bf16)fmaxf(acc.w, 0.f);
        *(unsigned long long*)(c2p + ((b * 34 + h + 1) * 34 + (w + 1)) * 128 + oc4 * 4)
            = r.ull;
    }
}

// ==================== conv2: global_load_lds dbuf MFMA GEMM + fused LN0 ====================
__global__ __launch_bounds__(256) void k_conv2_mfma(const __bf16* __restrict__ c2p,
                                                    const __bf16* __restrict__ wbT,
                                                    const float* __restrict__ g,
                                                    const float* __restrict__ bt,
                                                    float* __restrict__ val) {
    __shared__ unsigned short sA[2][128 * 32];
    __shared__ unsigned short sB[2][64 * 32];

    const int t = threadIdx.x;
    const int mblk = blockIdx.x >> 3, nblk = blockIdx.x & 7;
    const int pbase = mblk * 128, ocbase = nblk * 64;
    const int b = pbase >> 8;

    const int kc8 = (t & 3) * 8;
    const int r0 = t >> 2;
    const int oh0 = ((pbase + r0) >> 4) & 15, ow0 = (pbase + r0) & 15;
    const int oh1 = ((pbase + r0 + 64) >> 4) & 15, ow1 = (pbase + r0 + 64) & 15;

    const unsigned short* cb = (const unsigned short*)c2p + (size_t)b * 147968;
    const unsigned short* ws = (const unsigned short*)wbT
                               + (ocbase + (t >> 2)) * 1152 + kc8;

    const int lane = t & 63, wid = t >> 6;
    const int lo = lane & 15, hi = lane >> 4;

    f32x4 acc[2][4];
    #pragma unroll
    for (int fr = 0; fr < 2; ++fr)
        #pragma unroll
        for (int fc = 0; fc < 4; ++fc)
            acc[fr][fc] = (f32x4){0.f, 0.f, 0.f, 0.f};

    auto stage = [&](int buf, int ks) {
        int tap = ks / 4, ic0 = (ks % 4) * 32;
        int ty = tap / 3, tx = tap % 3;
        gld16(cb + ((2 * oh0 + ty) * 34 + (2 * ow0 + tx)) * 128 + ic0 + kc8,
              &sA[buf][(unsigned)t * 8]);
        gld16(cb + ((2 * oh1 + ty) * 34 + (2 * ow1 + tx)) * 128 + ic0 + kc8,
              &sA[buf][((unsigned)t + 256) * 8]);
        gld16(ws + ks * 32, &sB[buf][(unsigned)t * 8]);
    };

    stage(0, 0);
    __syncthreads();

    for (int ks = 0; ks < 36; ++ks) {
        const int cur = ks & 1;
        if (ks + 1 < 36) stage(cur ^ 1, ks + 1);
        Frag af0, af1, bf[4];
        af0.s = *(const short8*)&sA[cur][(wid * 32 + lo) * 32 + hi * 8];
        af1.s = *(const short8*)&sA[cur][(wid * 32 + 16 + lo) * 32 + hi * 8];
        #pragma unroll
        for (int fc = 0; fc < 4; ++fc)
            bf[fc].s = *(const short8*)&sB[cur][(fc * 16 + lo) * 32 + hi * 8];
        #pragma unroll
        for (int fc = 0; fc < 4; ++fc) {
            acc[0][fc] = __builtin_amdgcn_mfma_f32_16x16x32_bf16(
                af0.b, bf[fc].b, acc[0][fc], 0, 0, 0);
            acc[1][fc] = __builtin_amdgcn_mfma_f32_16x16x32_bf16(
                af1.b, bf[fc].b, acc[1][fc], 0, 0, 0);
        }
        __syncthreads();
    }

    const float gv = g[lo], bv = bt[lo];
    #pragma unroll
    for (int fr = 0; fr < 2; ++fr) {
        #pragma unroll
        for (int fc = 0; fc < 4; ++fc) {
            const int n = (ocbase >> 4) + fc;
            #pragma unroll
            for (int j = 0; j < 4; ++j) {
                float v = acc[fr][fc][j];
                float s1 = v, s2 = v * v;
                #pragma unroll
                for (int off = 1; off < 16; off <<= 1) {
                    s1 += __shfl_xor(s1, off);
                    s2 += __shfl_xor(s2, off);
                }
                float mu  = s1 * (1.f / 16.f);
                float var = s2 * (1.f / 16.f) - mu * mu;
                float rs  = rsqrtf(var + EPSLN);
                float o   = (v - mu) * rs * gv + bv;
                int p  = pbase + wid * 32 + fr * 16 + hi * 4 + j;
                int oh = (p >> 4) & 15, ow = p & 15;
                val[(((b * 32 + n) * 16 + oh) * 16 + ow) * 16 + lo] = o;
            }
        }
    }
}

// ==================== nv1 GEMM (BM=64, pipelined): val x cwB -> nv1g ====================
__global__ __launch_bounds__(256) void k_nv1_mfma(const float* __restrict__ val,
                                                  const __bf16* __restrict__ cwB,
                                                  float* __restrict__ nv1g) {
    __shared__ unsigned short sA[64 * 32];
    __shared__ unsigned short sB[64 * 32];

    const int t = threadIdx.x;
    const int mblk = blockIdx.x >> 1, nblk = blockIdx.x & 1;   // 392 blocks
    const int pbase = mblk * 64, ocbase = nblk * 64;

    const float* vbase;
    {
        int r = pbase + (t >> 2);
        int site = r >> 2, a = r & 3;
        int b = site / 49, hw = site % 49;
        int h = hw / 7, w = hw % 7;
        vbase = val + (size_t)b * 131072 + (2 * h) * 256 + (2 * w) * 16 + a * 4;
    }
    const unsigned short* wsrc = (const unsigned short*)cwB
                                 + (ocbase + (t >> 2)) * 1152 + (t & 3) * 8;

    const int lane = t & 63, wid = t >> 6;
    const int lo = lane & 15, hi = lane >> 4;

    f32x4 acc[4];
    #pragma unroll
    for (int fc = 0; fc < 4; ++fc)
        acc[fc] = (f32x4){0.f, 0.f, 0.f, 0.f};

    auto itemoff = [](int i) {
        int n = i / 9, kl = i % 9;
        return n * 4096 + (kl / 3) * 256 + (kl % 3) * 16;
    };

    {
        int i0 = (t & 3) * 2;
        int o0 = itemoff(i0), o1 = itemoff(i0 + 1);
        uint4 a0 = pack_bf16_8(*(const float4*)(vbase + o0),
                               *(const float4*)(vbase + o1));
        uint4 b0 = *(const uint4*)(wsrc);
        *(uint4*)&sA[(unsigned)t * 8] = a0;
        *(uint4*)&sB[(unsigned)t * 8] = b0;
        __syncthreads();
    }

    for (int ks = 0; ks < 36; ++ks) {
        uint4 a0, b0;
        const bool pre = (ks + 1) < 36;
        if (pre) {
            int i0 = (ks + 1) * 8 + (t & 3) * 2;
            int o0 = itemoff(i0), o1 = itemoff(i0 + 1);
            a0 = pack_bf16_8(*(const float4*)(vbase + o0),
                             *(const float4*)(vbase + o1));
            b0 = *(const uint4*)(wsrc + (ks + 1) * 32);
        }
        Frag af, bf[4];
        af.s = *(const short8*)&sA[(wid * 16 + lo) * 32 + hi * 8];
        #pragma unroll
        for (int fc = 0; fc < 4; ++fc)
            bf[fc].s = *(const short8*)&sB[(fc * 16 + lo) * 32 + hi * 8];
        #pragma unroll
        for (int fc = 0; fc < 4; ++fc)
            acc[fc] = __builtin_amdgcn_mfma_f32_16x16x32_bf16(
                af.b, bf[fc].b, acc[fc], 0, 0, 0);
        __syncthreads();
        if (pre) {
            *(uint4*)&sA[(unsigned)t * 8] = a0;
            *(uint4*)&sB[(unsigned)t * 8] = b0;
        }
        __syncthreads();
    }

    #pragma unroll
    for (int fc = 0; fc < 4; ++fc)
        #pragma unroll
        for (int j = 0; j < 4; ++j) {
            int row = pbase + wid * 16 + hi * 4 + j;
            int col = ocbase + fc * 16 + lo;
            nv1g[row * 128 + col] = acc[fc][j];
        }
}

// ===================== caps routing pass 2 + LN1 (XCD-swizzled) =====================
__global__ __launch_bounds__(256) void k_capsfused(const float* __restrict__ val,
                                                   const __bf16* __restrict__ cw2,
                                                   const float* __restrict__ nv1g,
                                                   const float* __restrict__ g,
                                                   const float* __restrict__ bt,
                                                   float* __restrict__ vout) {
    // XCD swizzle: 1568 blocks, 8 XCDs, 196 per chunk (bijective)
    int swz = (blockIdx.x & 7) * 196 + (blockIdx.x >> 3);
    int bb = swz / 49;
    int hw = swz % 49;
    int h = hw / 7, w = hw % 7;

    __shared__ float4 uloc4[2][1152];
    __shared__ float  v1s[2][512];
    float* wred = (float*)uloc4;

    for (int t = threadIdx.x; t < 2304; t += 256) {
        int s  = t >= 1152;
        int tt = t - s * 1152;
        int f  = tt & 3;
        int kl = (tt >> 2) % 9;
        int n  = tt / 36;
        int k = kl / 3, l = kl % 3;
        int b = bb + s * 32;
        uloc4[s][tt] = *(const float4*)(val +
            (((b * 32 + n) * 16 + (2 * h + k)) * 16 + (2 * w + l)) * 16 + f * 4);
    }

    const int lane  = threadIdx.x & 31;
    const int grpid = threadIdx.x >> 5;
    const int wid   = threadIdx.x >> 6;
    const bool half0 = (threadIdx.x & 32) == 0;

    float nvp[2][16];
    #pragma unroll
    for (int s = 0; s < 2; ++s) {
        int site = (bb + s * 32) * 49 + hw;
        #pragma unroll
        for (int a = 0; a < 4; ++a) {
            float4 q = *(const float4*)(nv1g + (site * 4 + a) * 128 + lane * 4);
            nvp[s][a * 4 + 0] = q.x * (1.f / 32.f);
            nvp[s][a * 4 + 1] = q.y * (1.f / 32.f);
            nvp[s][a * 4 + 2] = q.z * (1.f / 32.f);
            nvp[s][a * 4 + 3] = q.w * (1.f / 32.f);
        }
        float mu = 0.f;
        #pragma unroll
        for (int j = 0; j < 16; ++j) mu += nvp[s][j];
        mu *= (1.f / 16.f);
        float var = 0.f;
        #pragma unroll
        for (int j = 0; j < 16; ++j) { float d = nvp[s][j] - mu; var += d * d; }
        var *= (1.f / 16.f);
        float rs = rsqrtf(var + EPSLN);
        #pragma unroll
        for (int j = 0; j < 16; ++j)
            nvp[s][j] = (nvp[s][j] - mu) * rs * g[j] + bt[j];
    }

    float nvacc[2][16];
    #pragma unroll
    for (int s = 0; s < 2; ++s)
        #pragma unroll
        for (int j = 0; j < 16; ++j) nvacc[s][j] = 0.f;

    __syncthreads();

    {
        uint4 wq0, wq1;
        {
            int n = grpid / 9, kl = grpid % 9;
            const uint4* wb = (const uint4*)(cw2 + (((kl * 32 + n) * 32) + lane) * 16);
            wq0 = wb[0]; wq1 = wb[1];
        }
        for (int it = grpid; it < 288; it += 8) {
            int nit = it + 8;
            uint4 nq0 = wq0, nq1 = wq1;
            if (nit < 288) {
                int n = nit / 9, kl = nit % 9;
                const uint4* wb = (const uint4*)(cw2 + (((kl * 32 + n) * 32) + lane) * 16);
                nq0 = wb[0]; nq1 = wb[1];
            }
            float cwv[16];
            {
                union { uint4 u; __bf16 hh[8]; } qa, qb;
                qa.u = wq0; qb.u = wq1;
                #pragma unroll
                for (int j = 0; j < 8; ++j) {
                    cwv[j] = (float)qa.hh[j]; cwv[8 + j] = (float)qb.hh[j];
                }
            }
            #pragma unroll
            for (int s = 0; s < 2; ++s) {
                float u16[16];
                #pragma unroll
                for (int f = 0; f < 4; ++f) {
                    float4 t4 = uloc4[s][it * 4 + f];
                    u16[f * 4 + 0] = t4.x; u16[f * 4 + 1] = t4.y;
                    u16[f * 4 + 2] = t4.z; u16[f * 4 + 3] = t4.w;
                }
                float votes[16];
                #pragma unroll
                for (int a = 0; a < 4; ++a)
                    #pragma unroll
                    for (int d = 0; d < 4; ++d) {
                        float v = 0.f;
                        #pragma unroll
                        for (int x = 0; x < 4; ++x)
                            v = fmaf(u16[a * 4 + x], cwv[x * 4 + d], v);
                        votes[a * 4 + d] = v;
                    }
                float qk = 0.f;
                #pragma unroll
                for (int j = 0; j < 16; ++j) qk = fmaf(votes[j], nvp[s][j], qk);
                qk *= 0.25f;
                float e = __expf(fminf(qk, 60.f));
                float sm = e;
                #pragma unroll
                for (int off = 1; off < 32; off <<= 1) sm += __shfl_xor(sm, off);
                float qv = e * __builtin_amdgcn_rcpf(sm);
                #pragma unroll
                for (int j = 0; j < 16; ++j) nvacc[s][j] = fmaf(qv, votes[j], nvacc[s][j]);
            }
            wq0 = nq0; wq1 = nq1;
        }
    }

    #pragma unroll
    for (int s = 0; s < 2; ++s)
        #pragma unroll
        for (int j = 0; j < 16; ++j)
            nvacc[s][j] += __shfl_xor(nvacc[s][j], 32);
    #pragma unroll
    for (int s = 0; s < 2; ++s) {
        __syncthreads();
        if (half0) {
            #pragma unroll
            for (int j = 0; j < 16; ++j) wred[wid * 544 + lane * 17 + j] = nvacc[s][j];
        }
        __syncthreads();
        for (int o = threadIdx.x; o < 512; o += 256) {
            int mm = o >> 4, j = o & 15;
            float sum = wred[0 * 544 + mm * 17 + j] + wred[1 * 544 + mm * 17 + j]
                      + wred[2 * 544 + mm * 17 + j] + wred[3 * 544 + mm * 17 + j];
            v1s[s][o] = sum;
        }
    }
    __syncthreads();
    if (threadIdx.x < 64) {
        int s = threadIdx.x >> 5, m = threadIdx.x & 31;
        int b = bb + s * 32;
        float v16[16], mu = 0.f;
        #pragma unroll
        for (int j = 0; j < 16; ++j) { v16[j] = v1s[s][m * 16 + j]; mu += v16[j]; }
        mu *= (1.f / 16.f);
        float var = 0.f;
        #pragma unroll
        for (int j = 0; j < 16; ++j) { float t = v16[j] - mu; var += t * t; }
        var *= (1.f / 16.f);
        float rs = rsqrtf(var + EPSLN);
        float o16[16];
        #pragma unroll
        for (int j = 0; j < 16; ++j) o16[j] = (v16[j] - mu) * rs * g[j] + bt[j];
        float4* dst = (float4*)(vout + (((b * 32 + m) * 7 + h) * 7 + w) * 16);
        dst[0] = make_float4(o16[0],  o16[1],  o16[2],  o16[3]);
        dst[1] = make_float4(o16[4],  o16[5],  o16[6],  o16[7]);
        dst[2] = make_float4(o16[8],  o16[9],  o16[10], o16[11]);
        dst[3] = make_float4(o16[12], o16[13], o16[14], o16[15]);
    }
}

// ===================== fc step1 + LN2: v2 -> p =====================
__global__ __launch_bounds__(256) void k_fc1(const float* __restrict__ fin,
                                             const float* __restrict__ fwp,
                                             const float* __restrict__ g,
                                             const float* __restrict__ bt,
                                             float* __restrict__ p) {
    int b = blockIdx.x / 10, m = blockIdx.x % 10;
    const float* fb = fin + b * 1568 * 16;
    const float* wb = fwp + m * 1568 * 16;
    float acc[16];
    #pragma unroll
    for (int j = 0; j < 16; ++j) acc[j] = 0.f;

    for (int n = threadIdx.x; n < 1568; n += 256) {
        const float4* u4 = (const float4*)(fb + n * 16);
        const float4* w4 = (const float4*)(wb + n * 16);
        float u16[16], w16[16];
        #pragma unroll
        for (int f = 0; f < 4; ++f) {
            float4 a = u4[f], bq = w4[f];
            u16[f * 4 + 0] = a.x;  u16[f * 4 + 1] = a.y;
            u16[f * 4 + 2] = a.z;  u16[f * 4 + 3] = a.w;
            w16[f * 4 + 0] = bq.x; w16[f * 4 + 1] = bq.y;
            w16[f * 4 + 2] = bq.z; w16[f * 4 + 3] = bq.w;
        }
        #pragma unroll
        for (int a = 0; a < 4; ++a)
            #pragma unroll
            for (int d = 0; d < 4; ++d) {
                float s = acc[a * 4 + d];
                #pragma unroll
                for (int x = 0; x < 4; ++x)
                    s = fmaf(u16[a * 4 + x], w16[x * 4 + d], s);
                acc[a * 4 + d] = s;
            }
    }
    #pragma unroll
    for (int j = 0; j < 16; ++j)
        #pragma unroll
        for (int off = 1; off < 64; off <<= 1)
            acc[j] += __shfl_xor(acc[j], off);

    __shared__ float red[4][16];
    int wid = threadIdx.x >> 6, ln = threadIdx.x & 63;
    if (ln == 0) {
        #pragma unroll
        for (int j = 0; j < 16; ++j) red[wid][j] = acc[j];
    }
    __syncthreads();
    if (threadIdx.x < 16) {
        int j = threadIdx.x;
        float s = (red[0][j] + red[1][j] + red[2][j] + red[3][j]) * 0.1f;
        float mu = s;
        #pragma unroll
        for (int off = 1; off < 16; off <<= 1) mu += __shfl_xor(mu, off);
        mu *= (1.f / 16.f);
        float t = s - mu;
        float var = t * t;
        #pragma unroll
        for (int off = 1; off < 16; off <<= 1) var += __shfl_xor(var, off);
        var *= (1.f / 16.f);
        float rs = rsqrtf(var + EPSLN);
        p[(b * 10 + m) * 16 + j] = t * rs * g[j] + bt[j];
    }
}

// ===================== fc routing, n-split partials =====================
__global__ __launch_bounds__(256) void k_fc2_part(const float* __restrict__ fin,
                                                  const float* __restrict__ fw,
                                                  const float* __restrict__ p,
                                                  float* __restrict__ part) {
    int b = blockIdx.x >> 4, slice = blockIdx.x & 15;
    int ad    = threadIdx.x & 15;
    int grpid = threadIdx.x >> 4;
    int a = ad >> 2, d = ad & 3;

    float pv[10];
    #pragma unroll
    for (int m = 0; m < 10; ++m) pv[m] = p[(b * 10 + m) * 16 + ad];

    float acc[10];
    #pragma unroll
    for (int m = 0; m < 10; ++m) acc[m] = 0.f;

    const float* fb = fin + b * 1568 * 16;
    int nbase = slice * 98;
    for (int n = nbase + grpid; n < nbase + 98; n += 16) {
        float4 u4 = *(const float4*)(fb + n * 16 + a * 4);
        const float* wb = fw + n * 160 + d * 10;
        float votes[10];
        #pragma unroll
        for (int m = 0; m < 10; ++m)
            votes[m] = u4.x * wb[m] + u4.y * wb[40 + m] +
                       u4.z * wb[80 + m] + u4.w * wb[120 + m];
        float qk[10];
        #pragma unroll
        for (int m = 0; m < 10; ++m) {
            float t = votes[m] * pv[m];
            #pragma unroll
            for (int off = 1; off < 16; off <<= 1) t += __shfl_xor(t, off);
            qk[m] = t * 0.25f;
        }
        float mx = qk[0];
        #pragma unroll
        for (int m = 1; m < 10; ++m) mx = fmaxf(mx, qk[m]);
        float e[10], s = 0.f;
        #pragma unroll
        for (int m = 0; m < 10; ++m) { e[m] = __expf(qk[m] - mx); s += e[m]; }
        float inv = 1.f / s;
        #pragma unroll
        for (int m = 0; m < 10; ++m) acc[m] = fmaf(e[m] * inv, votes[m], acc[m]);
    }

    __shared__ float red[16][16][10];
    #pragma unroll
    for (int m = 0; m < 10; ++m) red[grpid][ad][m] = acc[m];
    __syncthreads();

    if (threadIdx.x < 160) {
        int m = threadIdx.x / 16, j = threadIdx.x % 16;
        float s = 0.f;
        #pragma unroll
        for (int gg = 0; gg < 16; ++gg) s += red[gg][j][m];
        part[(b * 16 + slice) * 160 + m * 16 + j] = s;
    }
}

// ===================== fc final: reduce slices + LN2 -> out =====================
__global__ __launch_bounds__(256) void k_fc2_fin(const float* __restrict__ part,
                                                 const float* __restrict__ g,
                                                 const float* __restrict__ bt,
                                                 float* __restrict__ out) {
    int b = blockIdx.x;
    if (threadIdx.x >= 160) return;
    int m = threadIdx.x / 16, j = threadIdx.x % 16;
    float s = 0.f;
    #pragma unroll
    for (int sl = 0; sl < 16; ++sl)
        s += part[(b * 16 + sl) * 160 + m * 16 + j];
    float mu = s;
    #pragma unroll
    for (int off = 1; off < 16; off <<= 1) mu += __shfl_xor(mu, off);
    mu *= (1.f / 16.f);
    float t = s - mu;
    float var = t * t;
    #pragma unroll
    for (int off = 1; off < 16; off <<= 1) var += __shfl_xor(var, off);
    var *= (1.f / 16.f);
    float rs = rsqrtf(var + EPSLN);
    out[(b * 10 + m) * 16 + j] = t * rs * g[j] + bt[j];
}

// ============================ launch ============================
extern "C" void kernel_launch(void* const* d_in, const int* in_sizes, int n_in,
                              void* d_out, int out_size, void* d_ws, size_t ws_size,
                              hipStream_t stream) {
    const float* x    = (const float*)d_in[0];
    const float* bbw  = (const float*)d_in[1];
    const float* bbb  = (const float*)d_in[2];
    const float* pcw  = (const float*)d_in[3];
    const float* ln0g = (const float*)d_in[4];
    const float* ln0b = (const float*)d_in[5];
    const float* cwt  = (const float*)d_in[6];
    const float* ln1g = (const float*)d_in[7];
    const float* ln1b = (const float*)d_in[8];
    const float* fw   = (const float*)d_in[9];
    const float* ln2g = (const float*)d_in[10];
    const float* ln2b = (const float*)d_in[11];
    float* outp = (float*)d_out;

    float* ws = (float*)d_ws;
    __bf16* c2p  = (__bf16*)ws;                 // [0,          4,734,976)
    __bf16* wbT  = (__bf16*)(ws + 4734976);     // [4,734,976,  5,029,888)
    float*  bwT  = ws + 5029888;                // [5,029,888,  5,033,344)
    float*  val  = ws + 5033344;                // [5,033,344, 13,421,952)
    float*  v2   = ws + 13421952;               // [13,421,952, 15,027,584)
    float*  fwp  = ws + 15027584;               // [15,027,584, 15,278,464)
    float*  p    = ws + 15278464;               // [15,278,464, 15,288,704)
    __bf16* cw2  = (__bf16*)(ws + 15288704);    // [15,288,704, 15,362,432)
    __bf16* cwB  = (__bf16*)(ws + 15362432);    // [15,362,432, 15,436,160)
    float*  nv1g = ws + 15436160;               // [15,436,160, 17,041,792)
    float*  part = val;                         // aliases dead val

    hipMemsetAsync(c2p, 0, (size_t)9469952 * 2, stream);
    k_repack_all <<<4450, 256, 0, stream>>>(bbw, bwT, pcw, wbT, fw, fwp, cwt, cw2, cwB);
    k_conv1      <<<2048, 256, 0, stream>>>(x, bwT, bbb, c2p);
    k_conv2_mfma <<<1024, 256, 0, stream>>>(c2p, wbT, ln0g, ln0b, val);
    k_nv1_mfma   <<<392,  256, 0, stream>>>(val, cwB, nv1g);
    k_capsfused  <<<1568, 256, 0, stream>>>(val, cw2, nv1g, ln1g, ln1b, v2);
    k_fc1        <<<640, 256, 0, stream>>>(v2, fwp, ln2g, ln2b, p);
    k_fc2_part   <<<1024, 256, 0, stream>>>(v2, fw, p, part);
    k_fc2_fin    <<<64, 256, 0, stream>>>(part, ln2g, ln2b, outp);
}

// Round 17
// 236.029 us; speedup vs baseline: 1.5409x; 1.0427x over previous
//
#include <hip/hip_runtime.h>

// CapsTimeModel forward, round 17: conv2 retile 128x64 -> 128x128
// (16 MFMA per barrier-pair instead of 8; 512 blocks; 32KB dbuf LDS).
// Everything else identical to R16 (passing, 246us).

#define EPSLN 1e-5f

typedef short  short8 __attribute__((ext_vector_type(8)));
typedef __bf16 bf16x8 __attribute__((ext_vector_type(8)));
typedef float  f32x4  __attribute__((ext_vector_type(4)));

union Frag { short8 s; bf16x8 b; };

__device__ __forceinline__ uint4 pack_bf16_8(float4 a, float4 b) {
    union { __bf16 h[8]; uint4 u; } r;
    r.h[0] = (__bf16)a.x; r.h[1] = (__bf16)a.y;
    r.h[2] = (__bf16)a.z; r.h[3] = (__bf16)a.w;
    r.h[4] = (__bf16)b.x; r.h[5] = (__bf16)b.y;
    r.h[6] = (__bf16)b.z; r.h[7] = (__bf16)b.w;
    return r.u;
}

__device__ __forceinline__ void gld16(const void* g, void* l) {
    __builtin_amdgcn_global_load_lds(
        (const __attribute__((address_space(1))) void*)g,
        (__attribute__((address_space(3))) void*)l, 16, 0, 0);
}

// ==================== fused repacks (blockIdx-range dispatch) ====================
__global__ __launch_bounds__(256) void k_repack_all(
        const float* __restrict__ bw,  float* __restrict__ bwT,
        const float* __restrict__ pw,  __bf16* __restrict__ wbT,
        const float* __restrict__ fw,  float* __restrict__ fwp,
        const float* __restrict__ cw,  __bf16* __restrict__ cw2,
        __bf16* __restrict__ cwB) {
    int blk = blockIdx.x;
    if (blk < 2304) {                         // pcw -> wbT : 589824 exact
        int i = blk * 256 + threadIdx.x;
        int oc = i / 1152, r = i % 1152;
        int ic = r / 9, tap = r % 9;
        wbT[oc * 1152 + tap * 128 + ic] = (__bf16)pw[i];
    } else if (blk < 3284) {                  // fw -> fwp : 250880 exact
        int i = (blk - 2304) * 256 + threadIdx.x;
        int m = i % 10;
        int d = (i / 10) & 3;
        int x = (i / 40) & 3;
        int n = i / 160;
        fwp[(m * 1568 + n) * 16 + x * 4 + d] = fw[i];
    } else if (blk < 3860) {                  // cw -> cw2 : 147456 exact
        int i = (blk - 3284) * 256 + threadIdx.x;
        int m  = i & 31;
        int d  = (i >> 5) & 3;
        int x  = (i >> 7) & 3;
        int n  = (i >> 9) & 31;
        int kl = i >> 14;
        cw2[(((kl * 32 + n) * 32) + m) * 16 + x * 4 + d] = (__bf16)cw[i];
    } else if (blk < 4436) {                  // cw -> cwB : 147456 exact
        int i = (blk - 3860) * 256 + threadIdx.x;
        int m  = i & 31;
        int d  = (i >> 5) & 3;
        int x  = (i >> 7) & 3;
        int n  = (i >> 9) & 31;
        int kl = i >> 14;
        cwB[(m * 4 + d) * 1152 + (n * 9 + kl) * 4 + x] = (__bf16)cw[i];
    } else {                                  // bw -> bwT : 3456
        int i = (blk - 4436) * 256 + threadIdx.x;
        if (i < 3456) {
            int oc = i / 27, r = i % 27;
            bwT[r * 128 + oc] = bw[i];
        }
    }
}

// ==================== conv1 (LDS-staged): x -> c2p (NHWC bf16, padded) ====================
__global__ __launch_bounds__(256) void k_conv1(const float* __restrict__ x,
                                               const float* __restrict__ bwT,
                                               const float* __restrict__ bb,
                                               __bf16* __restrict__ c2p) {
    __shared__ float xs[3][3][66];

    int b = blockIdx.x >> 5, h = blockIdx.x & 31;
    for (int i = threadIdx.x; i < 594; i += 256) {
        int iw = i % 66;
        int r  = (i / 66) % 3;
        int ic = i / 198;
        int ih  = 2 * h + r - 1;
        int riw = iw - 1;
        float v = 0.f;
        if ((unsigned)ih < 64u && (unsigned)riw < 64u)
            v = x[((b * 3 + ic) * 64 + ih) * 64 + riw];
        xs[ic][r][iw] = v;
    }
    __syncthreads();

    int oc4 = threadIdx.x & 31, wq = threadIdx.x >> 5;
    float4 wv[27];
    #pragma unroll
    for (int r = 0; r < 27; ++r)
        wv[r] = *(const float4*)(bwT + r * 128 + oc4 * 4);
    float4 bias = *(const float4*)(bb + oc4 * 4);

    #pragma unroll
    for (int q = 0; q < 4; ++q) {
        int w = wq + q * 8;
        float4 acc = bias;
        #pragma unroll
        for (int ky = 0; ky < 3; ++ky)
            #pragma unroll
            for (int kx = 0; kx < 3; ++kx)
                #pragma unroll
                for (int ic = 0; ic < 3; ++ic) {
                    float in = xs[ic][ky][2 * w + kx];
                    float4 ww = wv[ic * 9 + ky * 3 + kx];
                    acc.x = fmaf(in, ww.x, acc.x);
                    acc.y = fmaf(in, ww.y, acc.y);
                    acc.z = fmaf(in, ww.z, acc.z);
                    acc.w = fmaf(in, ww.w, acc.w);
                }
        union { __bf16 h4[4]; unsigned long long ull; } r;
        r.h4[0] = (__bf16)fmaxf(acc.x, 0.f);
        r.h4[1] = (__bf16)fmaxf(acc.y, 0.f);
        r.h4[2] = (__bf16)fmaxf(acc.z, 0.f);
        r.h4[3] = (__bf16)fmaxf(acc.w, 0.f);
        *(unsigned long long*)(c2p + ((b * 34 + h + 1) * 34 + (w + 1)) * 128 + oc4 * 4)
            = r.ull;
    }
}

// ==================== conv2: 128x128 gld-dbuf MFMA GEMM + fused LN0 ====================
__global__ __launch_bounds__(256) void k_conv2_mfma(const __bf16* __restrict__ c2p,
                                                    const __bf16* __restrict__ wbT,
                                                    const float* __restrict__ g,
                                                    const float* __restrict__ bt,
                                                    float* __restrict__ val) {
    __shared__ unsigned short sA[2][128 * 32];   // 16 KB
    __shared__ unsigned short sB[2][128 * 32];   // 16 KB

    const int t = threadIdx.x;
    const int mblk = blockIdx.x >> 2, nblk = blockIdx.x & 3;
    const int pbase = mblk * 128, ocbase = nblk * 128;
    const int b = pbase >> 8;

    const int kc8 = (t & 3) * 8;
    const int r0 = t >> 2;
    const int oh0 = ((pbase + r0) >> 4) & 15, ow0 = (pbase + r0) & 15;
    const int oh1 = ((pbase + r0 + 64) >> 4) & 15, ow1 = (pbase + r0 + 64) & 15;

    const unsigned short* cb  = (const unsigned short*)c2p + (size_t)b * 147968;
    const unsigned short* ws0 = (const unsigned short*)wbT
                                + (ocbase + r0) * 1152 + kc8;
    const unsigned short* ws1 = ws0 + (size_t)64 * 1152;

    const int lane = t & 63, wid = t >> 6;
    const int lo = lane & 15, hi = lane >> 4;

    f32x4 acc[2][8];
    #pragma unroll
    for (int fr = 0; fr < 2; ++fr)
        #pragma unroll
        for (int fc = 0; fc < 8; ++fc)
            acc[fr][fc] = (f32x4){0.f, 0.f, 0.f, 0.f};

    auto stage = [&](int buf, int ks) {
        int tap = ks / 4, ic0 = (ks % 4) * 32;
        int ty = tap / 3, tx = tap % 3;
        gld16(cb + ((2 * oh0 + ty) * 34 + (2 * ow0 + tx)) * 128 + ic0 + kc8,
              &sA[buf][(unsigned)t * 8]);
        gld16(cb + ((2 * oh1 + ty) * 34 + (2 * ow1 + tx)) * 128 + ic0 + kc8,
              &sA[buf][((unsigned)t + 256) * 8]);
        gld16(ws0 + ks * 32, &sB[buf][(unsigned)t * 8]);
        gld16(ws1 + ks * 32, &sB[buf][((unsigned)t + 256) * 8]);
    };

    stage(0, 0);
    __syncthreads();

    for (int ks = 0; ks < 36; ++ks) {
        const int cur = ks & 1;
        if (ks + 1 < 36) stage(cur ^ 1, ks + 1);
        Frag af0, af1, bf[8];
        af0.s = *(const short8*)&sA[cur][(wid * 32 + lo) * 32 + hi * 8];
        af1.s = *(const short8*)&sA[cur][(wid * 32 + 16 + lo) * 32 + hi * 8];
        #pragma unroll
        for (int fc = 0; fc < 8; ++fc)
            bf[fc].s = *(const short8*)&sB[cur][(fc * 16 + lo) * 32 + hi * 8];
        #pragma unroll
        for (int fc = 0; fc < 8; ++fc) {
            acc[0][fc] = __builtin_amdgcn_mfma_f32_16x16x32_bf16(
                af0.b, bf[fc].b, acc[0][fc], 0, 0, 0);
            acc[1][fc] = __builtin_amdgcn_mfma_f32_16x16x32_bf16(
                af1.b, bf[fc].b, acc[1][fc], 0, 0, 0);
        }
        __syncthreads();
    }

    const float gv = g[lo], bv = bt[lo];
    #pragma unroll
    for (int fr = 0; fr < 2; ++fr) {
        #pragma unroll
        for (int fc = 0; fc < 8; ++fc) {
            const int n = (ocbase >> 4) + fc;
            #pragma unroll
            for (int j = 0; j < 4; ++j) {
                float v = acc[fr][fc][j];
                float s1 = v, s2 = v * v;
                #pragma unroll
                for (int off = 1; off < 16; off <<= 1) {
                    s1 += __shfl_xor(s1, off);
                    s2 += __shfl_xor(s2, off);
                }
                float mu  = s1 * (1.f / 16.f);
                float var = s2 * (1.f / 16.f) - mu * mu;
                float rs  = rsqrtf(var + EPSLN);
                float o   = (v - mu) * rs * gv + bv;
                int p  = pbase + wid * 32 + fr * 16 + hi * 4 + j;
                int oh = (p >> 4) & 15, ow = p & 15;
                val[(((b * 32 + n) * 16 + oh) * 16 + ow) * 16 + lo] = o;
            }
        }
    }
}

// ==================== nv1 GEMM (BM=64, pipelined): val x cwB -> nv1g ====================
__global__ __launch_bounds__(256) void k_nv1_mfma(const float* __restrict__ val,
                                                  const __bf16* __restrict__ cwB,
                                                  float* __restrict__ nv1g) {
    __shared__ unsigned short sA[64 * 32];
    __shared__ unsigned short sB[64 * 32];

    const int t = threadIdx.x;
    const int mblk = blockIdx.x >> 1, nblk = blockIdx.x & 1;
    const int pbase = mblk * 64, ocbase = nblk * 64;

    const float* vbase;
    {
        int r = pbase + (t >> 2);
        int site = r >> 2, a = r & 3;
        int b = site / 49, hw = site % 49;
        int h = hw / 7, w = hw % 7;
        vbase = val + (size_t)b * 131072 + (2 * h) * 256 + (2 * w) * 16 + a * 4;
    }
    const unsigned short* wsrc = (const unsigned short*)cwB
                                 + (ocbase + (t >> 2)) * 1152 + (t & 3) * 8;

    const int lane = t & 63, wid = t >> 6;
    const int lo = lane & 15, hi = lane >> 4;

    f32x4 acc[4];
    #pragma unroll
    for (int fc = 0; fc < 4; ++fc)
        acc[fc] = (f32x4){0.f, 0.f, 0.f, 0.f};

    auto itemoff = [](int i) {
        int n = i / 9, kl = i % 9;
        return n * 4096 + (kl / 3) * 256 + (kl % 3) * 16;
    };

    {
        int i0 = (t & 3) * 2;
        int o0 = itemoff(i0), o1 = itemoff(i0 + 1);
        uint4 a0 = pack_bf16_8(*(const float4*)(vbase + o0),
                               *(const float4*)(vbase + o1));
        uint4 b0 = *(const uint4*)(wsrc);
        *(uint4*)&sA[(unsigned)t * 8] = a0;
        *(uint4*)&sB[(unsigned)t * 8] = b0;
        __syncthreads();
    }

    for (int ks = 0; ks < 36; ++ks) {
        uint4 a0, b0;
        const bool pre = (ks + 1) < 36;
        if (pre) {
            int i0 = (ks + 1) * 8 + (t & 3) * 2;
            int o0 = itemoff(i0), o1 = itemoff(i0 + 1);
            a0 = pack_bf16_8(*(const float4*)(vbase + o0),
                             *(const float4*)(vbase + o1));
            b0 = *(const uint4*)(wsrc + (ks + 1) * 32);
        }
        Frag af, bf[4];
        af.s = *(const short8*)&sA[(wid * 16 + lo) * 32 + hi * 8];
        #pragma unroll
        for (int fc = 0; fc < 4; ++fc)
            bf[fc].s = *(const short8*)&sB[(fc * 16 + lo) * 32 + hi * 8];
        #pragma unroll
        for (int fc = 0; fc < 4; ++fc)
            acc[fc] = __builtin_amdgcn_mfma_f32_16x16x32_bf16(
                af.b, bf[fc].b, acc[fc], 0, 0, 0);
        __syncthreads();
        if (pre) {
            *(uint4*)&sA[(unsigned)t * 8] = a0;
            *(uint4*)&sB[(unsigned)t * 8] = b0;
        }
        __syncthreads();
    }

    #pragma unroll
    for (int fc = 0; fc < 4; ++fc)
        #pragma unroll
        for (int j = 0; j < 4; ++j) {
            int row = pbase + wid * 16 + hi * 4 + j;
            int col = ocbase + fc * 16 + lo;
            nv1g[row * 128 + col] = acc[fc][j];
        }
}

// ===================== caps routing pass 2 + LN1 (XCD-swizzled) =====================
__global__ __launch_bounds__(256) void k_capsfused(const float* __restrict__ val,
                                                   const __bf16* __restrict__ cw2,
                                                   const float* __restrict__ nv1g,
                                                   const float* __restrict__ g,
                                                   const float* __restrict__ bt,
                                                   float* __restrict__ vout) {
    int swz = (blockIdx.x & 7) * 196 + (blockIdx.x >> 3);
    int bb = swz / 49;
    int hw = swz % 49;
    int h = hw / 7, w = hw % 7;

    __shared__ float4 uloc4[2][1152];
    __shared__ float  v1s[2][512];
    float* wred = (float*)uloc4;

    for (int t = threadIdx.x; t < 2304; t += 256) {
        int s  = t >= 1152;
        int tt = t - s * 1152;
        int f  = tt & 3;
        int kl = (tt >> 2) % 9;
        int n  = tt / 36;
        int k = kl / 3, l = kl % 3;
        int b = bb + s * 32;
        uloc4[s][tt] = *(const float4*)(val +
            (((b * 32 + n) * 16 + (2 * h + k)) * 16 + (2 * w + l)) * 16 + f * 4);
    }

    const int lane  = threadIdx.x & 31;
    const int grpid = threadIdx.x >> 5;
    const int wid   = threadIdx.x >> 6;
    const bool half0 = (threadIdx.x & 32) == 0;

    float nvp[2][16];
    #pragma unroll
    for (int s = 0; s < 2; ++s) {
        int site = (bb + s * 32) * 49 + hw;
        #pragma unroll
        for (int a = 0; a < 4; ++a) {
            float4 q = *(const float4*)(nv1g + (site * 4 + a) * 128 + lane * 4);
            nvp[s][a * 4 + 0] = q.x * (1.f / 32.f);
            nvp[s][a * 4 + 1] = q.y * (1.f / 32.f);
            nvp[s][a * 4 + 2] = q.z * (1.f / 32.f);
            nvp[s][a * 4 + 3] = q.w * (1.f / 32.f);
        }
        float mu = 0.f;
        #pragma unroll
        for (int j = 0; j < 16; ++j) mu += nvp[s][j];
        mu *= (1.f / 16.f);
        float var = 0.f;
        #pragma unroll
        for (int j = 0; j < 16; ++j) { float d = nvp[s][j] - mu; var += d * d; }
        var *= (1.f / 16.f);
        float rs = rsqrtf(var + EPSLN);
        #pragma unroll
        for (int j = 0; j < 16; ++j)
            nvp[s][j] = (nvp[s][j] - mu) * rs * g[j] + bt[j];
    }

    float nvacc[2][16];
    #pragma unroll
    for (int s = 0; s < 2; ++s)
        #pragma unroll
        for (int j = 0; j < 16; ++j) nvacc[s][j] = 0.f;

    __syncthreads();

    {
        uint4 wq0, wq1;
        {
            int n = grpid / 9, kl = grpid % 9;
            const uint4* wb = (const uint4*)(cw2 + (((kl * 32 + n) * 32) + lane) * 16);
            wq0 = wb[0]; wq1 = wb[1];
        }
        for (int it = grpid; it < 288; it += 8) {
            int nit = it + 8;
            uint4 nq0 = wq0, nq1 = wq1;
            if (nit < 288) {
                int n = nit / 9, kl = nit % 9;
                const uint4* wb = (const uint4*)(cw2 + (((kl * 32 + n) * 32) + lane) * 16);
                nq0 = wb[0]; nq1 = wb[1];
            }
            float cwv[16];
            {
                union { uint4 u; __bf16 hh[8]; } qa, qb;
                qa.u = wq0; qb.u = wq1;
                #pragma unroll
                for (int j = 0; j < 8; ++j) {
                    cwv[j] = (float)qa.hh[j]; cwv[8 + j] = (float)qb.hh[j];
                }
            }
            #pragma unroll
            for (int s = 0; s < 2; ++s) {
                float u16[16];
                #pragma unroll
                for (int f = 0; f < 4; ++f) {
                    float4 t4 = uloc4[s][it * 4 + f];
                    u16[f * 4 + 0] = t4.x; u16[f * 4 + 1] = t4.y;
                    u16[f * 4 + 2] = t4.z; u16[f * 4 + 3] = t4.w;
                }
                float votes[16];
                #pragma unroll
                for (int a = 0; a < 4; ++a)
                    #pragma unroll
                    for (int d = 0; d < 4; ++d) {
                        float v = 0.f;
                        #pragma unroll
                        for (int x = 0; x < 4; ++x)
                            v = fmaf(u16[a * 4 + x], cwv[x * 4 + d], v);
                        votes[a * 4 + d] = v;
                    }
                float qk = 0.f;
                #pragma unroll
                for (int j = 0; j < 16; ++j) qk = fmaf(votes[j], nvp[s][j], qk);
                qk *= 0.25f;
                float e = __expf(fminf(qk, 60.f));
                float sm = e;
                #pragma unroll
                for (int off = 1; off < 32; off <<= 1) sm += __shfl_xor(sm, off);
                float qv = e * __builtin_amdgcn_rcpf(sm);
                #pragma unroll
                for (int j = 0; j < 16; ++j) nvacc[s][j] = fmaf(qv, votes[j], nvacc[s][j]);
            }
            wq0 = nq0; wq1 = nq1;
        }
    }

    #pragma unroll
    for (int s = 0; s < 2; ++s)
        #pragma unroll
        for (int j = 0; j < 16; ++j)
            nvacc[s][j] += __shfl_xor(nvacc[s][j], 32);
    #pragma unroll
    for (int s = 0; s < 2; ++s) {
        __syncthreads();
        if (half0) {
            #pragma unroll
            for (int j = 0; j < 16; ++j) wred[wid * 544 + lane * 17 + j] = nvacc[s][j];
        }
        __syncthreads();
        for (int o = threadIdx.x; o < 512; o += 256) {
            int mm = o >> 4, j = o & 15;
            float sum = wred[0 * 544 + mm * 17 + j] + wred[1 * 544 + mm * 17 + j]
                      + wred[2 * 544 + mm * 17 + j] + wred[3 * 544 + mm * 17 + j];
            v1s[s][o] = sum;
        }
    }
    __syncthreads();
    if (threadIdx.x < 64) {
        int s = threadIdx.x >> 5, m = threadIdx.x & 31;
        int b = bb + s * 32;
        float v16[16], mu = 0.f;
        #pragma unroll
        for (int j = 0; j < 16; ++j) { v16[j] = v1s[s][m * 16 + j]; mu += v16[j]; }
        mu *= (1.f / 16.f);
        float var = 0.f;
        #pragma unroll
        for (int j = 0; j < 16; ++j) { float t = v16[j] - mu; var += t * t; }
        var *= (1.f / 16.f);
        float rs = rsqrtf(var + EPSLN);
        float o16[16];
        #pragma unroll
        for (int j = 0; j < 16; ++j) o16[j] = (v16[j] - mu) * rs * g[j] + bt[j];
        float4* dst = (float4*)(vout + (((b * 32 + m) * 7 + h) * 7 + w) * 16);
        dst[0] = make_float4(o16[0],  o16[1],  o16[2],  o16[3]);
        dst[1] = make_float4(o16[4],  o16[5],  o16[6],  o16[7]);
        dst[2] = make_float4(o16[8],  o16[9],  o16[10], o16[11]);
        dst[3] = make_float4(o16[12], o16[13], o16[14], o16[15]);
    }
}

// ===================== fc step1 + LN2: v2 -> p =====================
__global__ __launch_bounds__(256) void k_fc1(const float* __restrict__ fin,
                                             const float* __restrict__ fwp,
                                             const float* __restrict__ g,
                                             const float* __restrict__ bt,
                                             float* __restrict__ p) {
    int b = blockIdx.x / 10, m = blockIdx.x % 10;
    const float* fb = fin + b * 1568 * 16;
    const float* wb = fwp + m * 1568 * 16;
    float acc[16];
    #pragma unroll
    for (int j = 0; j < 16; ++j) acc[j] = 0.f;

    for (int n = threadIdx.x; n < 1568; n += 256) {
        const float4* u4 = (const float4*)(fb + n * 16);
        const float4* w4 = (const float4*)(wb + n * 16);
        float u16[16], w16[16];
        #pragma unroll
        for (int f = 0; f < 4; ++f) {
            float4 a = u4[f], bq = w4[f];
            u16[f * 4 + 0] = a.x;  u16[f * 4 + 1] = a.y;
            u16[f * 4 + 2] = a.z;  u16[f * 4 + 3] = a.w;
            w16[f * 4 + 0] = bq.x; w16[f * 4 + 1] = bq.y;
            w16[f * 4 + 2] = bq.z; w16[f * 4 + 3] = bq.w;
        }
        #pragma unroll
        for (int a = 0; a < 4; ++a)
            #pragma unroll
            for (int d = 0; d < 4; ++d) {
                float s = acc[a * 4 + d];
                #pragma unroll
                for (int x = 0; x < 4; ++x)
                    s = fmaf(u16[a * 4 + x], w16[x * 4 + d], s);
                acc[a * 4 + d] = s;
            }
    }
    #pragma unroll
    for (int j = 0; j < 16; ++j)
        #pragma unroll
        for (int off = 1; off < 64; off <<= 1)
            acc[j] += __shfl_xor(acc[j], off);

    __shared__ float red[4][16];
    int wid = threadIdx.x >> 6, ln = threadIdx.x & 63;
    if (ln == 0) {
        #pragma unroll
        for (int j = 0; j < 16; ++j) red[wid][j] = acc[j];
    }
    __syncthreads();
    if (threadIdx.x < 16) {
        int j = threadIdx.x;
        float s = (red[0][j] + red[1][j] + red[2][j] + red[3][j]) * 0.1f;
        float mu = s;
        #pragma unroll
        for (int off = 1; off < 16; off <<= 1) mu += __shfl_xor(mu, off);
        mu *= (1.f / 16.f);
        float t = s - mu;
        float var = t * t;
        #pragma unroll
        for (int off = 1; off < 16; off <<= 1) var += __shfl_xor(var, off);
        var *= (1.f / 16.f);
        float rs = rsqrtf(var + EPSLN);
        p[(b * 10 + m) * 16 + j] = t * rs * g[j] + bt[j];
    }
}

// ===================== fc routing, n-split partials =====================
__global__ __launch_bounds__(256) void k_fc2_part(const float* __restrict__ fin,
                                                  const float* __restrict__ fw,
                                                  const float* __restrict__ p,
                                                  float* __restrict__ part) {
    int b = blockIdx.x >> 4, slice = blockIdx.x & 15;
    int ad    = threadIdx.x & 15;
    int grpid = threadIdx.x >> 4;
    int a = ad >> 2, d = ad & 3;

    float pv[10];
    #pragma unroll
    for (int m = 0; m < 10; ++m) pv[m] = p[(b * 10 + m) * 16 + ad];

    float acc[10];
    #pragma unroll
    for (int m = 0; m < 10; ++m) acc[m] = 0.f;

    const float* fb = fin + b * 1568 * 16;
    int nbase = slice * 98;
    for (int n = nbase + grpid; n < nbase + 98; n += 16) {
        float4 u4 = *(const float4*)(fb + n * 16 + a * 4);
        const float* wb = fw + n * 160 + d * 10;
        float votes[10];
        #pragma unroll
        for (int m = 0; m < 10; ++m)
            votes[m] = u4.x * wb[m] + u4.y * wb[40 + m] +
                       u4.z * wb[80 + m] + u4.w * wb[120 + m];
        float qk[10];
        #pragma unroll
        for (int m = 0; m < 10; ++m) {
            float t = votes[m] * pv[m];
            #pragma unroll
            for (int off = 1; off < 16; off <<= 1) t += __shfl_xor(t, off);
            qk[m] = t * 0.25f;
        }
        float mx = qk[0];
        #pragma unroll
        for (int m = 1; m < 10; ++m) mx = fmaxf(mx, qk[m]);
        float e[10], s = 0.f;
        #pragma unroll
        for (int m = 0; m < 10; ++m) { e[m] = __expf(qk[m] - mx); s += e[m]; }
        float inv = 1.f / s;
        #pragma unroll
        for (int m = 0; m < 10; ++m) acc[m] = fmaf(e[m] * inv, votes[m], acc[m]);
    }

    __shared__ float red[16][16][10];
    #pragma unroll
    for (int m = 0; m < 10; ++m) red[grpid][ad][m] = acc[m];
    __syncthreads();

    if (threadIdx.x < 160) {
        int m = threadIdx.x / 16, j = threadIdx.x % 16;
        float s = 0.f;
        #pragma unroll
        for (int gg = 0; gg < 16; ++gg) s += red[gg][j][m];
        part[(b * 16 + slice) * 160 + m * 16 + j] = s;
    }
}

// ===================== fc final: reduce slices + LN2 -> out =====================
__global__ __launch_bounds__(256) void k_fc2_fin(const float* __restrict__ part,
                                                 const float* __restrict__ g,
                                                 const float* __restrict__ bt,
                                                 float* __restrict__ out) {
    int b = blockIdx.x;
    if (threadIdx.x >= 160) return;
    int m = threadIdx.x / 16, j = threadIdx.x % 16;
    float s = 0.f;
    #pragma unroll
    for (int sl = 0; sl < 16; ++sl)
        s += part[(b * 16 + sl) * 160 + m * 16 + j];
    float mu = s;
    #pragma unroll
    for (int off = 1; off < 16; off <<= 1) mu += __shfl_xor(mu, off);
    mu *= (1.f / 16.f);
    float t = s - mu;
    float var = t * t;
    #pragma unroll
    for (int off = 1; off < 16; off <<= 1) var += __shfl_xor(var, off);
    var *= (1.f / 16.f);
    float rs = rsqrtf(var + EPSLN);
    out[(b * 10 + m) * 16 + j] = t * rs * g[j] + bt[j];
}

// ============================ launch ============================
extern "C" void kernel_launch(void* const* d_in, const int* in_sizes, int n_in,
                              void* d_out, int out_size, void* d_ws, size_t ws_size,
                              hipStream_t stream) {
    const float* x    = (const float*)d_in[0];
    const float* bbw  = (const float*)d_in[1];
    const float* bbb  = (const float*)d_in[2];
    const float* pcw  = (const float*)d_in[3];
    const float* ln0g = (const float*)d_in[4];
    const float* ln0b = (const float*)d_in[5];
    const float* cwt  = (const float*)d_in[6];
    const float* ln1g = (const float*)d_in[7];
    const float* ln1b = (const float*)d_in[8];
    const float* fw   = (const float*)d_in[9];
    const float* ln2g = (const float*)d_in[10];
    const float* ln2b = (const float*)d_in[11];
    float* outp = (float*)d_out;

    float* ws = (float*)d_ws;
    __bf16* c2p  = (__bf16*)ws;                 // [0,          4,734,976)
    __bf16* wbT  = (__bf16*)(ws + 4734976);     // [4,734,976,  5,029,888)
    float*  bwT  = ws + 5029888;                // [5,029,888,  5,033,344)
    float*  val  = ws + 5033344;                // [5,033,344, 13,421,952)
    float*  v2   = ws + 13421952;               // [13,421,952, 15,027,584)
    float*  fwp  = ws + 15027584;               // [15,027,584, 15,278,464)
    float*  p    = ws + 15278464;               // [15,278,464, 15,288,704)
    __bf16* cw2  = (__bf16*)(ws + 15288704);    // [15,288,704, 15,362,432)
    __bf16* cwB  = (__bf16*)(ws + 15362432);    // [15,362,432, 15,436,160)
    float*  nv1g = ws + 15436160;               // [15,436,160, 17,041,792)
    float*  part = val;                         // aliases dead val

    hipMemsetAsync(c2p, 0, (size_t)9469952 * 2, stream);
    k_repack_all <<<4450, 256, 0, stream>>>(bbw, bwT, pcw, wbT, fw, fwp, cwt, cw2, cwB);
    k_conv1      <<<2048, 256, 0, stream>>>(x, bwT, bbb, c2p);
    k_conv2_mfma <<<512,  256, 0, stream>>>(c2p, wbT, ln0g, ln0b, val);
    k_nv1_mfma   <<<392,  256, 0, stream>>>(val, cwB, nv1g);
    k_capsfused  <<<1568, 256, 0, stream>>>(val, cw2, nv1g, ln1g, ln1b, v2);
    k_fc1        <<<640, 256, 0, stream>>>(v2, fwp, ln2g, ln2b, p);
    k_fc2_part   <<<1024, 256, 0, stream>>>(v2, fw, p, part);
    k_fc2_fin    <<<64, 256, 0, stream>>>(part, ln2g, ln2b, outp);
}

// Round 18
// 234.178 us; speedup vs baseline: 1.5531x; 1.0079x over previous
//
#include <hip/hip_runtime.h>

// CapsTimeModel forward, round 18: capsfused -> 1 site/block.
//   2-site kept 64 VGPRs permanently live (nvp+nvacc) -> 72 VGPR, over the
//   64-reg occupancy cliff. 1-site: 32 persistent regs, LDS 20.5KB, 3136
//   blocks (XCD swizzle 8x392). Weight L2 traffic doubles (acceptable).
// All other kernels identical to R17 (passing, 236us).

#define EPSLN 1e-5f

typedef short  short8 __attribute__((ext_vector_type(8)));
typedef __bf16 bf16x8 __attribute__((ext_vector_type(8)));
typedef float  f32x4  __attribute__((ext_vector_type(4)));

union Frag { short8 s; bf16x8 b; };

__device__ __forceinline__ uint4 pack_bf16_8(float4 a, float4 b) {
    union { __bf16 h[8]; uint4 u; } r;
    r.h[0] = (__bf16)a.x; r.h[1] = (__bf16)a.y;
    r.h[2] = (__bf16)a.z; r.h[3] = (__bf16)a.w;
    r.h[4] = (__bf16)b.x; r.h[5] = (__bf16)b.y;
    r.h[6] = (__bf16)b.z; r.h[7] = (__bf16)b.w;
    return r.u;
}

__device__ __forceinline__ void gld16(const void* g, void* l) {
    __builtin_amdgcn_global_load_lds(
        (const __attribute__((address_space(1))) void*)g,
        (__attribute__((address_space(3))) void*)l, 16, 0, 0);
}

// ==================== fused repacks (blockIdx-range dispatch) ====================
__global__ __launch_bounds__(256) void k_repack_all(
        const float* __restrict__ bw,  float* __restrict__ bwT,
        const float* __restrict__ pw,  __bf16* __restrict__ wbT,
        const float* __restrict__ fw,  float* __restrict__ fwp,
        const float* __restrict__ cw,  __bf16* __restrict__ cw2,
        __bf16* __restrict__ cwB) {
    int blk = blockIdx.x;
    if (blk < 2304) {                         // pcw -> wbT : 589824 exact
        int i = blk * 256 + threadIdx.x;
        int oc = i / 1152, r = i % 1152;
        int ic = r / 9, tap = r % 9;
        wbT[oc * 1152 + tap * 128 + ic] = (__bf16)pw[i];
    } else if (blk < 3284) {                  // fw -> fwp : 250880 exact
        int i = (blk - 2304) * 256 + threadIdx.x;
        int m = i % 10;
        int d = (i / 10) & 3;
        int x = (i / 40) & 3;
        int n = i / 160;
        fwp[(m * 1568 + n) * 16 + x * 4 + d] = fw[i];
    } else if (blk < 3860) {                  // cw -> cw2 : 147456 exact
        int i = (blk - 3284) * 256 + threadIdx.x;
        int m  = i & 31;
        int d  = (i >> 5) & 3;
        int x  = (i >> 7) & 3;
        int n  = (i >> 9) & 31;
        int kl = i >> 14;
        cw2[(((kl * 32 + n) * 32) + m) * 16 + x * 4 + d] = (__bf16)cw[i];
    } else if (blk < 4436) {                  // cw -> cwB : 147456 exact
        int i = (blk - 3860) * 256 + threadIdx.x;
        int m  = i & 31;
        int d  = (i >> 5) & 3;
        int x  = (i >> 7) & 3;
        int n  = (i >> 9) & 31;
        int kl = i >> 14;
        cwB[(m * 4 + d) * 1152 + (n * 9 + kl) * 4 + x] = (__bf16)cw[i];
    } else {                                  // bw -> bwT : 3456
        int i = (blk - 4436) * 256 + threadIdx.x;
        if (i < 3456) {
            int oc = i / 27, r = i % 27;
            bwT[r * 128 + oc] = bw[i];
        }
    }
}

// ==================== conv1 (LDS-staged): x -> c2p (NHWC bf16, padded) ====================
__global__ __launch_bounds__(256) void k_conv1(const float* __restrict__ x,
                                               const float* __restrict__ bwT,
                                               const float* __restrict__ bb,
                                               __bf16* __restrict__ c2p) {
    __shared__ float xs[3][3][66];

    int b = blockIdx.x >> 5, h = blockIdx.x & 31;
    for (int i = threadIdx.x; i < 594; i += 256) {
        int iw = i % 66;
        int r  = (i / 66) % 3;
        int ic = i / 198;
        int ih  = 2 * h + r - 1;
        int riw = iw - 1;
        float v = 0.f;
        if ((unsigned)ih < 64u && (unsigned)riw < 64u)
            v = x[((b * 3 + ic) * 64 + ih) * 64 + riw];
        xs[ic][r][iw] = v;
    }
    __syncthreads();

    int oc4 = threadIdx.x & 31, wq = threadIdx.x >> 5;
    float4 wv[27];
    #pragma unroll
    for (int r = 0; r < 27; ++r)
        wv[r] = *(const float4*)(bwT + r * 128 + oc4 * 4);
    float4 bias = *(const float4*)(bb + oc4 * 4);

    #pragma unroll
    for (int q = 0; q < 4; ++q) {
        int w = wq + q * 8;
        float4 acc = bias;
        #pragma unroll
        for (int ky = 0; ky < 3; ++ky)
            #pragma unroll
            for (int kx = 0; kx < 3; ++kx)
                #pragma unroll
                for (int ic = 0; ic < 3; ++ic) {
                    float in = xs[ic][ky][2 * w + kx];
                    float4 ww = wv[ic * 9 + ky * 3 + kx];
                    acc.x = fmaf(in, ww.x, acc.x);
                    acc.y = fmaf(in, ww.y, acc.y);
                    acc.z = fmaf(in, ww.z, acc.z);
                    acc.w = fmaf(in, ww.w, acc.w);
                }
        union { __bf16 h4[4]; unsigned long long ull; } r;
        r.h4[0] = (__bf16)fmaxf(acc.x, 0.f);
        r.h4[1] = (__bf16)fmaxf(acc.y, 0.f);
        r.h4[2] = (__bf16)fmaxf(acc.z, 0.f);
        r.h4[3] = (__bf16)fmaxf(acc.w, 0.f);
        *(unsigned long long*)(c2p + ((b * 34 + h + 1) * 34 + (w + 1)) * 128 + oc4 * 4)
            = r.ull;
    }
}

// ==================== conv2: 128x128 gld-dbuf MFMA GEMM + fused LN0 ====================
__global__ __launch_bounds__(256) void k_conv2_mfma(const __bf16* __restrict__ c2p,
                                                    const __bf16* __restrict__ wbT,
                                                    const float* __restrict__ g,
                                                    const float* __restrict__ bt,
                                                    float* __restrict__ val) {
    __shared__ unsigned short sA[2][128 * 32];
    __shared__ unsigned short sB[2][128 * 32];

    const int t = threadIdx.x;
    const int mblk = blockIdx.x >> 2, nblk = blockIdx.x & 3;
    const int pbase = mblk * 128, ocbase = nblk * 128;
    const int b = pbase >> 8;

    const int kc8 = (t & 3) * 8;
    const int r0 = t >> 2;
    const int oh0 = ((pbase + r0) >> 4) & 15, ow0 = (pbase + r0) & 15;
    const int oh1 = ((pbase + r0 + 64) >> 4) & 15, ow1 = (pbase + r0 + 64) & 15;

    const unsigned short* cb  = (const unsigned short*)c2p + (size_t)b * 147968;
    const unsigned short* ws0 = (const unsigned short*)wbT
                                + (ocbase + r0) * 1152 + kc8;
    const unsigned short* ws1 = ws0 + (size_t)64 * 1152;

    const int lane = t & 63, wid = t >> 6;
    const int lo = lane & 15, hi = lane >> 4;

    f32x4 acc[2][8];
    #pragma unroll
    for (int fr = 0; fr < 2; ++fr)
        #pragma unroll
        for (int fc = 0; fc < 8; ++fc)
            acc[fr][fc] = (f32x4){0.f, 0.f, 0.f, 0.f};

    auto stage = [&](int buf, int ks) {
        int tap = ks / 4, ic0 = (ks % 4) * 32;
        int ty = tap / 3, tx = tap % 3;
        gld16(cb + ((2 * oh0 + ty) * 34 + (2 * ow0 + tx)) * 128 + ic0 + kc8,
              &sA[buf][(unsigned)t * 8]);
        gld16(cb + ((2 * oh1 + ty) * 34 + (2 * ow1 + tx)) * 128 + ic0 + kc8,
              &sA[buf][((unsigned)t + 256) * 8]);
        gld16(ws0 + ks * 32, &sB[buf][(unsigned)t * 8]);
        gld16(ws1 + ks * 32, &sB[buf][((unsigned)t + 256) * 8]);
    };

    stage(0, 0);
    __syncthreads();

    for (int ks = 0; ks < 36; ++ks) {
        const int cur = ks & 1;
        if (ks + 1 < 36) stage(cur ^ 1, ks + 1);
        Frag af0, af1, bf[8];
        af0.s = *(const short8*)&sA[cur][(wid * 32 + lo) * 32 + hi * 8];
        af1.s = *(const short8*)&sA[cur][(wid * 32 + 16 + lo) * 32 + hi * 8];
        #pragma unroll
        for (int fc = 0; fc < 8; ++fc)
            bf[fc].s = *(const short8*)&sB[cur][(fc * 16 + lo) * 32 + hi * 8];
        #pragma unroll
        for (int fc = 0; fc < 8; ++fc) {
            acc[0][fc] = __builtin_amdgcn_mfma_f32_16x16x32_bf16(
                af0.b, bf[fc].b, acc[0][fc], 0, 0, 0);
            acc[1][fc] = __builtin_amdgcn_mfma_f32_16x16x32_bf16(
                af1.b, bf[fc].b, acc[1][fc], 0, 0, 0);
        }
        __syncthreads();
    }

    const float gv = g[lo], bv = bt[lo];
    #pragma unroll
    for (int fr = 0; fr < 2; ++fr) {
        #pragma unroll
        for (int fc = 0; fc < 8; ++fc) {
            const int n = (ocbase >> 4) + fc;
            #pragma unroll
            for (int j = 0; j < 4; ++j) {
                float v = acc[fr][fc][j];
                float s1 = v, s2 = v * v;
                #pragma unroll
                for (int off = 1; off < 16; off <<= 1) {
                    s1 += __shfl_xor(s1, off);
                    s2 += __shfl_xor(s2, off);
                }
                float mu  = s1 * (1.f / 16.f);
                float var = s2 * (1.f / 16.f) - mu * mu;
                float rs  = rsqrtf(var + EPSLN);
                float o   = (v - mu) * rs * gv + bv;
                int p  = pbase + wid * 32 + fr * 16 + hi * 4 + j;
                int oh = (p >> 4) & 15, ow = p & 15;
                val[(((b * 32 + n) * 16 + oh) * 16 + ow) * 16 + lo] = o;
            }
        }
    }
}

// ==================== nv1 GEMM (BM=64, pipelined): val x cwB -> nv1g ====================
__global__ __launch_bounds__(256) void k_nv1_mfma(const float* __restrict__ val,
                                                  const __bf16* __restrict__ cwB,
                                                  float* __restrict__ nv1g) {
    __shared__ unsigned short sA[64 * 32];
    __shared__ unsigned short sB[64 * 32];

    const int t = threadIdx.x;
    const int mblk = blockIdx.x >> 1, nblk = blockIdx.x & 1;
    const int pbase = mblk * 64, ocbase = nblk * 64;

    const float* vbase;
    {
        int r = pbase + (t >> 2);
        int site = r >> 2, a = r & 3;
        int b = site / 49, hw = site % 49;
        int h = hw / 7, w = hw % 7;
        vbase = val + (size_t)b * 131072 + (2 * h) * 256 + (2 * w) * 16 + a * 4;
    }
    const unsigned short* wsrc = (const unsigned short*)cwB
                                 + (ocbase + (t >> 2)) * 1152 + (t & 3) * 8;

    const int lane = t & 63, wid = t >> 6;
    const int lo = lane & 15, hi = lane >> 4;

    f32x4 acc[4];
    #pragma unroll
    for (int fc = 0; fc < 4; ++fc)
        acc[fc] = (f32x4){0.f, 0.f, 0.f, 0.f};

    auto itemoff = [](int i) {
        int n = i / 9, kl = i % 9;
        return n * 4096 + (kl / 3) * 256 + (kl % 3) * 16;
    };

    {
        int i0 = (t & 3) * 2;
        int o0 = itemoff(i0), o1 = itemoff(i0 + 1);
        uint4 a0 = pack_bf16_8(*(const float4*)(vbase + o0),
                               *(const float4*)(vbase + o1));
        uint4 b0 = *(const uint4*)(wsrc);
        *(uint4*)&sA[(unsigned)t * 8] = a0;
        *(uint4*)&sB[(unsigned)t * 8] = b0;
        __syncthreads();
    }

    for (int ks = 0; ks < 36; ++ks) {
        uint4 a0, b0;
        const bool pre = (ks + 1) < 36;
        if (pre) {
            int i0 = (ks + 1) * 8 + (t & 3) * 2;
            int o0 = itemoff(i0), o1 = itemoff(i0 + 1);
            a0 = pack_bf16_8(*(const float4*)(vbase + o0),
                             *(const float4*)(vbase + o1));
            b0 = *(const uint4*)(wsrc + (ks + 1) * 32);
        }
        Frag af, bf[4];
        af.s = *(const short8*)&sA[(wid * 16 + lo) * 32 + hi * 8];
        #pragma unroll
        for (int fc = 0; fc < 4; ++fc)
            bf[fc].s = *(const short8*)&sB[(fc * 16 + lo) * 32 + hi * 8];
        #pragma unroll
        for (int fc = 0; fc < 4; ++fc)
            acc[fc] = __builtin_amdgcn_mfma_f32_16x16x32_bf16(
                af.b, bf[fc].b, acc[fc], 0, 0, 0);
        __syncthreads();
        if (pre) {
            *(uint4*)&sA[(unsigned)t * 8] = a0;
            *(uint4*)&sB[(unsigned)t * 8] = b0;
        }
        __syncthreads();
    }

    #pragma unroll
    for (int fc = 0; fc < 4; ++fc)
        #pragma unroll
        for (int j = 0; j < 4; ++j) {
            int row = pbase + wid * 16 + hi * 4 + j;
            int col = ocbase + fc * 16 + lo;
            nv1g[row * 128 + col] = acc[fc][j];
        }
}

// ===================== caps routing pass 2 + LN1 (1 site/block, XCD-swizzled) =====================
__global__ __launch_bounds__(256) void k_capsfused(const float* __restrict__ val,
                                                   const __bf16* __restrict__ cw2,
                                                   const float* __restrict__ nv1g,
                                                   const float* __restrict__ g,
                                                   const float* __restrict__ bt,
                                                   float* __restrict__ vout) {
    // XCD swizzle: 3136 blocks, 8 XCDs, 392 per chunk (bijective)
    int swz = (blockIdx.x & 7) * 392 + (blockIdx.x >> 3);
    int b  = swz / 49;
    int hw = swz % 49;
    int h = hw / 7, w = hw % 7;

    __shared__ float4 uloc4[1152];      // 18432 B; aliased by wred after loop
    __shared__ float  v1s[512];         //  2048 B
    float* wred = (float*)uloc4;

    for (int tt = threadIdx.x; tt < 1152; tt += 256) {
        int f  = tt & 3;
        int kl = (tt >> 2) % 9;
        int n  = tt / 36;
        int k = kl / 3, l = kl % 3;
        uloc4[tt] = *(const float4*)(val +
            (((b * 32 + n) * 16 + (2 * h + k)) * 16 + (2 * w + l)) * 16 + f * 4);
    }

    const int lane  = threadIdx.x & 31;          // m
    const int grpid = threadIdx.x >> 5;          // 0..7
    const int wid   = threadIdx.x >> 6;          // 0..3
    const bool half0 = (threadIdx.x & 32) == 0;

    // nvp from nv1 GEMM: /32 + lane-local LN
    float nvp[16];
    {
        int site = b * 49 + hw;
        #pragma unroll
        for (int a = 0; a < 4; ++a) {
            float4 q = *(const float4*)(nv1g + (site * 4 + a) * 128 + lane * 4);
            nvp[a * 4 + 0] = q.x * (1.f / 32.f);
            nvp[a * 4 + 1] = q.y * (1.f / 32.f);
            nvp[a * 4 + 2] = q.z * (1.f / 32.f);
            nvp[a * 4 + 3] = q.w * (1.f / 32.f);
        }
        float mu = 0.f;
        #pragma unroll
        for (int j = 0; j < 16; ++j) mu += nvp[j];
        mu *= (1.f / 16.f);
        float var = 0.f;
        #pragma unroll
        for (int j = 0; j < 16; ++j) { float d = nvp[j] - mu; var += d * d; }
        var *= (1.f / 16.f);
        float rs = rsqrtf(var + EPSLN);
        #pragma unroll
        for (int j = 0; j < 16; ++j)
            nvp[j] = (nvp[j] - mu) * rs * g[j] + bt[j];
    }

    float nvacc[16];
    #pragma unroll
    for (int j = 0; j < 16; ++j) nvacc[j] = 0.f;

    __syncthreads();

    {
        uint4 wq0, wq1;
        {
            int n = grpid / 9, kl = grpid % 9;
            const uint4* wb = (const uint4*)(cw2 + (((kl * 32 + n) * 32) + lane) * 16);
            wq0 = wb[0]; wq1 = wb[1];
        }
        for (int it = grpid; it < 288; it += 8) {
            int nit = it + 8;
            uint4 nq0 = wq0, nq1 = wq1;
            if (nit < 288) {
                int n = nit / 9, kl = nit % 9;
                const uint4* wb = (const uint4*)(cw2 + (((kl * 32 + n) * 32) + lane) * 16);
                nq0 = wb[0]; nq1 = wb[1];
            }
            float cwv[16];
            {
                union { uint4 u; __bf16 hh[8]; } qa, qb;
                qa.u = wq0; qb.u = wq1;
                #pragma unroll
                for (int j = 0; j < 8; ++j) {
                    cwv[j] = (float)qa.hh[j]; cwv[8 + j] = (float)qb.hh[j];
                }
            }
            float u16[16];
            #pragma unroll
            for (int f = 0; f < 4; ++f) {
                float4 t4 = uloc4[it * 4 + f];
                u16[f * 4 + 0] = t4.x; u16[f * 4 + 1] = t4.y;
                u16[f * 4 + 2] = t4.z; u16[f * 4 + 3] = t4.w;
            }
            float votes[16];
            #pragma unroll
            for (int a = 0; a < 4; ++a)
                #pragma unroll
                for (int d = 0; d < 4; ++d) {
                    float v = 0.f;
                    #pragma unroll
                    for (int x = 0; x < 4; ++x)
                        v = fmaf(u16[a * 4 + x], cwv[x * 4 + d], v);
                    votes[a * 4 + d] = v;
                }
            float qk = 0.f;
            #pragma unroll
            for (int j = 0; j < 16; ++j) qk = fmaf(votes[j], nvp[j], qk);
            qk *= 0.25f;
            float e = __expf(fminf(qk, 60.f));
            float sm = e;
            #pragma unroll
            for (int off = 1; off < 32; off <<= 1) sm += __shfl_xor(sm, off);
            float qv = e * __builtin_amdgcn_rcpf(sm);
            #pragma unroll
            for (int j = 0; j < 16; ++j) nvacc[j] = fmaf(qv, votes[j], nvacc[j]);
            wq0 = nq0; wq1 = nq1;
        }
    }

    // reduce -> nv2 -> LN -> global  (wred aliases uloc4; barrier-separated)
    #pragma unroll
    for (int j = 0; j < 16; ++j)
        nvacc[j] += __shfl_xor(nvacc[j], 32);
    __syncthreads();
    if (half0) {
        #pragma unroll
        for (int j = 0; j < 16; ++j) wred[wid * 544 + lane * 17 + j] = nvacc[j];
    }
    __syncthreads();
    for (int o = threadIdx.x; o < 512; o += 256) {
        int mm = o >> 4, j = o & 15;
        float sum = wred[0 * 544 + mm * 17 + j] + wred[1 * 544 + mm * 17 + j]
                  + wred[2 * 544 + mm * 17 + j] + wred[3 * 544 + mm * 17 + j];
        v1s[o] = sum;
    }
    __syncthreads();
    if (threadIdx.x < 32) {
        int m = threadIdx.x;
        float v16[16], mu = 0.f;
        #pragma unroll
        for (int j = 0; j < 16; ++j) { v16[j] = v1s[m * 16 + j]; mu += v16[j]; }
        mu *= (1.f / 16.f);
        float var = 0.f;
        #pragma unroll
        for (int j = 0; j < 16; ++j) { float t = v16[j] - mu; var += t * t; }
        var *= (1.f / 16.f);
        float rs = rsqrtf(var + EPSLN);
        float o16[16];
        #pragma unroll
        for (int j = 0; j < 16; ++j) o16[j] = (v16[j] - mu) * rs * g[j] + bt[j];
        float4* dst = (float4*)(vout + (((b * 32 + m) * 7 + h) * 7 + w) * 16);
        dst[0] = make_float4(o16[0],  o16[1],  o16[2],  o16[3]);
        dst[1] = make_float4(o16[4],  o16[5],  o16[6],  o16[7]);
        dst[2] = make_float4(o16[8],  o16[9],  o16[10], o16[11]);
        dst[3] = make_float4(o16[12], o16[13], o16[14], o16[15]);
    }
}

// ===================== fc step1 + LN2: v2 -> p =====================
__global__ __launch_bounds__(256) void k_fc1(const float* __restrict__ fin,
                                             const float* __restrict__ fwp,
                                             const float* __restrict__ g,
                                             const float* __restrict__ bt,
                                             float* __restrict__ p) {
    int b = blockIdx.x / 10, m = blockIdx.x % 10;
    const float* fb = fin + b * 1568 * 16;
    const float* wb = fwp + m * 1568 * 16;
    float acc[16];
    #pragma unroll
    for (int j = 0; j < 16; ++j) acc[j] = 0.f;

    for (int n = threadIdx.x; n < 1568; n += 256) {
        const float4* u4 = (const float4*)(fb + n * 16);
        const float4* w4 = (const float4*)(wb + n * 16);
        float u16[16], w16[16];
        #pragma unroll
        for (int f = 0; f < 4; ++f) {
            float4 a = u4[f], bq = w4[f];
            u16[f * 4 + 0] = a.x;  u16[f * 4 + 1] = a.y;
            u16[f * 4 + 2] = a.z;  u16[f * 4 + 3] = a.w;
            w16[f * 4 + 0] = bq.x; w16[f * 4 + 1] = bq.y;
            w16[f * 4 + 2] = bq.z; w16[f * 4 + 3] = bq.w;
        }
        #pragma unroll
        for (int a = 0; a < 4; ++a)
            #pragma unroll
            for (int d = 0; d < 4; ++d) {
                float s = acc[a * 4 + d];
                #pragma unroll
                for (int x = 0; x < 4; ++x)
                    s = fmaf(u16[a * 4 + x], w16[x * 4 + d], s);
                acc[a * 4 + d] = s;
            }
    }
    #pragma unroll
    for (int j = 0; j < 16; ++j)
        #pragma unroll
        for (int off = 1; off < 64; off <<= 1)
            acc[j] += __shfl_xor(acc[j], off);

    __shared__ float red[4][16];
    int wid = threadIdx.x >> 6, ln = threadIdx.x & 63;
    if (ln == 0) {
        #pragma unroll
        for (int j = 0; j < 16; ++j) red[wid][j] = acc[j];
    }
    __syncthreads();
    if (threadIdx.x < 16) {
        int j = threadIdx.x;
        float s = (red[0][j] + red[1][j] + red[2][j] + red[3][j]) * 0.1f;
        float mu = s;
        #pragma unroll
        for (int off = 1; off < 16; off <<= 1) mu += __shfl_xor(mu, off);
        mu *= (1.f / 16.f);
        float t = s - mu;
        float var = t * t;
        #pragma unroll
        for (int off = 1; off < 16; off <<= 1) var += __shfl_xor(var, off);
        var *= (1.f / 16.f);
        float rs = rsqrtf(var + EPSLN);
        p[(b * 10 + m) * 16 + j] = t * rs * g[j] + bt[j];
    }
}

// ===================== fc routing, n-split partials =====================
__global__ __launch_bounds__(256) void k_fc2_part(const float* __restrict__ fin,
                                                  const float* __restrict__ fw,
                                                  const float* __restrict__ p,
                                                  float* __restrict__ part) {
    int b = blockIdx.x >> 4, slice = blockIdx.x & 15;
    int ad    = threadIdx.x & 15;
    int grpid = threadIdx.x >> 4;
    int a = ad >> 2, d = ad & 3;

    float pv[10];
    #pragma unroll
    for (int m = 0; m < 10; ++m) pv[m] = p[(b * 10 + m) * 16 + ad];

    float acc[10];
    #pragma unroll
    for (int m = 0; m < 10; ++m) acc[m] = 0.f;

    const float* fb = fin + b * 1568 * 16;
    int nbase = slice * 98;
    for (int n = nbase + grpid; n < nbase + 98; n += 16) {
        float4 u4 = *(const float4*)(fb + n * 16 + a * 4);
        const float* wb = fw + n * 160 + d * 10;
        float votes[10];
        #pragma unroll
        for (int m = 0; m < 10; ++m)
            votes[m] = u4.x * wb[m] + u4.y * wb[40 + m] +
                       u4.z * wb[80 + m] + u4.w * wb[120 + m];
        float qk[10];
        #pragma unroll
        for (int m = 0; m < 10; ++m) {
            float t = votes[m] * pv[m];
            #pragma unroll
            for (int off = 1; off < 16; off <<= 1) t += __shfl_xor(t, off);
            qk[m] = t * 0.25f;
        }
        float mx = qk[0];
        #pragma unroll
        for (int m = 1; m < 10; ++m) mx = fmaxf(mx, qk[m]);
        float e[10], s = 0.f;
        #pragma unroll
        for (int m = 0; m < 10; ++m) { e[m] = __expf(qk[m] - mx); s += e[m]; }
        float inv = 1.f / s;
        #pragma unroll
        for (int m = 0; m < 10; ++m) acc[m] = fmaf(e[m] * inv, votes[m], acc[m]);
    }

    __shared__ float red[16][16][10];
    #pragma unroll
    for (int m = 0; m < 10; ++m) red[grpid][ad][m] = acc[m];
    __syncthreads();

    if (threadIdx.x < 160) {
        int m = threadIdx.x / 16, j = threadIdx.x % 16;
        float s = 0.f;
        #pragma unroll
        for (int gg = 0; gg < 16; ++gg) s += red[gg][j][m];
        part[(b * 16 + slice) * 160 + m * 16 + j] = s;
    }
}

// ===================== fc final: reduce slices + LN2 -> out =====================
__global__ __launch_bounds__(256) void k_fc2_fin(const float* __restrict__ part,
                                                 const float* __restrict__ g,
                                                 const float* __restrict__ bt,
                                                 float* __restrict__ out) {
    int b = blockIdx.x;
    if (threadIdx.x >= 160) return;
    int m = threadIdx.x / 16, j = threadIdx.x % 16;
    float s = 0.f;
    #pragma unroll
    for (int sl = 0; sl < 16; ++sl)
        s += part[(b * 16 + sl) * 160 + m * 16 + j];
    float mu = s;
    #pragma unroll
    for (int off = 1; off < 16; off <<= 1) mu += __shfl_xor(mu, off);
    mu *= (1.f / 16.f);
    float t = s - mu;
    float var = t * t;
    #pragma unroll
    for (int off = 1; off < 16; off <<= 1) var += __shfl_xor(var, off);
    var *= (1.f / 16.f);
    float rs = rsqrtf(var + EPSLN);
    out[(b * 10 + m) * 16 + j] = t * rs * g[j] + bt[j];
}

// ============================ launch ============================
extern "C" void kernel_launch(void* const* d_in, const int* in_sizes, int n_in,
                              void* d_out, int out_size, void* d_ws, size_t ws_size,
                              hipStream_t stream) {
    const float* x    = (const float*)d_in[0];
    const float* bbw  = (const float*)d_in[1];
    const float* bbb  = (const float*)d_in[2];
    const float* pcw  = (const float*)d_in[3];
    const float* ln0g = (const float*)d_in[4];
    const float* ln0b = (const float*)d_in[5];
    const float* cwt  = (const float*)d_in[6];
    const float* ln1g = (const float*)d_in[7];
    const float* ln1b = (const float*)d_in[8];
    const float* fw   = (const float*)d_in[9];
    const float* ln2g = (const float*)d_in[10];
    const float* ln2b = (const float*)d_in[11];
    float* outp = (float*)d_out;

    float* ws = (float*)d_ws;
    __bf16* c2p  = (__bf16*)ws;                 // [0,          4,734,976)
    __bf16* wbT  = (__bf16*)(ws + 4734976);     // [4,734,976,  5,029,888)
    float*  bwT  = ws + 5029888;                // [5,029,888,  5,033,344)
    float*  val  = ws + 5033344;                // [5,033,344, 13,421,952)
    float*  v2   = ws + 13421952;               // [13,421,952, 15,027,584)
    float*  fwp  = ws + 15027584;               // [15,027,584, 15,278,464)
    float*  p    = ws + 15278464;               // [15,278,464, 15,288,704)
    __bf16* cw2  = (__bf16*)(ws + 15288704);    // [15,288,704, 15,362,432)
    __bf16* cwB  = (__bf16*)(ws + 15362432);    // [15,362,432, 15,436,160)
    float*  nv1g = ws + 15436160;               // [15,436,160, 17,041,792)
    float*  part = val;                         // aliases dead val

    hipMemsetAsync(c2p, 0, (size_t)9469952 * 2, stream);
    k_repack_all <<<4450, 256, 0, stream>>>(bbw, bwT, pcw, wbT, fw, fwp, cwt, cw2, cwB);
    k_conv1      <<<2048, 256, 0, stream>>>(x, bwT, bbb, c2p);
    k_conv2_mfma <<<512,  256, 0, stream>>>(c2p, wbT, ln0g, ln0b, val);
    k_nv1_mfma   <<<392,  256, 0, stream>>>(val, cwB, nv1g);
    k_capsfused  <<<3136, 256, 0, stream>>>(val, cw2, nv1g, ln1g, ln1b, v2);
    k_fc1        <<<640, 256, 0, stream>>>(v2, fwp, ln2g, ln2b, p);
    k_fc2_part   <<<1024, 256, 0, stream>>>(v2, fw, p, part);
    k_fc2_fin    <<<64, 256, 0, stream>>>(part, ln2g, ln2b, outp);
}

// Round 19
// 223.816 us; speedup vs baseline: 1.6250x; 1.0463x over previous
//
#include <hip/hip_runtime.h>

// CapsTimeModel forward, round 19: capsfused votes via v_dot2_f32_bf16.
//   - dot2 path: u staged as packed bf16 x-pairs; weights repacked pair-major;
//     votes = 32 dot2 (was 64 fma + 16 cvt) -> ~40% fewer VALU ops/item.
//   - #if __has_builtin hedge: fallback = R18 body + static index remap.
//   - conv2: XCD swizzle (512 blocks, bijective).
// All else identical to R18 (passing, 234us).

#define EPSLN 1e-5f

#if defined(__has_builtin)
# if __has_builtin(__builtin_amdgcn_fdot2_f32_bf16)
#  define HAS_DOT2 1
# endif
#endif
#ifndef HAS_DOT2
# define HAS_DOT2 0
#endif

typedef short  short8 __attribute__((ext_vector_type(8)));
typedef __bf16 bf16x8 __attribute__((ext_vector_type(8)));
typedef __bf16 bf16x2 __attribute__((ext_vector_type(2)));
typedef float  f32x4  __attribute__((ext_vector_type(4)));

union Frag { short8 s; bf16x8 b; };

__device__ __forceinline__ uint4 pack_bf16_8(float4 a, float4 b) {
    union { __bf16 h[8]; uint4 u; } r;
    r.h[0] = (__bf16)a.x; r.h[1] = (__bf16)a.y;
    r.h[2] = (__bf16)a.z; r.h[3] = (__bf16)a.w;
    r.h[4] = (__bf16)b.x; r.h[5] = (__bf16)b.y;
    r.h[6] = (__bf16)b.z; r.h[7] = (__bf16)b.w;
    return r.u;
}

__device__ __forceinline__ void gld16(const void* g, void* l) {
    __builtin_amdgcn_global_load_lds(
        (const __attribute__((address_space(1))) void*)g,
        (__attribute__((address_space(3))) void*)l, 16, 0, 0);
}

// ==================== fused repacks (blockIdx-range dispatch) ====================
// cw2 layout (dot2 pair-major): elem pos = d*4 + (x>>1)*2 + (x&1)
__global__ __launch_bounds__(256) void k_repack_all(
        const float* __restrict__ bw,  float* __restrict__ bwT,
        const float* __restrict__ pw,  __bf16* __restrict__ wbT,
        const float* __restrict__ fw,  float* __restrict__ fwp,
        const float* __restrict__ cw,  __bf16* __restrict__ cw2,
        __bf16* __restrict__ cwB) {
    int blk = blockIdx.x;
    if (blk < 2304) {                         // pcw -> wbT : 589824 exact
        int i = blk * 256 + threadIdx.x;
        int oc = i / 1152, r = i % 1152;
        int ic = r / 9, tap = r % 9;
        wbT[oc * 1152 + tap * 128 + ic] = (__bf16)pw[i];
    } else if (blk < 3284) {                  // fw -> fwp : 250880 exact
        int i = (blk - 2304) * 256 + threadIdx.x;
        int m = i % 10;
        int d = (i / 10) & 3;
        int x = (i / 40) & 3;
        int n = i / 160;
        fwp[(m * 1568 + n) * 16 + x * 4 + d] = fw[i];
    } else if (blk < 3860) {                  // cw -> cw2 : 147456 exact
        int i = (blk - 3284) * 256 + threadIdx.x;
        int m  = i & 31;
        int d  = (i >> 5) & 3;
        int x  = (i >> 7) & 3;
        int n  = (i >> 9) & 31;
        int kl = i >> 14;
        cw2[(((kl * 32 + n) * 32) + m) * 16 + d * 4 + (x >> 1) * 2 + (x & 1)]
            = (__bf16)cw[i];
    } else if (blk < 4436) {                  // cw -> cwB : 147456 exact
        int i = (blk - 3860) * 256 + threadIdx.x;
        int m  = i & 31;
        int d  = (i >> 5) & 3;
        int x  = (i >> 7) & 3;
        int n  = (i >> 9) & 31;
        int kl = i >> 14;
        cwB[(m * 4 + d) * 1152 + (n * 9 + kl) * 4 + x] = (__bf16)cw[i];
    } else {                                  // bw -> bwT : 3456
        int i = (blk - 4436) * 256 + threadIdx.x;
        if (i < 3456) {
            int oc = i / 27, r = i % 27;
            bwT[r * 128 + oc] = bw[i];
        }
    }
}

// ==================== conv1 (LDS-staged): x -> c2p (NHWC bf16, padded) ====================
__global__ __launch_bounds__(256) void k_conv1(const float* __restrict__ x,
                                               const float* __restrict__ bwT,
                                               const float* __restrict__ bb,
                                               __bf16* __restrict__ c2p) {
    __shared__ float xs[3][3][66];

    int b = blockIdx.x >> 5, h = blockIdx.x & 31;
    for (int i = threadIdx.x; i < 594; i += 256) {
        int iw = i % 66;
        int r  = (i / 66) % 3;
        int ic = i / 198;
        int ih  = 2 * h + r - 1;
        int riw = iw - 1;
        float v = 0.f;
        if ((unsigned)ih < 64u && (unsigned)riw < 64u)
            v = x[((b * 3 + ic) * 64 + ih) * 64 + riw];
        xs[ic][r][iw] = v;
    }
    __syncthreads();

    int oc4 = threadIdx.x & 31, wq = threadIdx.x >> 5;
    float4 wv[27];
    #pragma unroll
    for (int r = 0; r < 27; ++r)
        wv[r] = *(const float4*)(bwT + r * 128 + oc4 * 4);
    float4 bias = *(const float4*)(bb + oc4 * 4);

    #pragma unroll
    for (int q = 0; q < 4; ++q) {
        int w = wq + q * 8;
        float4 acc = bias;
        #pragma unroll
        for (int ky = 0; ky < 3; ++ky)
            #pragma unroll
            for (int kx = 0; kx < 3; ++kx)
                #pragma unroll
                for (int ic = 0; ic < 3; ++ic) {
                    float in = xs[ic][ky][2 * w + kx];
                    float4 ww = wv[ic * 9 + ky * 3 + kx];
                    acc.x = fmaf(in, ww.x, acc.x);
                    acc.y = fmaf(in, ww.y, acc.y);
                    acc.z = fmaf(in, ww.z, acc.z);
                    acc.w = fmaf(in, ww.w, acc.w);
                }
        union { __bf16 h4[4]; unsigned long long ull; } r;
        r.h4[0] = (__bf16)fmaxf(acc.x, 0.f);
        r.h4[1] = (__bf16)fmaxf(acc.y, 0.f);
        r.h4[2] = (__bf16)fmaxf(acc.z, 0.f);
        r.h4[3] = (__bf16)fmaxf(acc.w, 0.f);
        *(unsigned long long*)(c2p + ((b * 34 + h + 1) * 34 + (w + 1)) * 128 + oc4 * 4)
            = r.ull;
    }
}

// ==================== conv2: 128x128 gld-dbuf MFMA GEMM + fused LN0 (XCD swz) ====================
__global__ __launch_bounds__(256) void k_conv2_mfma(const __bf16* __restrict__ c2p,
                                                    const __bf16* __restrict__ wbT,
                                                    const float* __restrict__ g,
                                                    const float* __restrict__ bt,
                                                    float* __restrict__ val) {
    __shared__ unsigned short sA[2][128 * 32];
    __shared__ unsigned short sB[2][128 * 32];

    const int t = threadIdx.x;
    const int swz = (blockIdx.x & 7) * 64 + (blockIdx.x >> 3);   // 512 blocks
    const int mblk = swz >> 2, nblk = swz & 3;
    const int pbase = mblk * 128, ocbase = nblk * 128;
    const int b = pbase >> 8;

    const int kc8 = (t & 3) * 8;
    const int r0 = t >> 2;
    const int oh0 = ((pbase + r0) >> 4) & 15, ow0 = (pbase + r0) & 15;
    const int oh1 = ((pbase + r0 + 64) >> 4) & 15, ow1 = (pbase + r0 + 64) & 15;

    const unsigned short* cb  = (const unsigned short*)c2p + (size_t)b * 147968;
    const unsigned short* ws0 = (const unsigned short*)wbT
                                + (ocbase + r0) * 1152 + kc8;
    const unsigned short* ws1 = ws0 + (size_t)64 * 1152;

    const int lane = t & 63, wid = t >> 6;
    const int lo = lane & 15, hi = lane >> 4;

    f32x4 acc[2][8];
    #pragma unroll
    for (int fr = 0; fr < 2; ++fr)
        #pragma unroll
        for (int fc = 0; fc < 8; ++fc)
            acc[fr][fc] = (f32x4){0.f, 0.f, 0.f, 0.f};

    auto stage = [&](int buf, int ks) {
        int tap = ks / 4, ic0 = (ks % 4) * 32;
        int ty = tap / 3, tx = tap % 3;
        gld16(cb + ((2 * oh0 + ty) * 34 + (2 * ow0 + tx)) * 128 + ic0 + kc8,
              &sA[buf][(unsigned)t * 8]);
        gld16(cb + ((2 * oh1 + ty) * 34 + (2 * ow1 + tx)) * 128 + ic0 + kc8,
              &sA[buf][((unsigned)t + 256) * 8]);
        gld16(ws0 + ks * 32, &sB[buf][(unsigned)t * 8]);
        gld16(ws1 + ks * 32, &sB[buf][((unsigned)t + 256) * 8]);
    };

    stage(0, 0);
    __syncthreads();

    for (int ks = 0; ks < 36; ++ks) {
        const int cur = ks & 1;
        if (ks + 1 < 36) stage(cur ^ 1, ks + 1);
        Frag af0, af1, bf[8];
        af0.s = *(const short8*)&sA[cur][(wid * 32 + lo) * 32 + hi * 8];
        af1.s = *(const short8*)&sA[cur][(wid * 32 + 16 + lo) * 32 + hi * 8];
        #pragma unroll
        for (int fc = 0; fc < 8; ++fc)
            bf[fc].s = *(const short8*)&sB[cur][(fc * 16 + lo) * 32 + hi * 8];
        #pragma unroll
        for (int fc = 0; fc < 8; ++fc) {
            acc[0][fc] = __builtin_amdgcn_mfma_f32_16x16x32_bf16(
                af0.b, bf[fc].b, acc[0][fc], 0, 0, 0);
            acc[1][fc] = __builtin_amdgcn_mfma_f32_16x16x32_bf16(
                af1.b, bf[fc].b, acc[1][fc], 0, 0, 0);
        }
        __syncthreads();
    }

    const float gv = g[lo], bv = bt[lo];
    #pragma unroll
    for (int fr = 0; fr < 2; ++fr) {
        #pragma unroll
        for (int fc = 0; fc < 8; ++fc) {
            const int n = (ocbase >> 4) + fc;
            #pragma unroll
            for (int j = 0; j < 4; ++j) {
                float v = acc[fr][fc][j];
                float s1 = v, s2 = v * v;
                #pragma unroll
                for (int off = 1; off < 16; off <<= 1) {
                    s1 += __shfl_xor(s1, off);
                    s2 += __shfl_xor(s2, off);
                }
                float mu  = s1 * (1.f / 16.f);
                float var = s2 * (1.f / 16.f) - mu * mu;
                float rs  = rsqrtf(var + EPSLN);
                float o   = (v - mu) * rs * gv + bv;
                int p  = pbase + wid * 32 + fr * 16 + hi * 4 + j;
                int oh = (p >> 4) & 15, ow = p & 15;
                val[(((b * 32 + n) * 16 + oh) * 16 + ow) * 16 + lo] = o;
            }
        }
    }
}

// ==================== nv1 GEMM (BM=64, pipelined): val x cwB -> nv1g ====================
__global__ __launch_bounds__(256) void k_nv1_mfma(const float* __restrict__ val,
                                                  const __bf16* __restrict__ cwB,
                                                  float* __restrict__ nv1g) {
    __shared__ unsigned short sA[64 * 32];
    __shared__ unsigned short sB[64 * 32];

    const int t = threadIdx.x;
    const int mblk = blockIdx.x >> 1, nblk = blockIdx.x & 1;
    const int pbase = mblk * 64, ocbase = nblk * 64;

    const float* vbase;
    {
        int r = pbase + (t >> 2);
        int site = r >> 2, a = r & 3;
        int b = site / 49, hw = site % 49;
        int h = hw / 7, w = hw % 7;
        vbase = val + (size_t)b * 131072 + (2 * h) * 256 + (2 * w) * 16 + a * 4;
    }
    const unsigned short* wsrc = (const unsigned short*)cwB
                                 + (ocbase + (t >> 2)) * 1152 + (t & 3) * 8;

    const int lane = t & 63, wid = t >> 6;
    const int lo = lane & 15, hi = lane >> 4;

    f32x4 acc[4];
    #pragma unroll
    for (int fc = 0; fc < 4; ++fc)
        acc[fc] = (f32x4){0.f, 0.f, 0.f, 0.f};

    auto itemoff = [](int i) {
        int n = i / 9, kl = i % 9;
        return n * 4096 + (kl / 3) * 256 + (kl % 3) * 16;
    };

    {
        int i0 = (t & 3) * 2;
        int o0 = itemoff(i0), o1 = itemoff(i0 + 1);
        uint4 a0 = pack_bf16_8(*(const float4*)(vbase + o0),
                               *(const float4*)(vbase + o1));
        uint4 b0 = *(const uint4*)(wsrc);
        *(uint4*)&sA[(unsigned)t * 8] = a0;
        *(uint4*)&sB[(unsigned)t * 8] = b0;
        __syncthreads();
    }

    for (int ks = 0; ks < 36; ++ks) {
        uint4 a0, b0;
        const bool pre = (ks + 1) < 36;
        if (pre) {
            int i0 = (ks + 1) * 8 + (t & 3) * 2;
            int o0 = itemoff(i0), o1 = itemoff(i0 + 1);
            a0 = pack_bf16_8(*(const float4*)(vbase + o0),
                             *(const float4*)(vbase + o1));
            b0 = *(const uint4*)(wsrc + (ks + 1) * 32);
        }
        Frag af, bf[4];
        af.s = *(const short8*)&sA[(wid * 16 + lo) * 32 + hi * 8];
        #pragma unroll
        for (int fc = 0; fc < 4; ++fc)
            bf[fc].s = *(const short8*)&sB[(fc * 16 + lo) * 32 + hi * 8];
        #pragma unroll
        for (int fc = 0; fc < 4; ++fc)
            acc[fc] = __builtin_amdgcn_mfma_f32_16x16x32_bf16(
                af.b, bf[fc].b, acc[fc], 0, 0, 0);
        __syncthreads();
        if (pre) {
            *(uint4*)&sA[(unsigned)t * 8] = a0;
            *(uint4*)&sB[(unsigned)t * 8] = b0;
        }
        __syncthreads();
    }

    #pragma unroll
    for (int fc = 0; fc < 4; ++fc)
        #pragma unroll
        for (int j = 0; j < 4; ++j) {
            int row = pbase + wid * 16 + hi * 4 + j;
            int col = ocbase + fc * 16 + lo;
            nv1g[row * 128 + col] = acc[fc][j];
        }
}

// ===================== caps routing pass 2 + LN1 (1 site/block, dot2) =====================
__global__ __launch_bounds__(256) void k_capsfused(const float* __restrict__ val,
                                                   const __bf16* __restrict__ cw2,
                                                   const float* __restrict__ nv1g,
                                                   const float* __restrict__ g,
                                                   const float* __restrict__ bt,
                                                   float* __restrict__ vout) {
    int swz = (blockIdx.x & 7) * 392 + (blockIdx.x >> 3);
    int b  = swz / 49;
    int hw = swz % 49;
    int h = hw / 7, w = hw % 7;

#if HAS_DOT2
    __shared__ uint4 ulocH[576];        //  9216 B  packed bf16 u (item*2+half)
    __shared__ float v1s[512];          //  2048 B
    float* wred = (float*)ulocH;        //  8704 B needed <= 9216

    for (int tt = threadIdx.x; tt < 576; tt += 256) {
        int item = tt >> 1, hf = tt & 1;
        int n = item / 9, kl = item % 9;
        int k = kl / 3, l = kl % 3;
        const float4* src = (const float4*)(val +
            (((b * 32 + n) * 16 + (2 * h + k)) * 16 + (2 * w + l)) * 16 + hf * 8);
        ulocH[tt] = pack_bf16_8(src[0], src[1]);
    }
#else
    __shared__ float4 uloc4[1152];      // 18432 B  f32 u
    __shared__ float  v1s[512];
    float* wred = (float*)uloc4;

    for (int tt = threadIdx.x; tt < 1152; tt += 256) {
        int f  = tt & 3;
        int kl = (tt >> 2) % 9;
        int n  = tt / 36;
        int k = kl / 3, l = kl % 3;
        uloc4[tt] = *(const float4*)(val +
            (((b * 32 + n) * 16 + (2 * h + k)) * 16 + (2 * w + l)) * 16 + f * 4);
    }
#endif

    const int lane  = threadIdx.x & 31;
    const int grpid = threadIdx.x >> 5;
    const int wid   = threadIdx.x >> 6;
    const bool half0 = (threadIdx.x & 32) == 0;

    float nvp[16];
    {
        int site = b * 49 + hw;
        #pragma unroll
        for (int a = 0; a < 4; ++a) {
            float4 q = *(const float4*)(nv1g + (site * 4 + a) * 128 + lane * 4);
            nvp[a * 4 + 0] = q.x * (1.f / 32.f);
            nvp[a * 4 + 1] = q.y * (1.f / 32.f);
            nvp[a * 4 + 2] = q.z * (1.f / 32.f);
            nvp[a * 4 + 3] = q.w * (1.f / 32.f);
        }
        float mu = 0.f;
        #pragma unroll
        for (int j = 0; j < 16; ++j) mu += nvp[j];
        mu *= (1.f / 16.f);
        float var = 0.f;
        #pragma unroll
        for (int j = 0; j < 16; ++j) { float d = nvp[j] - mu; var += d * d; }
        var *= (1.f / 16.f);
        float rs = rsqrtf(var + EPSLN);
        #pragma unroll
        for (int j = 0; j < 16; ++j)
            nvp[j] = (nvp[j] - mu) * rs * g[j] + bt[j];
    }

    float nvacc[16];
    #pragma unroll
    for (int j = 0; j < 16; ++j) nvacc[j] = 0.f;

    __syncthreads();

    {
        uint4 wq0, wq1;
        {
            int n = grpid / 9, kl = grpid % 9;
            const uint4* wb = (const uint4*)(cw2 + (((kl * 32 + n) * 32) + lane) * 16);
            wq0 = wb[0]; wq1 = wb[1];
        }
        for (int it = grpid; it < 288; it += 8) {
            int nit = it + 8;
            uint4 nq0 = wq0, nq1 = wq1;
            if (nit < 288) {
                int n = nit / 9, kl = nit % 9;
                const uint4* wb = (const uint4*)(cw2 + (((kl * 32 + n) * 32) + lane) * 16);
                nq0 = wb[0]; nq1 = wb[1];
            }
            float votes[16];
#if HAS_DOT2
            {
                union { uint4 u; bf16x2 h2[4]; } wA, wB, uA, uB;
                wA.u = wq0; wB.u = wq1;                // w pairs: d0,d1 | d2,d3
                uA.u = ulocH[it * 2];                   // u pairs: a0,a1
                uB.u = ulocH[it * 2 + 1];               //          a2,a3
                #pragma unroll
                for (int a = 0; a < 4; ++a) {
                    bf16x2 u0 = (a < 2) ? uA.h2[a * 2]     : uB.h2[(a - 2) * 2];
                    bf16x2 u1 = (a < 2) ? uA.h2[a * 2 + 1] : uB.h2[(a - 2) * 2 + 1];
                    #pragma unroll
                    for (int d = 0; d < 4; ++d) {
                        bf16x2 w0 = (d < 2) ? wA.h2[d * 2]     : wB.h2[(d - 2) * 2];
                        bf16x2 w1 = (d < 2) ? wA.h2[d * 2 + 1] : wB.h2[(d - 2) * 2 + 1];
                        votes[a * 4 + d] = __builtin_amdgcn_fdot2_f32_bf16(
                            u1, w1,
                            __builtin_amdgcn_fdot2_f32_bf16(u0, w0, 0.f, false),
                            false);
                    }
                }
            }
#else
            {
                union { uint4 u; __bf16 hh[8]; } qa, qb;
                qa.u = wq0; qb.u = wq1;
                float cwv[16];
                #pragma unroll
                for (int x = 0; x < 4; ++x)
                    #pragma unroll
                    for (int d = 0; d < 4; ++d) {
                        int pos = d * 4 + (x >> 1) * 2 + (x & 1);
                        cwv[x * 4 + d] = (float)(pos < 8 ? qa.hh[pos] : qb.hh[pos - 8]);
                    }
                float u16[16];
                #pragma unroll
                for (int f = 0; f < 4; ++f) {
                    float4 t4 = uloc4[it * 4 + f];
                    u16[f * 4 + 0] = t4.x; u16[f * 4 + 1] = t4.y;
                    u16[f * 4 + 2] = t4.z; u16[f * 4 + 3] = t4.w;
                }
                #pragma unroll
                for (int a = 0; a < 4; ++a)
                    #pragma unroll
                    for (int d = 0; d < 4; ++d) {
                        float v = 0.f;
                        #pragma unroll
                        for (int x = 0; x < 4; ++x)
                            v = fmaf(u16[a * 4 + x], cwv[x * 4 + d], v);
                        votes[a * 4 + d] = v;
                    }
            }
#endif
            float qk = 0.f;
            #pragma unroll
            for (int j = 0; j < 16; ++j) qk = fmaf(votes[j], nvp[j], qk);
            qk *= 0.25f;
            float e = __expf(fminf(qk, 60.f));
            float sm = e;
            #pragma unroll
            for (int off = 1; off < 32; off <<= 1) sm += __shfl_xor(sm, off);
            float qv = e * __builtin_amdgcn_rcpf(sm);
            #pragma unroll
            for (int j = 0; j < 16; ++j) nvacc[j] = fmaf(qv, votes[j], nvacc[j]);
            wq0 = nq0; wq1 = nq1;
        }
    }

    #pragma unroll
    for (int j = 0; j < 16; ++j)
        nvacc[j] += __shfl_xor(nvacc[j], 32);
    __syncthreads();
    if (half0) {
        #pragma unroll
        for (int j = 0; j < 16; ++j) wred[wid * 544 + lane * 17 + j] = nvacc[j];
    }
    __syncthreads();
    for (int o = threadIdx.x; o < 512; o += 256) {
        int mm = o >> 4, j = o & 15;
        float sum = wred[0 * 544 + mm * 17 + j] + wred[1 * 544 + mm * 17 + j]
                  + wred[2 * 544 + mm * 17 + j] + wred[3 * 544 + mm * 17 + j];
        v1s[o] = sum;
    }
    __syncthreads();
    if (threadIdx.x < 32) {
        int m = threadIdx.x;
        float v16[16], mu = 0.f;
        #pragma unroll
        for (int j = 0; j < 16; ++j) { v16[j] = v1s[m * 16 + j]; mu += v16[j]; }
        mu *= (1.f / 16.f);
        float var = 0.f;
        #pragma unroll
        for (int j = 0; j < 16; ++j) { float t = v16[j] - mu; var += t * t; }
        var *= (1.f / 16.f);
        float rs = rsqrtf(var + EPSLN);
        float o16[16];
        #pragma unroll
        for (int j = 0; j < 16; ++j) o16[j] = (v16[j] - mu) * rs * g[j] + bt[j];
        float4* dst = (float4*)(vout + (((b * 32 + m) * 7 + h) * 7 + w) * 16);
        dst[0] = make_float4(o16[0],  o16[1],  o16[2],  o16[3]);
        dst[1] = make_float4(o16[4],  o16[5],  o16[6],  o16[7]);
        dst[2] = make_float4(o16[8],  o16[9],  o16[10], o16[11]);
        dst[3] = make_float4(o16[12], o16[13], o16[14], o16[15]);
    }
}

// ===================== fc step1 + LN2: v2 -> p =====================
__global__ __launch_bounds__(256) void k_fc1(const float* __restrict__ fin,
                                             const float* __restrict__ fwp,
                                             const float* __restrict__ g,
                                             const float* __restrict__ bt,
                                             float* __restrict__ p) {
    int b = blockIdx.x / 10, m = blockIdx.x % 10;
    const float* fb = fin + b * 1568 * 16;
    const float* wb = fwp + m * 1568 * 16;
    float acc[16];
    #pragma unroll
    for (int j = 0; j < 16; ++j) acc[j] = 0.f;

    for (int n = threadIdx.x; n < 1568; n += 256) {
        const float4* u4 = (const float4*)(fb + n * 16);
        const float4* w4 = (const float4*)(wb + n * 16);
        float u16[16], w16[16];
        #pragma unroll
        for (int f = 0; f < 4; ++f) {
            float4 a = u4[f], bq = w4[f];
            u16[f * 4 + 0] = a.x;  u16[f * 4 + 1] = a.y;
            u16[f * 4 + 2] = a.z;  u16[f * 4 + 3] = a.w;
            w16[f * 4 + 0] = bq.x; w16[f * 4 + 1] = bq.y;
            w16[f * 4 + 2] = bq.z; w16[f * 4 + 3] = bq.w;
        }
        #pragma unroll
        for (int a = 0; a < 4; ++a)
            #pragma unroll
            for (int d = 0; d < 4; ++d) {
                float s = acc[a * 4 + d];
                #pragma unroll
                for (int x = 0; x < 4; ++x)
                    s = fmaf(u16[a * 4 + x], w16[x * 4 + d], s);
                acc[a * 4 + d] = s;
            }
    }
    #pragma unroll
    for (int j = 0; j < 16; ++j)
        #pragma unroll
        for (int off = 1; off < 64; off <<= 1)
            acc[j] += __shfl_xor(acc[j], off);

    __shared__ float red[4][16];
    int wid = threadIdx.x >> 6, ln = threadIdx.x & 63;
    if (ln == 0) {
        #pragma unroll
        for (int j = 0; j < 16; ++j) red[wid][j] = acc[j];
    }
    __syncthreads();
    if (threadIdx.x < 16) {
        int j = threadIdx.x;
        float s = (red[0][j] + red[1][j] + red[2][j] + red[3][j]) * 0.1f;
        float mu = s;
        #pragma unroll
        for (int off = 1; off < 16; off <<= 1) mu += __shfl_xor(mu, off);
        mu *= (1.f / 16.f);
        float t = s - mu;
        float var = t * t;
        #pragma unroll
        for (int off = 1; off < 16; off <<= 1) var += __shfl_xor(var, off);
        var *= (1.f / 16.f);
        float rs = rsqrtf(var + EPSLN);
        p[(b * 10 + m) * 16 + j] = t * rs * g[j] + bt[j];
    }
}

// ===================== fc routing, n-split partials =====================
__global__ __launch_bounds__(256) void k_fc2_part(const float* __restrict__ fin,
                                                  const float* __restrict__ fw,
                                                  const float* __restrict__ p,
                                                  float* __restrict__ part) {
    int b = blockIdx.x >> 4, slice = blockIdx.x & 15;
    int ad    = threadIdx.x & 15;
    int grpid = threadIdx.x >> 4;
    int a = ad >> 2, d = ad & 3;

    float pv[10];
    #pragma unroll
    for (int m = 0; m < 10; ++m) pv[m] = p[(b * 10 + m) * 16 + ad];

    float acc[10];
    #pragma unroll
    for (int m = 0; m < 10; ++m) acc[m] = 0.f;

    const float* fb = fin + b * 1568 * 16;
    int nbase = slice * 98;
    for (int n = nbase + grpid; n < nbase + 98; n += 16) {
        float4 u4 = *(const float4*)(fb + n * 16 + a * 4);
        const float* wb = fw + n * 160 + d * 10;
        float votes[10];
        #pragma unroll
        for (int m = 0; m < 10; ++m)
            votes[m] = u4.x * wb[m] + u4.y * wb[40 + m] +
                       u4.z * wb[80 + m] + u4.w * wb[120 + m];
        float qk[10];
        #pragma unroll
        for (int m = 0; m < 10; ++m) {
            float t = votes[m] * pv[m];
            #pragma unroll
            for (int off = 1; off < 16; off <<= 1) t += __shfl_xor(t, off);
            qk[m] = t * 0.25f;
        }
        float mx = qk[0];
        #pragma unroll
        for (int m = 1; m < 10; ++m) mx = fmaxf(mx, qk[m]);
        float e[10], s = 0.f;
        #pragma unroll
        for (int m = 0; m < 10; ++m) { e[m] = __expf(qk[m] - mx); s += e[m]; }
        float inv = 1.f / s;
        #pragma unroll
        for (int m = 0; m < 10; ++m) acc[m] = fmaf(e[m] * inv, votes[m], acc[m]);
    }

    __shared__ float red[16][16][10];
    #pragma unroll
    for (int m = 0; m < 10; ++m) red[grpid][ad][m] = acc[m];
    __syncthreads();

    if (threadIdx.x < 160) {
        int m = threadIdx.x / 16, j = threadIdx.x % 16;
        float s = 0.f;
        #pragma unroll
        for (int gg = 0; gg < 16; ++gg) s += red[gg][j][m];
        part[(b * 16 + slice) * 160 + m * 16 + j] = s;
    }
}

// ===================== fc final: reduce slices + LN2 -> out =====================
__global__ __launch_bounds__(256) void k_fc2_fin(const float* __restrict__ part,
                                                 const float* __restrict__ g,
                                                 const float* __restrict__ bt,
                                                 float* __restrict__ out) {
    int b = blockIdx.x;
    if (threadIdx.x >= 160) return;
    int m = threadIdx.x / 16, j = threadIdx.x % 16;
    float s = 0.f;
    #pragma unroll
    for (int sl = 0; sl < 16; ++sl)
        s += part[(b * 16 + sl) * 160 + m * 16 + j];
    float mu = s;
    #pragma unroll
    for (int off = 1; off < 16; off <<= 1) mu += __shfl_xor(mu, off);
    mu *= (1.f / 16.f);
    float t = s - mu;
    float var = t * t;
    #pragma unroll
    for (int off = 1; off < 16; off <<= 1) var += __shfl_xor(var, off);
    var *= (1.f / 16.f);
    float rs = rsqrtf(var + EPSLN);
    out[(b * 10 + m) * 16 + j] = t * rs * g[j] + bt[j];
}

// ============================ launch ============================
extern "C" void kernel_launch(void* const* d_in, const int* in_sizes, int n_in,
                              void* d_out, int out_size, void* d_ws, size_t ws_size,
                              hipStream_t stream) {
    const float* x    = (const float*)d_in[0];
    const float* bbw  = (const float*)d_in[1];
    const float* bbb  = (const float*)d_in[2];
    const float* pcw  = (const float*)d_in[3];
    const float* ln0g = (const float*)d_in[4];
    const float* ln0b = (const float*)d_in[5];
    const float* cwt  = (const float*)d_in[6];
    const float* ln1g = (const float*)d_in[7];
    const float* ln1b = (const float*)d_in[8];
    const float* fw   = (const float*)d_in[9];
    const float* ln2g = (const float*)d_in[10];
    const float* ln2b = (const float*)d_in[11];
    float* outp = (float*)d_out;

    float* ws = (float*)d_ws;
    __bf16* c2p  = (__bf16*)ws;                 // [0,          4,734,976)
    __bf16* wbT  = (__bf16*)(ws + 4734976);     // [4,734,976,  5,029,888)
    float*  bwT  = ws + 5029888;                // [5,029,888,  5,033,344)
    float*  val  = ws + 5033344;                // [5,033,344, 13,421,952)
    float*  v2   = ws + 13421952;               // [13,421,952, 15,027,584)
    float*  fwp  = ws + 15027584;               // [15,027,584, 15,278,464)
    float*  p    = ws + 15278464;               // [15,278,464, 15,288,704)
    __bf16* cw2  = (__bf16*)(ws + 15288704);    // [15,288,704, 15,362,432)
    __bf16* cwB  = (__bf16*)(ws + 15362432);    // [15,362,432, 15,436,160)
    float*  nv1g = ws + 15436160;               // [15,436,160, 17,041,792)
    float*  part = val;                         // aliases dead val

    hipMemsetAsync(c2p, 0, (size_t)9469952 * 2, stream);
    k_repack_all <<<4450, 256, 0, stream>>>(bbw, bwT, pcw, wbT, fw, fwp, cwt, cw2, cwB);
    k_conv1      <<<2048, 256, 0, stream>>>(x, bwT, bbb, c2p);
    k_conv2_mfma <<<512,  256, 0, stream>>>(c2p, wbT, ln0g, ln0b, val);
    k_nv1_mfma   <<<392,  256, 0, stream>>>(val, cwB, nv1g);
    k_capsfused  <<<3136, 256, 0, stream>>>(val, cw2, nv1g, ln1g, ln1b, v2);
    k_fc1        <<<640, 256, 0, stream>>>(v2, fwp, ln2g, ln2b, p);
    k_fc2_part   <<<1024, 256, 0, stream>>>(v2, fw, p, part);
    k_fc2_fin    <<<64, 256, 0, stream>>>(part, ln2g, ln2b, outp);
}

// Round 20
// 223.246 us; speedup vs baseline: 1.6292x; 1.0026x over previous
//
#include <hip/hip_runtime.h>

// CapsTimeModel forward, round 20: capsfused 512 threads / 16 groups x 18 items
// (halves per-group serial softmax chain; 2x wave TLP per block).
// All else identical to R19 (passing, 224us).

#define EPSLN 1e-5f

#if defined(__has_builtin)
# if __has_builtin(__builtin_amdgcn_fdot2_f32_bf16)
#  define HAS_DOT2 1
# endif
#endif
#ifndef HAS_DOT2
# define HAS_DOT2 0
#endif

typedef short  short8 __attribute__((ext_vector_type(8)));
typedef __bf16 bf16x8 __attribute__((ext_vector_type(8)));
typedef __bf16 bf16x2 __attribute__((ext_vector_type(2)));
typedef float  f32x4  __attribute__((ext_vector_type(4)));

union Frag { short8 s; bf16x8 b; };

__device__ __forceinline__ uint4 pack_bf16_8(float4 a, float4 b) {
    union { __bf16 h[8]; uint4 u; } r;
    r.h[0] = (__bf16)a.x; r.h[1] = (__bf16)a.y;
    r.h[2] = (__bf16)a.z; r.h[3] = (__bf16)a.w;
    r.h[4] = (__bf16)b.x; r.h[5] = (__bf16)b.y;
    r.h[6] = (__bf16)b.z; r.h[7] = (__bf16)b.w;
    return r.u;
}

__device__ __forceinline__ void gld16(const void* g, void* l) {
    __builtin_amdgcn_global_load_lds(
        (const __attribute__((address_space(1))) void*)g,
        (__attribute__((address_space(3))) void*)l, 16, 0, 0);
}

// ==================== fused repacks (blockIdx-range dispatch) ====================
__global__ __launch_bounds__(256) void k_repack_all(
        const float* __restrict__ bw,  float* __restrict__ bwT,
        const float* __restrict__ pw,  __bf16* __restrict__ wbT,
        const float* __restrict__ fw,  float* __restrict__ fwp,
        const float* __restrict__ cw,  __bf16* __restrict__ cw2,
        __bf16* __restrict__ cwB) {
    int blk = blockIdx.x;
    if (blk < 2304) {                         // pcw -> wbT : 589824 exact
        int i = blk * 256 + threadIdx.x;
        int oc = i / 1152, r = i % 1152;
        int ic = r / 9, tap = r % 9;
        wbT[oc * 1152 + tap * 128 + ic] = (__bf16)pw[i];
    } else if (blk < 3284) {                  // fw -> fwp : 250880 exact
        int i = (blk - 2304) * 256 + threadIdx.x;
        int m = i % 10;
        int d = (i / 10) & 3;
        int x = (i / 40) & 3;
        int n = i / 160;
        fwp[(m * 1568 + n) * 16 + x * 4 + d] = fw[i];
    } else if (blk < 3860) {                  // cw -> cw2 : 147456 exact (pair-major)
        int i = (blk - 3284) * 256 + threadIdx.x;
        int m  = i & 31;
        int d  = (i >> 5) & 3;
        int x  = (i >> 7) & 3;
        int n  = (i >> 9) & 31;
        int kl = i >> 14;
        cw2[(((kl * 32 + n) * 32) + m) * 16 + d * 4 + (x >> 1) * 2 + (x & 1)]
            = (__bf16)cw[i];
    } else if (blk < 4436) {                  // cw -> cwB : 147456 exact
        int i = (blk - 3860) * 256 + threadIdx.x;
        int m  = i & 31;
        int d  = (i >> 5) & 3;
        int x  = (i >> 7) & 3;
        int n  = (i >> 9) & 31;
        int kl = i >> 14;
        cwB[(m * 4 + d) * 1152 + (n * 9 + kl) * 4 + x] = (__bf16)cw[i];
    } else {                                  // bw -> bwT : 3456
        int i = (blk - 4436) * 256 + threadIdx.x;
        if (i < 3456) {
            int oc = i / 27, r = i % 27;
            bwT[r * 128 + oc] = bw[i];
        }
    }
}

// ==================== conv1 (LDS-staged): x -> c2p (NHWC bf16, padded) ====================
__global__ __launch_bounds__(256) void k_conv1(const float* __restrict__ x,
                                               const float* __restrict__ bwT,
                                               const float* __restrict__ bb,
                                               __bf16* __restrict__ c2p) {
    __shared__ float xs[3][3][66];

    int b = blockIdx.x >> 5, h = blockIdx.x & 31;
    for (int i = threadIdx.x; i < 594; i += 256) {
        int iw = i % 66;
        int r  = (i / 66) % 3;
        int ic = i / 198;
        int ih  = 2 * h + r - 1;
        int riw = iw - 1;
        float v = 0.f;
        if ((unsigned)ih < 64u && (unsigned)riw < 64u)
            v = x[((b * 3 + ic) * 64 + ih) * 64 + riw];
        xs[ic][r][iw] = v;
    }
    __syncthreads();

    int oc4 = threadIdx.x & 31, wq = threadIdx.x >> 5;
    float4 wv[27];
    #pragma unroll
    for (int r = 0; r < 27; ++r)
        wv[r] = *(const float4*)(bwT + r * 128 + oc4 * 4);
    float4 bias = *(const float4*)(bb + oc4 * 4);

    #pragma unroll
    for (int q = 0; q < 4; ++q) {
        int w = wq + q * 8;
        float4 acc = bias;
        #pragma unroll
        for (int ky = 0; ky < 3; ++ky)
            #pragma unroll
            for (int kx = 0; kx < 3; ++kx)
                #pragma unroll
                for (int ic = 0; ic < 3; ++ic) {
                    float in = xs[ic][ky][2 * w + kx];
                    float4 ww = wv[ic * 9 + ky * 3 + kx];
                    acc.x = fmaf(in, ww.x, acc.x);
                    acc.y = fmaf(in, ww.y, acc.y);
                    acc.z = fmaf(in, ww.z, acc.z);
                    acc.w = fmaf(in, ww.w, acc.w);
                }
        union { __bf16 h4[4]; unsigned long long ull; } r;
        r.h4[0] = (__bf16)fmaxf(acc.x, 0.f);
        r.h4[1] = (__bf16)fmaxf(acc.y, 0.f);
        r.h4[2] = (__bf16)fmaxf(acc.z, 0.f);
        r.h4[3] = (__bf16)fmaxf(acc.w, 0.f);
        *(unsigned long long*)(c2p + ((b * 34 + h + 1) * 34 + (w + 1)) * 128 + oc4 * 4)
            = r.ull;
    }
}

// ==================== conv2: 128x128 gld-dbuf MFMA GEMM + fused LN0 (XCD swz) ====================
__global__ __launch_bounds__(256) void k_conv2_mfma(const __bf16* __restrict__ c2p,
                                                    const __bf16* __restrict__ wbT,
                                                    const float* __restrict__ g,
                                                    const float* __restrict__ bt,
                                                    float* __restrict__ val) {
    __shared__ unsigned short sA[2][128 * 32];
    __shared__ unsigned short sB[2][128 * 32];

    const int t = threadIdx.x;
    const int swz = (blockIdx.x & 7) * 64 + (blockIdx.x >> 3);
    const int mblk = swz >> 2, nblk = swz & 3;
    const int pbase = mblk * 128, ocbase = nblk * 128;
    const int b = pbase >> 8;

    const int kc8 = (t & 3) * 8;
    const int r0 = t >> 2;
    const int oh0 = ((pbase + r0) >> 4) & 15, ow0 = (pbase + r0) & 15;
    const int oh1 = ((pbase + r0 + 64) >> 4) & 15, ow1 = (pbase + r0 + 64) & 15;

    const unsigned short* cb  = (const unsigned short*)c2p + (size_t)b * 147968;
    const unsigned short* ws0 = (const unsigned short*)wbT
                                + (ocbase + r0) * 1152 + kc8;
    const unsigned short* ws1 = ws0 + (size_t)64 * 1152;

    const int lane = t & 63, wid = t >> 6;
    const int lo = lane & 15, hi = lane >> 4;

    f32x4 acc[2][8];
    #pragma unroll
    for (int fr = 0; fr < 2; ++fr)
        #pragma unroll
        for (int fc = 0; fc < 8; ++fc)
            acc[fr][fc] = (f32x4){0.f, 0.f, 0.f, 0.f};

    auto stage = [&](int buf, int ks) {
        int tap = ks / 4, ic0 = (ks % 4) * 32;
        int ty = tap / 3, tx = tap % 3;
        gld16(cb + ((2 * oh0 + ty) * 34 + (2 * ow0 + tx)) * 128 + ic0 + kc8,
              &sA[buf][(unsigned)t * 8]);
        gld16(cb + ((2 * oh1 + ty) * 34 + (2 * ow1 + tx)) * 128 + ic0 + kc8,
              &sA[buf][((unsigned)t + 256) * 8]);
        gld16(ws0 + ks * 32, &sB[buf][(unsigned)t * 8]);
        gld16(ws1 + ks * 32, &sB[buf][((unsigned)t + 256) * 8]);
    };

    stage(0, 0);
    __syncthreads();

    for (int ks = 0; ks < 36; ++ks) {
        const int cur = ks & 1;
        if (ks + 1 < 36) stage(cur ^ 1, ks + 1);
        Frag af0, af1, bf[8];
        af0.s = *(const short8*)&sA[cur][(wid * 32 + lo) * 32 + hi * 8];
        af1.s = *(const short8*)&sA[cur][(wid * 32 + 16 + lo) * 32 + hi * 8];
        #pragma unroll
        for (int fc = 0; fc < 8; ++fc)
            bf[fc].s = *(const short8*)&sB[cur][(fc * 16 + lo) * 32 + hi * 8];
        #pragma unroll
        for (int fc = 0; fc < 8; ++fc) {
            acc[0][fc] = __builtin_amdgcn_mfma_f32_16x16x32_bf16(
                af0.b, bf[fc].b, acc[0][fc], 0, 0, 0);
            acc[1][fc] = __builtin_amdgcn_mfma_f32_16x16x32_bf16(
                af1.b, bf[fc].b, acc[1][fc], 0, 0, 0);
        }
        __syncthreads();
    }

    const float gv = g[lo], bv = bt[lo];
    #pragma unroll
    for (int fr = 0; fr < 2; ++fr) {
        #pragma unroll
        for (int fc = 0; fc < 8; ++fc) {
            const int n = (ocbase >> 4) + fc;
            #pragma unroll
            for (int j = 0; j < 4; ++j) {
                float v = acc[fr][fc][j];
                float s1 = v, s2 = v * v;
                #pragma unroll
                for (int off = 1; off < 16; off <<= 1) {
                    s1 += __shfl_xor(s1, off);
                    s2 += __shfl_xor(s2, off);
                }
                float mu  = s1 * (1.f / 16.f);
                float var = s2 * (1.f / 16.f) - mu * mu;
                float rs  = rsqrtf(var + EPSLN);
                float o   = (v - mu) * rs * gv + bv;
                int p  = pbase + wid * 32 + fr * 16 + hi * 4 + j;
                int oh = (p >> 4) & 15, ow = p & 15;
                val[(((b * 32 + n) * 16 + oh) * 16 + ow) * 16 + lo] = o;
            }
        }
    }
}

// ==================== nv1 GEMM (BM=64, pipelined): val x cwB -> nv1g ====================
__global__ __launch_bounds__(256) void k_nv1_mfma(const float* __restrict__ val,
                                                  const __bf16* __restrict__ cwB,
                                                  float* __restrict__ nv1g) {
    __shared__ unsigned short sA[64 * 32];
    __shared__ unsigned short sB[64 * 32];

    const int t = threadIdx.x;
    const int mblk = blockIdx.x >> 1, nblk = blockIdx.x & 1;
    const int pbase = mblk * 64, ocbase = nblk * 64;

    const float* vbase;
    {
        int r = pbase + (t >> 2);
        int site = r >> 2, a = r & 3;
        int b = site / 49, hw = site % 49;
        int h = hw / 7, w = hw % 7;
        vbase = val + (size_t)b * 131072 + (2 * h) * 256 + (2 * w) * 16 + a * 4;
    }
    const unsigned short* wsrc = (const unsigned short*)cwB
                                 + (ocbase + (t >> 2)) * 1152 + (t & 3) * 8;

    const int lane = t & 63, wid = t >> 6;
    const int lo = lane & 15, hi = lane >> 4;

    f32x4 acc[4];
    #pragma unroll
    for (int fc = 0; fc < 4; ++fc)
        acc[fc] = (f32x4){0.f, 0.f, 0.f, 0.f};

    auto itemoff = [](int i) {
        int n = i / 9, kl = i % 9;
        return n * 4096 + (kl / 3) * 256 + (kl % 3) * 16;
    };

    {
        int i0 = (t & 3) * 2;
        int o0 = itemoff(i0), o1 = itemoff(i0 + 1);
        uint4 a0 = pack_bf16_8(*(const float4*)(vbase + o0),
                               *(const float4*)(vbase + o1));
        uint4 b0 = *(const uint4*)(wsrc);
        *(uint4*)&sA[(unsigned)t * 8] = a0;
        *(uint4*)&sB[(unsigned)t * 8] = b0;
        __syncthreads();
    }

    for (int ks = 0; ks < 36; ++ks) {
        uint4 a0, b0;
        const bool pre = (ks + 1) < 36;
        if (pre) {
            int i0 = (ks + 1) * 8 + (t & 3) * 2;
            int o0 = itemoff(i0), o1 = itemoff(i0 + 1);
            a0 = pack_bf16_8(*(const float4*)(vbase + o0),
                             *(const float4*)(vbase + o1));
            b0 = *(const uint4*)(wsrc + (ks + 1) * 32);
        }
        Frag af, bf[4];
        af.s = *(const short8*)&sA[(wid * 16 + lo) * 32 + hi * 8];
        #pragma unroll
        for (int fc = 0; fc < 4; ++fc)
            bf[fc].s = *(const short8*)&sB[(fc * 16 + lo) * 32 + hi * 8];
        #pragma unroll
        for (int fc = 0; fc < 4; ++fc)
            acc[fc] = __builtin_amdgcn_mfma_f32_16x16x32_bf16(
                af.b, bf[fc].b, acc[fc], 0, 0, 0);
        __syncthreads();
        if (pre) {
            *(uint4*)&sA[(unsigned)t * 8] = a0;
            *(uint4*)&sB[(unsigned)t * 8] = b0;
        }
        __syncthreads();
    }

    #pragma unroll
    for (int fc = 0; fc < 4; ++fc)
        #pragma unroll
        for (int j = 0; j < 4; ++j) {
            int row = pbase + wid * 16 + hi * 4 + j;
            int col = ocbase + fc * 16 + lo;
            nv1g[row * 128 + col] = acc[fc][j];
        }
}

// ===================== caps routing pass 2 + LN1 (512 thr, 16 grp x 18 items) =====================
__global__ __launch_bounds__(512) void k_capsfused(const float* __restrict__ val,
                                                   const __bf16* __restrict__ cw2,
                                                   const float* __restrict__ nv1g,
                                                   const float* __restrict__ g,
                                                   const float* __restrict__ bt,
                                                   float* __restrict__ vout) {
    int swz = (blockIdx.x & 7) * 392 + (blockIdx.x >> 3);
    int b  = swz / 49;
    int hw = swz % 49;
    int h = hw / 7, w = hw % 7;

#if HAS_DOT2
    __shared__ uint4 ulocH[576];        //  9216 B packed bf16 u
#else
    __shared__ float4 uloc4[1152];      // 18432 B f32 u
#endif
    __shared__ float wredS[8 * 544];    // 17408 B (8 wave-partials, padded)
    __shared__ float v1s[512];          //  2048 B

#if HAS_DOT2
    for (int tt = threadIdx.x; tt < 576; tt += 512) {
        int item = tt >> 1, hf = tt & 1;
        int n = item / 9, kl = item % 9;
        int k = kl / 3, l = kl % 3;
        const float4* src = (const float4*)(val +
            (((b * 32 + n) * 16 + (2 * h + k)) * 16 + (2 * w + l)) * 16 + hf * 8);
        ulocH[tt] = pack_bf16_8(src[0], src[1]);
    }
#else
    for (int tt = threadIdx.x; tt < 1152; tt += 512) {
        int f  = tt & 3;
        int kl = (tt >> 2) % 9;
        int n  = tt / 36;
        int k = kl / 3, l = kl % 3;
        uloc4[tt] = *(const float4*)(val +
            (((b * 32 + n) * 16 + (2 * h + k)) * 16 + (2 * w + l)) * 16 + f * 4);
    }
#endif

    const int lane  = threadIdx.x & 31;          // m
    const int grpid = threadIdx.x >> 5;          // 0..15
    const int wid   = threadIdx.x >> 6;          // 0..7
    const bool half0 = (threadIdx.x & 32) == 0;

    float nvp[16];
    {
        int site = b * 49 + hw;
        #pragma unroll
        for (int a = 0; a < 4; ++a) {
            float4 q = *(const float4*)(nv1g + (site * 4 + a) * 128 + lane * 4);
            nvp[a * 4 + 0] = q.x * (1.f / 32.f);
            nvp[a * 4 + 1] = q.y * (1.f / 32.f);
            nvp[a * 4 + 2] = q.z * (1.f / 32.f);
            nvp[a * 4 + 3] = q.w * (1.f / 32.f);
        }
        float mu = 0.f;
        #pragma unroll
        for (int j = 0; j < 16; ++j) mu += nvp[j];
        mu *= (1.f / 16.f);
        float var = 0.f;
        #pragma unroll
        for (int j = 0; j < 16; ++j) { float d = nvp[j] - mu; var += d * d; }
        var *= (1.f / 16.f);
        float rs = rsqrtf(var + EPSLN);
        #pragma unroll
        for (int j = 0; j < 16; ++j)
            nvp[j] = (nvp[j] - mu) * rs * g[j] + bt[j];
    }

    float nvacc[16];
    #pragma unroll
    for (int j = 0; j < 16; ++j) nvacc[j] = 0.f;

    __syncthreads();

    {
        uint4 wq0, wq1;
        {
            int n = grpid / 9, kl = grpid % 9;
            const uint4* wb = (const uint4*)(cw2 + (((kl * 32 + n) * 32) + lane) * 16);
            wq0 = wb[0]; wq1 = wb[1];
        }
        for (int it = grpid; it < 288; it += 16) {
            int nit = it + 16;
            uint4 nq0 = wq0, nq1 = wq1;
            if (nit < 288) {
                int n = nit / 9, kl = nit % 9;
                const uint4* wb = (const uint4*)(cw2 + (((kl * 32 + n) * 32) + lane) * 16);
                nq0 = wb[0]; nq1 = wb[1];
            }
            float votes[16];
#if HAS_DOT2
            {
                union { uint4 u; bf16x2 h2[4]; } wA, wB, uA, uB;
                wA.u = wq0; wB.u = wq1;
                uA.u = ulocH[it * 2];
                uB.u = ulocH[it * 2 + 1];
                #pragma unroll
                for (int a = 0; a < 4; ++a) {
                    bf16x2 u0 = (a < 2) ? uA.h2[a * 2]     : uB.h2[(a - 2) * 2];
                    bf16x2 u1 = (a < 2) ? uA.h2[a * 2 + 1] : uB.h2[(a - 2) * 2 + 1];
                    #pragma unroll
                    for (int d = 0; d < 4; ++d) {
                        bf16x2 w0 = (d < 2) ? wA.h2[d * 2]     : wB.h2[(d - 2) * 2];
                        bf16x2 w1 = (d < 2) ? wA.h2[d * 2 + 1] : wB.h2[(d - 2) * 2 + 1];
                        votes[a * 4 + d] = __builtin_amdgcn_fdot2_f32_bf16(
                            u1, w1,
                            __builtin_amdgcn_fdot2_f32_bf16(u0, w0, 0.f, false),
                            false);
                    }
                }
            }
#else
            {
                union { uint4 u; __bf16 hh[8]; } qa, qb;
                qa.u = wq0; qb.u = wq1;
                float cwv[16];
                #pragma unroll
                for (int x = 0; x < 4; ++x)
                    #pragma unroll
                    for (int d = 0; d < 4; ++d) {
                        int pos = d * 4 + (x >> 1) * 2 + (x & 1);
                        cwv[x * 4 + d] = (float)(pos < 8 ? qa.hh[pos] : qb.hh[pos - 8]);
                    }
                float u16[16];
                #pragma unroll
                for (int f = 0; f < 4; ++f) {
                    float4 t4 = uloc4[it * 4 + f];
                    u16[f * 4 + 0] = t4.x; u16[f * 4 + 1] = t4.y;
                    u16[f * 4 + 2] = t4.z; u16[f * 4 + 3] = t4.w;
                }
                #pragma unroll
                for (int a = 0; a < 4; ++a)
                    #pragma unroll
                    for (int d = 0; d < 4; ++d) {
                        float v = 0.f;
                        #pragma unroll
                        for (int x = 0; x < 4; ++x)
                            v = fmaf(u16[a * 4 + x], cwv[x * 4 + d], v);
                        votes[a * 4 + d] = v;
                    }
            }
#endif
            float qk = 0.f;
            #pragma unroll
            for (int j = 0; j < 16; ++j) qk = fmaf(votes[j], nvp[j], qk);
            qk *= 0.25f;
            float e = __expf(fminf(qk, 60.f));
            float sm = e;
            #pragma unroll
            for (int off = 1; off < 32; off <<= 1) sm += __shfl_xor(sm, off);
            float qv = e * __builtin_amdgcn_rcpf(sm);
            #pragma unroll
            for (int j = 0; j < 16; ++j) nvacc[j] = fmaf(qv, votes[j], nvacc[j]);
            wq0 = nq0; wq1 = nq1;
        }
    }

    // combine half-wave groups within each wave, then 8 wave-partials via LDS
    #pragma unroll
    for (int j = 0; j < 16; ++j)
        nvacc[j] += __shfl_xor(nvacc[j], 32);
    __syncthreads();
    if (half0) {
        #pragma unroll
        for (int j = 0; j < 16; ++j) wredS[wid * 544 + lane * 17 + j] = nvacc[j];
    }
    __syncthreads();
    if (threadIdx.x < 512) {
        int o = threadIdx.x;
        int mm = o >> 4, j = o & 15;
        float sum = 0.f;
        #pragma unroll
        for (int gg = 0; gg < 8; ++gg) sum += wredS[gg * 544 + mm * 17 + j];
        v1s[o] = sum;
    }
    __syncthreads();
    if (threadIdx.x < 32) {
        int m = threadIdx.x;
        float v16[16], mu = 0.f;
        #pragma unroll
        for (int j = 0; j < 16; ++j) { v16[j] = v1s[m * 16 + j]; mu += v16[j]; }
        mu *= (1.f / 16.f);
        float var = 0.f;
        #pragma unroll
        for (int j = 0; j < 16; ++j) { float t = v16[j] - mu; var += t * t; }
        var *= (1.f / 16.f);
        float rs = rsqrtf(var + EPSLN);
        float o16[16];
        #pragma unroll
        for (int j = 0; j < 16; ++j) o16[j] = (v16[j] - mu) * rs * g[j] + bt[j];
        float4* dst = (float4*)(vout + (((b * 32 + m) * 7 + h) * 7 + w) * 16);
        dst[0] = make_float4(o16[0],  o16[1],  o16[2],  o16[3]);
        dst[1] = make_float4(o16[4],  o16[5],  o16[6],  o16[7]);
        dst[2] = make_float4(o16[8],  o16[9],  o16[10], o16[11]);
        dst[3] = make_float4(o16[12], o16[13], o16[14], o16[15]);
    }
}

// ===================== fc step1 + LN2: v2 -> p =====================
__global__ __launch_bounds__(256) void k_fc1(const float* __restrict__ fin,
                                             const float* __restrict__ fwp,
                                             const float* __restrict__ g,
                                             const float* __restrict__ bt,
                                             float* __restrict__ p) {
    int b = blockIdx.x / 10, m = blockIdx.x % 10;
    const float* fb = fin + b * 1568 * 16;
    const float* wb = fwp + m * 1568 * 16;
    float acc[16];
    #pragma unroll
    for (int j = 0; j < 16; ++j) acc[j] = 0.f;

    for (int n = threadIdx.x; n < 1568; n += 256) {
        const float4* u4 = (const float4*)(fb + n * 16);
        const float4* w4 = (const float4*)(wb + n * 16);
        float u16[16], w16[16];
        #pragma unroll
        for (int f = 0; f < 4; ++f) {
            float4 a = u4[f], bq = w4[f];
            u16[f * 4 + 0] = a.x;  u16[f * 4 + 1] = a.y;
            u16[f * 4 + 2] = a.z;  u16[f * 4 + 3] = a.w;
            w16[f * 4 + 0] = bq.x; w16[f * 4 + 1] = bq.y;
            w16[f * 4 + 2] = bq.z; w16[f * 4 + 3] = bq.w;
        }
        #pragma unroll
        for (int a = 0; a < 4; ++a)
            #pragma unroll
            for (int d = 0; d < 4; ++d) {
                float s = acc[a * 4 + d];
                #pragma unroll
                for (int x = 0; x < 4; ++x)
                    s = fmaf(u16[a * 4 + x], w16[x * 4 + d], s);
                acc[a * 4 + d] = s;
            }
    }
    #pragma unroll
    for (int j = 0; j < 16; ++j)
        #pragma unroll
        for (int off = 1; off < 64; off <<= 1)
            acc[j] += __shfl_xor(acc[j], off);

    __shared__ float red[4][16];
    int wid = threadIdx.x >> 6, ln = threadIdx.x & 63;
    if (ln == 0) {
        #pragma unroll
        for (int j = 0; j < 16; ++j) red[wid][j] = acc[j];
    }
    __syncthreads();
    if (threadIdx.x < 16) {
        int j = threadIdx.x;
        float s = (red[0][j] + red[1][j] + red[2][j] + red[3][j]) * 0.1f;
        float mu = s;
        #pragma unroll
        for (int off = 1; off < 16; off <<= 1) mu += __shfl_xor(mu, off);
        mu *= (1.f / 16.f);
        float t = s - mu;
        float var = t * t;
        #pragma unroll
        for (int off = 1; off < 16; off <<= 1) var += __shfl_xor(var, off);
        var *= (1.f / 16.f);
        float rs = rsqrtf(var + EPSLN);
        p[(b * 10 + m) * 16 + j] = t * rs * g[j] + bt[j];
    }
}

// ===================== fc routing, n-split partials =====================
__global__ __launch_bounds__(256) void k_fc2_part(const float* __restrict__ fin,
                                                  const float* __restrict__ fw,
                                                  const float* __restrict__ p,
                                                  float* __restrict__ part) {
    int b = blockIdx.x >> 4, slice = blockIdx.x & 15;
    int ad    = threadIdx.x & 15;
    int grpid = threadIdx.x >> 4;
    int a = ad >> 2, d = ad & 3;

    float pv[10];
    #pragma unroll
    for (int m = 0; m < 10; ++m) pv[m] = p[(b * 10 + m) * 16 + ad];

    float acc[10];
    #pragma unroll
    for (int m = 0; m < 10; ++m) acc[m] = 0.f;

    const float* fb = fin + b * 1568 * 16;
    int nbase = slice * 98;
    for (int n = nbase + grpid; n < nbase + 98; n += 16) {
        float4 u4 = *(const float4*)(fb + n * 16 + a * 4);
        const float* wb = fw + n * 160 + d * 10;
        float votes[10];
        #pragma unroll
        for (int m = 0; m < 10; ++m)
            votes[m] = u4.x * wb[m] + u4.y * wb[40 + m] +
                       u4.z * wb[80 + m] + u4.w * wb[120 + m];
        float qk[10];
        #pragma unroll
        for (int m = 0; m < 10; ++m) {
            float t = votes[m] * pv[m];
            #pragma unroll
            for (int off = 1; off < 16; off <<= 1) t += __shfl_xor(t, off);
            qk[m] = t * 0.25f;
        }
        float mx = qk[0];
        #pragma unroll
        for (int m = 1; m < 10; ++m) mx = fmaxf(mx, qk[m]);
        float e[10], s = 0.f;
        #pragma unroll
        for (int m = 0; m < 10; ++m) { e[m] = __expf(qk[m] - mx); s += e[m]; }
        float inv = 1.f / s;
        #pragma unroll
        for (int m = 0; m < 10; ++m) acc[m] = fmaf(e[m] * inv, votes[m], acc[m]);
    }

    __shared__ float red[16][16][10];
    #pragma unroll
    for (int m = 0; m < 10; ++m) red[grpid][ad][m] = acc[m];
    __syncthreads();

    if (threadIdx.x < 160) {
        int m = threadIdx.x / 16, j = threadIdx.x % 16;
        float s = 0.f;
        #pragma unroll
        for (int gg = 0; gg < 16; ++gg) s += red[gg][j][m];
        part[(b * 16 + slice) * 160 + m * 16 + j] = s;
    }
}

// ===================== fc final: reduce slices + LN2 -> out =====================
__global__ __launch_bounds__(256) void k_fc2_fin(const float* __restrict__ part,
                                                 const float* __restrict__ g,
                                                 const float* __restrict__ bt,
                                                 float* __restrict__ out) {
    int b = blockIdx.x;
    if (threadIdx.x >= 160) return;
    int m = threadIdx.x / 16, j = threadIdx.x % 16;
    float s = 0.f;
    #pragma unroll
    for (int sl = 0; sl < 16; ++sl)
        s += part[(b * 16 + sl) * 160 + m * 16 + j];
    float mu = s;
    #pragma unroll
    for (int off = 1; off < 16; off <<= 1) mu += __shfl_xor(mu, off);
    mu *= (1.f / 16.f);
    float t = s - mu;
    float var = t * t;
    #pragma unroll
    for (int off = 1; off < 16; off <<= 1) var += __shfl_xor(var, off);
    var *= (1.f / 16.f);
    float rs = rsqrtf(var + EPSLN);
    out[(b * 10 + m) * 16 + j] = t * rs * g[j] + bt[j];
}

// ============================ launch ============================
extern "C" void kernel_launch(void* const* d_in, const int* in_sizes, int n_in,
                              void* d_out, int out_size, void* d_ws, size_t ws_size,
                              hipStream_t stream) {
    const float* x    = (const float*)d_in[0];
    const float* bbw  = (const float*)d_in[1];
    const float* bbb  = (const float*)d_in[2];
    const float* pcw  = (const float*)d_in[3];
    const float* ln0g = (const float*)d_in[4];
    const float* ln0b = (const float*)d_in[5];
    const float* cwt  = (const float*)d_in[6];
    const float* ln1g = (const float*)d_in[7];
    const float* ln1b = (const float*)d_in[8];
    const float* fw   = (const float*)d_in[9];
    const float* ln2g = (const float*)d_in[10];
    const float* ln2b = (const float*)d_in[11];
    float* outp = (float*)d_out;

    float* ws = (float*)d_ws;
    __bf16* c2p  = (__bf16*)ws;                 // [0,          4,734,976)
    __bf16* wbT  = (__bf16*)(ws + 4734976);     // [4,734,976,  5,029,888)
    float*  bwT  = ws + 5029888;                // [5,029,888,  5,033,344)
    float*  val  = ws + 5033344;                // [5,033,344, 13,421,952)
    float*  v2   = ws + 13421952;               // [13,421,952, 15,027,584)
    float*  fwp  = ws + 15027584;               // [15,027,584, 15,278,464)
    float*  p    = ws + 15278464;               // [15,278,464, 15,288,704)
    __bf16* cw2  = (__bf16*)(ws + 15288704);    // [15,288,704, 15,362,432)
    __bf16* cwB  = (__bf16*)(ws + 15362432);    // [15,362,432, 15,436,160)
    float*  nv1g = ws + 15436160;               // [15,436,160, 17,041,792)
    float*  part = val;                         // aliases dead val

    hipMemsetAsync(c2p, 0, (size_t)9469952 * 2, stream);
    k_repack_all <<<4450, 256, 0, stream>>>(bbw, bwT, pcw, wbT, fw, fwp, cwt, cw2, cwB);
    k_conv1      <<<2048, 256, 0, stream>>>(x, bwT, bbb, c2p);
    k_conv2_mfma <<<512,  256, 0, stream>>>(c2p, wbT, ln0g, ln0b, val);
    k_nv1_mfma   <<<392,  256, 0, stream>>>(val, cwB, nv1g);
    k_capsfused  <<<3136, 512, 0, stream>>>(val, cw2, nv1g, ln1g, ln1b, v2);
    k_fc1        <<<640, 256, 0, stream>>>(v2, fwp, ln2g, ln2b, p);
    k_fc2_part   <<<1024, 256, 0, stream>>>(v2, fw, p, part);
    k_fc2_fin    <<<64, 256, 0, stream>>>(part, ln2g, ln2b, outp);
}